// Round 1
// baseline (4422.986 us; speedup 1.0000x reference)
//
#include <hip/hip_runtime.h>
#include <cstdint>
#include <cstddef>

// ---------------------------------------------------------------------------
// GraphPartitionModule: quantile-masked 3-way edge partition -> per-class
// normalized-Laplacian powers (D=2) -> theta combination -> MLP head.
//
// Classes: 0=pos (ep > pos_thr), 1=unk, 2=neg (ep < neg_thr). They PARTITION
// the edge set (neg_thr < 0 < pos_thr), so both propagation steps cost one
// full-graph SpMV each per step.
//
// Theta (D=2): T[0]=[3,-3,0.75] (neg), T[1]=[0,3,-1.5] (unk), T[2]=[0,0,0.75]
// (pos). out = relu(concat(pos,unk,neg) @ W3 + b3) computed as 3 accumulating
// K=64 GEMMs (avoids materializing the [N,192] concat).
// ---------------------------------------------------------------------------

#define WS_ALIGN(x) (((x) + 255) & ~(size_t)255)

struct QState {
  unsigned n_neg, n_pos;
  unsigned prefix_neg, prefix_pos;
  int rank_neg, rank_pos;
  float frac_neg, frac_pos;
  unsigned vnext_neg, vnext_pos;
  float thr_neg, thr_pos;
  unsigned hist_neg[256];
  unsigned hist_pos[256];
};

// monotone float<->uint key mapping (ascending float == ascending key)
__device__ __forceinline__ unsigned f2key(float v) {
  unsigned u = __float_as_uint(v);
  return (u & 0x80000000u) ? ~u : (u | 0x80000000u);
}
__device__ __forceinline__ float key2f(unsigned k) {
  unsigned u = (k & 0x80000000u) ? (k ^ 0x80000000u) : ~k;
  return __uint_as_float(u);
}

__global__ void qcount_kernel(const float* __restrict__ ep, QState* st, int E) {
  int e = blockIdx.x * blockDim.x + threadIdx.x;
  bool valid = e < E;
  float v = valid ? ep[e] : 1.0f;
  unsigned long long mNeg = __ballot(valid && (v <= 0.f));
  unsigned long long mVal = __ballot(valid);
  if ((threadIdx.x & 63) == 0) {
    unsigned nn = (unsigned)__popcll(mNeg);
    unsigned nv = (unsigned)__popcll(mVal);
    if (nn) atomicAdd(&st->n_neg, nn);
    if (nv > nn) atomicAdd(&st->n_pos, nv - nn);
  }
}

__global__ void qinit_kernel(QState* st) {
  // replicate JAX/numpy f32 quantile index arithmetic exactly
  unsigned nN = st->n_neg, nP = st->n_pos;
  float idxN = __fmul_rn(0.2f, (float)(nN - 1));
  float lowN = floorf(idxN);
  st->rank_neg = (int)lowN;
  st->frac_neg = __fsub_rn(idxN, lowN);
  float idxP = __fmul_rn(0.8f, (float)(nP - 1));
  float lowP = floorf(idxP);
  st->rank_pos = (int)lowP;
  st->frac_pos = __fsub_rn(idxP, lowP);
  st->prefix_neg = 0u; st->prefix_pos = 0u;
  st->vnext_neg = 0xFFFFFFFFu; st->vnext_pos = 0xFFFFFFFFu;
}

__global__ __launch_bounds__(256) void qhist_kernel(const float* __restrict__ ep,
                                                    QState* st, int E, int round) {
  __shared__ unsigned hN[256], hP[256];
  hN[threadIdx.x] = 0u; hP[threadIdx.x] = 0u;
  __syncthreads();
  int shift = 24 - 8 * round;
  unsigned maskHi = 0u;
  if (round > 0) maskHi = 0xFFFFFFFFu << (shift + 8);
  unsigned pN = st->prefix_neg & maskHi;
  unsigned pP = st->prefix_pos & maskHi;
  int stride = gridDim.x * blockDim.x;
  for (int e = blockIdx.x * blockDim.x + threadIdx.x; e < E; e += stride) {
    float v = ep[e];
    unsigned key = f2key(v);
    if (v <= 0.f) {
      if ((key & maskHi) == pN) atomicAdd(&hN[(key >> shift) & 255], 1u);
    } else {
      if ((key & maskHi) == pP) atomicAdd(&hP[(key >> shift) & 255], 1u);
    }
  }
  __syncthreads();
  unsigned cN = hN[threadIdx.x], cP = hP[threadIdx.x];
  if (cN) atomicAdd(&st->hist_neg[threadIdx.x], cN);
  if (cP) atomicAdd(&st->hist_pos[threadIdx.x], cP);
}

__global__ void qupdate_kernel(QState* st, int round) {
  int shift = 24 - 8 * round;
  {
    unsigned cum = 0; unsigned r = (unsigned)st->rank_neg; unsigned pref = st->prefix_neg;
    for (int b = 0; b < 256; ++b) {
      unsigned c = st->hist_neg[b];
      if (r < cum + c) { pref |= ((unsigned)b) << shift; r -= cum; break; }
      cum += c;
    }
    st->prefix_neg = pref; st->rank_neg = (int)r;
  }
  {
    unsigned cum = 0; unsigned r = (unsigned)st->rank_pos; unsigned pref = st->prefix_pos;
    for (int b = 0; b < 256; ++b) {
      unsigned c = st->hist_pos[b];
      if (r < cum + c) { pref |= ((unsigned)b) << shift; r -= cum; break; }
      cum += c;
    }
    st->prefix_pos = pref; st->rank_pos = (int)r;
  }
  for (int i = 0; i < 256; ++i) { st->hist_neg[i] = 0u; st->hist_pos[i] = 0u; }
}

// min key strictly greater than the selected order statistic (v[k+1])
__global__ __launch_bounds__(256) void qvnext_kernel(const float* __restrict__ ep,
                                                     QState* st, int E) {
  __shared__ unsigned mn, mp;
  if (threadIdx.x == 0) { mn = 0xFFFFFFFFu; mp = 0xFFFFFFFFu; }
  __syncthreads();
  int e = blockIdx.x * blockDim.x + threadIdx.x;
  if (e < E) {
    unsigned pN = st->prefix_neg, pP = st->prefix_pos;
    float v = ep[e];
    unsigned key = f2key(v);
    if (v <= 0.f) { if (key > pN) atomicMin(&mn, key); }
    else          { if (key > pP) atomicMin(&mp, key); }
  }
  __syncthreads();
  if (threadIdx.x == 0) {
    if (mn != 0xFFFFFFFFu) atomicMin(&st->vnext_neg, mn);
    if (mp != 0xFFFFFFFFu) atomicMin(&st->vnext_pos, mp);
  }
}

__global__ void qfinal_kernel(QState* st) {
  {
    float v0 = key2f(st->prefix_neg);
    float v1 = (st->vnext_neg == 0xFFFFFFFFu) ? v0 : key2f(st->vnext_neg);
    float f = st->frac_neg;
    st->thr_neg = (f > 0.f) ? __fadd_rn(v0, __fmul_rn(f, __fsub_rn(v1, v0))) : v0;
  }
  {
    float v0 = key2f(st->prefix_pos);
    float v1 = (st->vnext_pos == 0xFFFFFFFFu) ? v0 : key2f(st->vnext_pos);
    float f = st->frac_pos;
    st->thr_pos = (f > 0.f) ? __fadd_rn(v0, __fmul_rn(f, __fsub_rn(v1, v0))) : v0;
  }
}

__global__ void cls_kernel(const float* __restrict__ ep, unsigned char* __restrict__ cls,
                           const QState* __restrict__ st, int E) {
  int e = blockIdx.x * blockDim.x + threadIdx.x;
  if (e >= E) return;
  float thrN = st->thr_neg, thrP = st->thr_pos;
  float v = ep[e];
  cls[e] = (v > thrP) ? (unsigned char)0 : ((v < thrN) ? (unsigned char)2 : (unsigned char)1);
}

__global__ void deg_kernel(const int* __restrict__ dst, const unsigned char* __restrict__ cls,
                           int* __restrict__ deg, int N, int E) {
  int e = blockIdx.x * blockDim.x + threadIdx.x;
  if (e >= E) return;
  atomicAdd(&deg[(int)cls[e] * N + dst[e]], 1);
}

__global__ void dinv_kernel(const int* __restrict__ deg, float* __restrict__ dinv, int total) {
  int i = blockIdx.x * blockDim.x + threadIdx.x;
  if (i >= total) return;
  float d = fmaxf((float)deg[i], 1.f);
  dinv[i] = 1.f / sqrtf(d);
}

// agg[dst] += f[src] * dinv[src] over edges of class myCls. 16 lanes/edge, float4.
__global__ __launch_bounds__(256) void scatter_kernel(const float* __restrict__ f,
    float* __restrict__ agg, const int* __restrict__ src, const int* __restrict__ dst,
    const unsigned char* __restrict__ cls, const float* __restrict__ dinv,
    int myCls, int E) {
  int i = blockIdx.x * 256 + threadIdx.x;
  if (i >= E * 16) return;
  int e = i >> 4, l = i & 15;
  if (cls[e] != (unsigned char)myCls) return;
  int s = src[e], d = dst[e];
  float sc = dinv[s];
  float4 v = ((const float4*)f)[(size_t)s * 16 + l];
  float* out = agg + (size_t)d * 64 + (size_t)l * 4;
  unsafeAtomicAdd(out + 0, v.x * sc);
  unsafeAtomicAdd(out + 1, v.y * sc);
  unsafeAtomicAdd(out + 2, v.z * sc);
  unsafeAtomicAdd(out + 3, v.w * sc);
}

// L1 = h - agg * dinv[n]
__global__ void l1_kernel(const float* __restrict__ h, const float* __restrict__ agg,
                          const float* __restrict__ dinv, float* __restrict__ L1, int N) {
  int i = blockIdx.x * 256 + threadIdx.x;
  if (i >= N * 16) return;
  int n = i >> 4;
  float di = dinv[n];
  float4 hv = ((const float4*)h)[i];
  float4 av = ((const float4*)agg)[i];
  float4 o;
  o.x = hv.x - av.x * di; o.y = hv.y - av.y * di;
  o.z = hv.z - av.z * di; o.w = hv.w - av.w * di;
  ((float4*)L1)[i] = o;
}

// combo = ch*h + c1*L1 + c2*L2, with L2 = L1 - agg2*dinv; written in-place over agg2
__global__ void combine_kernel(const float* __restrict__ h, const float* __restrict__ L1,
                               float* agg2, const float* __restrict__ dinv,
                               float ch, float c1, float c2, int N) {
  int i = blockIdx.x * 256 + threadIdx.x;
  if (i >= N * 16) return;
  int n = i >> 4;
  float di = dinv[n];
  float4 hv = ((const float4*)h)[i];
  float4 v1 = ((const float4*)L1)[i];
  float4 a2 = ((float4*)agg2)[i];
  float4 o;
  o.x = ch * hv.x + c1 * v1.x + c2 * (v1.x - a2.x * di);
  o.y = ch * hv.y + c1 * v1.y + c2 * (v1.y - a2.y * di);
  o.z = ch * hv.z + c1 * v1.z + c2 * (v1.z - a2.z * di);
  o.w = ch * hv.w + c1 * v1.w + c2 * (v1.w - a2.w * di);
  ((float4*)agg2)[i] = o;
}

// C[N,64] = A[N,K] @ W[K,64] (+ C if accum) (+bias, relu if finish)
template<int K>
__global__ __launch_bounds__(256) void gemm64_kernel(const float* __restrict__ A,
    const float* __restrict__ W, const float* __restrict__ bias,
    float* C, int N, int accum, int finish) {
  __shared__ float As[64][65];                 // [k][row], +1 pad kills store conflicts
  __shared__ __align__(16) float Ws[64][64];   // [k][col]
  const int tid = threadIdx.x;
  const int tx = tid & 15;   // col quad
  const int ty = tid >> 4;   // row quad
  const int rowBase = blockIdx.x * 64;
  float acc[4][4] = {};
  for (int kc = 0; kc < K; kc += 64) {
#pragma unroll
    for (int i = 0; i < 16; ++i) {
      int idx = tid + i * 256;
      int r = idx >> 6, c = idx & 63;
      int row = rowBase + r;
      float v = 0.f;
      if (row < N) v = A[(size_t)row * K + kc + c];
      As[c][r] = v;
    }
#pragma unroll
    for (int i = 0; i < 16; ++i) {
      int idx = tid + i * 256;
      int r = idx >> 6, c = idx & 63;
      Ws[r][c] = W[(size_t)(kc + r) * 64 + c];
    }
    __syncthreads();
#pragma unroll
    for (int k = 0; k < 64; ++k) {
      float a0 = As[k][ty * 4 + 0];
      float a1 = As[k][ty * 4 + 1];
      float a2 = As[k][ty * 4 + 2];
      float a3 = As[k][ty * 4 + 3];
      float4 wv = *(const float4*)&Ws[k][tx * 4];
      acc[0][0] += a0 * wv.x; acc[0][1] += a0 * wv.y; acc[0][2] += a0 * wv.z; acc[0][3] += a0 * wv.w;
      acc[1][0] += a1 * wv.x; acc[1][1] += a1 * wv.y; acc[1][2] += a1 * wv.z; acc[1][3] += a1 * wv.w;
      acc[2][0] += a2 * wv.x; acc[2][1] += a2 * wv.y; acc[2][2] += a2 * wv.z; acc[2][3] += a2 * wv.w;
      acc[3][0] += a3 * wv.x; acc[3][1] += a3 * wv.y; acc[3][2] += a3 * wv.z; acc[3][3] += a3 * wv.w;
    }
    __syncthreads();
  }
  float4 bv = make_float4(0.f, 0.f, 0.f, 0.f);
  if (finish) bv = *(const float4*)&bias[tx * 4];
#pragma unroll
  for (int i = 0; i < 4; ++i) {
    int row = rowBase + ty * 4 + i;
    if (row >= N) continue;
    float* cp = C + (size_t)row * 64 + tx * 4;
    float4 o = make_float4(acc[i][0], acc[i][1], acc[i][2], acc[i][3]);
    if (accum) {
      float4 p = *(const float4*)cp;
      o.x += p.x; o.y += p.y; o.z += p.z; o.w += p.w;
    }
    if (finish) {
      o.x = fmaxf(o.x + bv.x, 0.f);
      o.y = fmaxf(o.y + bv.y, 0.f);
      o.z = fmaxf(o.z + bv.z, 0.f);
      o.w = fmaxf(o.w + bv.w, 0.f);
    }
    *(float4*)cp = o;
  }
}

extern "C" void kernel_launch(void* const* d_in, const int* in_sizes, int n_in,
                              void* d_out, int out_size, void* d_ws, size_t ws_size,
                              hipStream_t stream) {
  const float* feat = (const float*)d_in[0];
  const float* ep   = (const float*)d_in[1];
  const int*   src  = (const int*)d_in[2];
  const int*   dst  = (const int*)d_in[3];
  const float* W1   = (const float*)d_in[4];
  const float* b1   = (const float*)d_in[5];
  const float* W2   = (const float*)d_in[6];
  const float* b2   = (const float*)d_in[7];
  const float* W3   = (const float*)d_in[8];
  const float* b3   = (const float*)d_in[9];
  float* out = (float*)d_out;
  const int N = in_sizes[0] / 128;
  const int E = in_sizes[1];

  char* w = (char*)d_ws;
  size_t off = 0;
  QState* st = (QState*)(w + off);           off += WS_ALIGN(sizeof(QState));
  int* deg = (int*)(w + off);                off += WS_ALIGN((size_t)3 * N * 4);
  const size_t zeroBytes = off;              // state + deg zeroed together
  float* dinv = (float*)(w + off);           off += WS_ALIGN((size_t)3 * N * 4);
  unsigned char* cls = (unsigned char*)(w + off); off += WS_ALIGN((size_t)E);
  float* h    = (float*)(w + off);           off += (size_t)N * 64 * 4;
  float* buf1 = (float*)(w + off);           off += (size_t)N * 64 * 4;
  float* buf2 = (float*)(w + off);           off += (size_t)N * 64 * 4;
  (void)ws_size; (void)n_in; (void)out_size;

  hipMemsetAsync(d_ws, 0, zeroBytes, stream);

  const int eb = (E + 255) / 256;
  qcount_kernel<<<eb, 256, 0, stream>>>(ep, st, E);
  qinit_kernel<<<1, 1, 0, stream>>>(st);
  for (int r = 0; r < 4; ++r) {
    qhist_kernel<<<512, 256, 0, stream>>>(ep, st, E, r);
    qupdate_kernel<<<1, 1, 0, stream>>>(st, r);
  }
  qvnext_kernel<<<eb, 256, 0, stream>>>(ep, st, E);
  qfinal_kernel<<<1, 1, 0, stream>>>(st);

  cls_kernel<<<eb, 256, 0, stream>>>(ep, cls, st, E);
  deg_kernel<<<eb, 256, 0, stream>>>(dst, cls, deg, N, E);
  dinv_kernel<<<(3 * N + 255) / 256, 256, 0, stream>>>(deg, dinv, 3 * N);

  const int gb = (N + 63) / 64;
  gemm64_kernel<128><<<gb, 256, 0, stream>>>(feat, W1, b1, buf1, N, 0, 1); // h1
  gemm64_kernel<64><<<gb, 256, 0, stream>>>(buf1, W2, b2, h, N, 0, 1);     // h

  // theta rows: pos=T[2], unk=T[1], neg=T[0]; combo = ch*h + c1*L1 + c2*L2
  const float chArr[3] = {0.f, 0.f, 3.f};
  const float c1Arr[3] = {0.f, 3.f, -3.f};
  const float c2Arr[3] = {0.75f, -1.5f, 0.75f};
  const int sgrid = (E * 16 + 255) / 256;
  const int ngrid = (N * 16 + 255) / 256;
  const size_t hBytes = (size_t)N * 64 * 4;
  for (int c = 0; c < 3; ++c) {
    const float* dv = dinv + (size_t)c * N;
    hipMemsetAsync(buf2, 0, hBytes, stream);
    scatter_kernel<<<sgrid, 256, 0, stream>>>(h, buf2, src, dst, cls, dv, c, E);
    l1_kernel<<<ngrid, 256, 0, stream>>>(h, buf2, dv, buf1, N);
    hipMemsetAsync(buf2, 0, hBytes, stream);
    scatter_kernel<<<sgrid, 256, 0, stream>>>(buf1, buf2, src, dst, cls, dv, c, E);
    combine_kernel<<<ngrid, 256, 0, stream>>>(h, buf1, buf2, dv,
                                              chArr[c], c1Arr[c], c2Arr[c], N);
    gemm64_kernel<64><<<gb, 256, 0, stream>>>(buf2, W3 + (size_t)c * 64 * 64, b3, out,
                                              N, c > 0 ? 1 : 0, c == 2 ? 1 : 0);
  }
}

// Round 2
// 1866.061 us; speedup vs baseline: 2.3702x; 2.3702x over previous
//
#include <hip/hip_runtime.h>
#include <cstdint>
#include <cstddef>

// ---------------------------------------------------------------------------
// GraphPartitionModule: quantile-masked 3-way edge partition -> per-class
// normalized-Laplacian powers (D=2) -> theta combination -> MLP head.
//
// R2: scatter+atomics replaced by CSR gather (zero float atomics).
// CSR rows = (class, dst) over 3N rows, built once; both propagation steps
// per class are gathers with fused epilogues (L1 / theta-combine).
// ---------------------------------------------------------------------------

#define WS_ALIGN(x) (((x) + 255) & ~(size_t)255)

struct QState {
  unsigned n_neg, n_pos;
  unsigned prefix_neg, prefix_pos;
  int rank_neg, rank_pos;
  float frac_neg, frac_pos;
  unsigned vnext_neg, vnext_pos;
  float thr_neg, thr_pos;
  unsigned hist_neg[256];
  unsigned hist_pos[256];
};

// monotone float<->uint key mapping (ascending float == ascending key)
__device__ __forceinline__ unsigned f2key(float v) {
  unsigned u = __float_as_uint(v);
  return (u & 0x80000000u) ? ~u : (u | 0x80000000u);
}
__device__ __forceinline__ float key2f(unsigned k) {
  unsigned u = (k & 0x80000000u) ? (k ^ 0x80000000u) : ~k;
  return __uint_as_float(u);
}

__global__ void qcount_kernel(const float* __restrict__ ep, QState* st, int E) {
  int e = blockIdx.x * blockDim.x + threadIdx.x;
  bool valid = e < E;
  float v = valid ? ep[e] : 1.0f;
  unsigned long long mNeg = __ballot(valid && (v <= 0.f));
  unsigned long long mVal = __ballot(valid);
  if ((threadIdx.x & 63) == 0) {
    unsigned nn = (unsigned)__popcll(mNeg);
    unsigned nv = (unsigned)__popcll(mVal);
    if (nn) atomicAdd(&st->n_neg, nn);
    if (nv > nn) atomicAdd(&st->n_pos, nv - nn);
  }
}

__global__ void qinit_kernel(QState* st) {
  // replicate JAX/numpy f32 quantile index arithmetic exactly
  unsigned nN = st->n_neg, nP = st->n_pos;
  float idxN = __fmul_rn(0.2f, (float)(nN - 1));
  float lowN = floorf(idxN);
  st->rank_neg = (int)lowN;
  st->frac_neg = __fsub_rn(idxN, lowN);
  float idxP = __fmul_rn(0.8f, (float)(nP - 1));
  float lowP = floorf(idxP);
  st->rank_pos = (int)lowP;
  st->frac_pos = __fsub_rn(idxP, lowP);
  st->prefix_neg = 0u; st->prefix_pos = 0u;
  st->vnext_neg = 0xFFFFFFFFu; st->vnext_pos = 0xFFFFFFFFu;
}

__global__ __launch_bounds__(256) void qhist_kernel(const float* __restrict__ ep,
                                                    QState* st, int E, int round) {
  __shared__ unsigned hN[256], hP[256];
  hN[threadIdx.x] = 0u; hP[threadIdx.x] = 0u;
  __syncthreads();
  int shift = 24 - 8 * round;
  unsigned maskHi = 0u;
  if (round > 0) maskHi = 0xFFFFFFFFu << (shift + 8);
  unsigned pN = st->prefix_neg & maskHi;
  unsigned pP = st->prefix_pos & maskHi;
  int stride = gridDim.x * blockDim.x;
  for (int e = blockIdx.x * blockDim.x + threadIdx.x; e < E; e += stride) {
    float v = ep[e];
    unsigned key = f2key(v);
    if (v <= 0.f) {
      if ((key & maskHi) == pN) atomicAdd(&hN[(key >> shift) & 255], 1u);
    } else {
      if ((key & maskHi) == pP) atomicAdd(&hP[(key >> shift) & 255], 1u);
    }
  }
  __syncthreads();
  unsigned cN = hN[threadIdx.x], cP = hP[threadIdx.x];
  if (cN) atomicAdd(&st->hist_neg[threadIdx.x], cN);
  if (cP) atomicAdd(&st->hist_pos[threadIdx.x], cP);
}

__global__ void qupdate_kernel(QState* st, int round) {
  int shift = 24 - 8 * round;
  {
    unsigned cum = 0; unsigned r = (unsigned)st->rank_neg; unsigned pref = st->prefix_neg;
    for (int b = 0; b < 256; ++b) {
      unsigned c = st->hist_neg[b];
      if (r < cum + c) { pref |= ((unsigned)b) << shift; r -= cum; break; }
      cum += c;
    }
    st->prefix_neg = pref; st->rank_neg = (int)r;
  }
  {
    unsigned cum = 0; unsigned r = (unsigned)st->rank_pos; unsigned pref = st->prefix_pos;
    for (int b = 0; b < 256; ++b) {
      unsigned c = st->hist_pos[b];
      if (r < cum + c) { pref |= ((unsigned)b) << shift; r -= cum; break; }
      cum += c;
    }
    st->prefix_pos = pref; st->rank_pos = (int)r;
  }
  for (int i = 0; i < 256; ++i) { st->hist_neg[i] = 0u; st->hist_pos[i] = 0u; }
}

// min key strictly greater than the selected order statistic (v[k+1])
__global__ __launch_bounds__(256) void qvnext_kernel(const float* __restrict__ ep,
                                                     QState* st, int E) {
  __shared__ unsigned mn, mp;
  if (threadIdx.x == 0) { mn = 0xFFFFFFFFu; mp = 0xFFFFFFFFu; }
  __syncthreads();
  int e = blockIdx.x * blockDim.x + threadIdx.x;
  if (e < E) {
    unsigned pN = st->prefix_neg, pP = st->prefix_pos;
    float v = ep[e];
    unsigned key = f2key(v);
    if (v <= 0.f) { if (key > pN) atomicMin(&mn, key); }
    else          { if (key > pP) atomicMin(&mp, key); }
  }
  __syncthreads();
  if (threadIdx.x == 0) {
    if (mn != 0xFFFFFFFFu) atomicMin(&st->vnext_neg, mn);
    if (mp != 0xFFFFFFFFu) atomicMin(&st->vnext_pos, mp);
  }
}

__global__ void qfinal_kernel(QState* st) {
  {
    float v0 = key2f(st->prefix_neg);
    float v1 = (st->vnext_neg == 0xFFFFFFFFu) ? v0 : key2f(st->vnext_neg);
    float f = st->frac_neg;
    st->thr_neg = (f > 0.f) ? __fadd_rn(v0, __fmul_rn(f, __fsub_rn(v1, v0))) : v0;
  }
  {
    float v0 = key2f(st->prefix_pos);
    float v1 = (st->vnext_pos == 0xFFFFFFFFu) ? v0 : key2f(st->vnext_pos);
    float f = st->frac_pos;
    st->thr_pos = (f > 0.f) ? __fadd_rn(v0, __fmul_rn(f, __fsub_rn(v1, v0))) : v0;
  }
}

// class per edge + per-(class,dst) in-degree histogram (int atomics)
__global__ void cls_deg_kernel(const float* __restrict__ ep, const int* __restrict__ dst,
                               unsigned char* __restrict__ cls, int* __restrict__ deg,
                               const QState* __restrict__ st, int N, int E) {
  int e = blockIdx.x * blockDim.x + threadIdx.x;
  if (e >= E) return;
  float thrN = st->thr_neg, thrP = st->thr_pos;
  float v = ep[e];
  int c = (v > thrP) ? 0 : ((v < thrN) ? 2 : 1);
  cls[e] = (unsigned char)c;
  atomicAdd(&deg[c * N + dst[e]], 1);
}

// ---- 3-kernel exclusive scan over deg[3N] -> rowPtr/cursor, fused dinv ----
__global__ __launch_bounds__(256) void scan1_kernel(const int* __restrict__ deg,
                                                    int* __restrict__ bsum, int nRows) {
  __shared__ int s[256];
  int i = blockIdx.x * 256 + threadIdx.x;
  s[threadIdx.x] = (i < nRows) ? deg[i] : 0;
  __syncthreads();
  for (int off = 128; off > 0; off >>= 1) {
    if (threadIdx.x < off) s[threadIdx.x] += s[threadIdx.x + off];
    __syncthreads();
  }
  if (threadIdx.x == 0) bsum[blockIdx.x] = s[0];
}

__global__ __launch_bounds__(256) void scan2_kernel(int* __restrict__ bsum, int nb) {
  __shared__ int s[256];
  __shared__ int carry;
  if (threadIdx.x == 0) carry = 0;
  __syncthreads();
  for (int base = 0; base < nb; base += 256) {
    int i = base + threadIdx.x;
    int v = (i < nb) ? bsum[i] : 0;
    s[threadIdx.x] = v;
    __syncthreads();
    for (int off = 1; off < 256; off <<= 1) {
      int x = (threadIdx.x >= off) ? s[threadIdx.x - off] : 0;
      __syncthreads();
      s[threadIdx.x] += x;
      __syncthreads();
    }
    int excl = s[threadIdx.x] - v;
    int c = carry;
    if (i < nb) bsum[i] = c + excl;
    int tot = s[255];
    __syncthreads();
    if (threadIdx.x == 0) carry = c + tot;
    __syncthreads();
  }
}

__global__ __launch_bounds__(256) void scan3_kernel(const int* __restrict__ deg,
    const int* __restrict__ bsum, int* __restrict__ rowPtr, int* __restrict__ cursor,
    float* __restrict__ dinv, int nRows) {
  __shared__ int s[256];
  int i = blockIdx.x * 256 + threadIdx.x;
  int v = (i < nRows) ? deg[i] : 0;
  s[threadIdx.x] = v;
  __syncthreads();
  for (int off = 1; off < 256; off <<= 1) {
    int x = (threadIdx.x >= off) ? s[threadIdx.x - off] : 0;
    __syncthreads();
    s[threadIdx.x] += x;
    __syncthreads();
  }
  if (i < nRows) {
    int excl = bsum[blockIdx.x] + s[threadIdx.x] - v;
    rowPtr[i] = excl;
    cursor[i] = excl;
    dinv[i] = 1.f / sqrtf(fmaxf((float)v, 1.f));
    if (i == nRows - 1) rowPtr[nRows] = excl + v;
  }
}

// bucket edges into CSR slots (order within a row is irrelevant: sums)
__global__ void fill_kernel(const int* __restrict__ src, const int* __restrict__ dst,
                            const unsigned char* __restrict__ cls, int* __restrict__ cursor,
                            int* __restrict__ eSrc, int N, int E) {
  int e = blockIdx.x * blockDim.x + threadIdx.x;
  if (e >= E) return;
  int row = (int)cls[e] * N + dst[e];
  int p = atomicAdd(&cursor[row], 1);
  eSrc[p] = src[e];
}

// Gather propagation step. 16 lanes per destination node, float4 per lane.
// STEP 1: out = f - dinv * sum(f[src]*dinv[src])              (L1)
// STEP 2: out = ch*h + c1*f + c2*(f - dinv*sum(f[src]*dinv[src]))  (theta combo)
template<int STEP>
__global__ __launch_bounds__(256) void gather_kernel(const float* __restrict__ f,
    const float* __restrict__ h, float* __restrict__ outBuf,
    const int* __restrict__ rowPtr, const int* __restrict__ eSrc,
    const float* __restrict__ dinv, float ch, float c1, float c2, int N) {
  int n = blockIdx.x * 16 + (threadIdx.x >> 4);
  if (n >= N) return;
  int l = threadIdx.x & 15;
  int beg = rowPtr[n], end = rowPtr[n + 1];
  float4 acc = make_float4(0.f, 0.f, 0.f, 0.f);
  for (int e = beg; e < end; ++e) {
    int s = eSrc[e];
    float sc = dinv[s];
    float4 v = ((const float4*)f)[(size_t)s * 16 + l];
    acc.x += v.x * sc; acc.y += v.y * sc; acc.z += v.z * sc; acc.w += v.w * sc;
  }
  float di = dinv[n];
  size_t idx = (size_t)n * 16 + l;
  float4 fv = ((const float4*)f)[idx];
  float4 o;
  if (STEP == 1) {
    o.x = fv.x - di * acc.x; o.y = fv.y - di * acc.y;
    o.z = fv.z - di * acc.z; o.w = fv.w - di * acc.w;
  } else {
    float4 hv = ((const float4*)h)[idx];
    o.x = ch * hv.x + c1 * fv.x + c2 * (fv.x - di * acc.x);
    o.y = ch * hv.y + c1 * fv.y + c2 * (fv.y - di * acc.y);
    o.z = ch * hv.z + c1 * fv.z + c2 * (fv.z - di * acc.z);
    o.w = ch * hv.w + c1 * fv.w + c2 * (fv.w - di * acc.w);
  }
  ((float4*)outBuf)[idx] = o;
}

// C[N,64] = A[N,K] @ W[K,64] (+ C if accum) (+bias, relu if finish)
template<int K>
__global__ __launch_bounds__(256) void gemm64_kernel(const float* __restrict__ A,
    const float* __restrict__ W, const float* __restrict__ bias,
    float* C, int N, int accum, int finish) {
  __shared__ float As[64][65];                 // [k][row], +1 pad kills store conflicts
  __shared__ __align__(16) float Ws[64][64];   // [k][col]
  const int tid = threadIdx.x;
  const int tx = tid & 15;   // col quad
  const int ty = tid >> 4;   // row quad
  const int rowBase = blockIdx.x * 64;
  float acc[4][4] = {};
  for (int kc = 0; kc < K; kc += 64) {
#pragma unroll
    for (int i = 0; i < 16; ++i) {
      int idx = tid + i * 256;
      int r = idx >> 6, c = idx & 63;
      int row = rowBase + r;
      float v = 0.f;
      if (row < N) v = A[(size_t)row * K + kc + c];
      As[c][r] = v;
    }
#pragma unroll
    for (int i = 0; i < 16; ++i) {
      int idx = tid + i * 256;
      int r = idx >> 6, c = idx & 63;
      Ws[r][c] = W[(size_t)(kc + r) * 64 + c];
    }
    __syncthreads();
#pragma unroll
    for (int k = 0; k < 64; ++k) {
      float a0 = As[k][ty * 4 + 0];
      float a1 = As[k][ty * 4 + 1];
      float a2 = As[k][ty * 4 + 2];
      float a3 = As[k][ty * 4 + 3];
      float4 wv = *(const float4*)&Ws[k][tx * 4];
      acc[0][0] += a0 * wv.x; acc[0][1] += a0 * wv.y; acc[0][2] += a0 * wv.z; acc[0][3] += a0 * wv.w;
      acc[1][0] += a1 * wv.x; acc[1][1] += a1 * wv.y; acc[1][2] += a1 * wv.z; acc[1][3] += a1 * wv.w;
      acc[2][0] += a2 * wv.x; acc[2][1] += a2 * wv.y; acc[2][2] += a2 * wv.z; acc[2][3] += a2 * wv.w;
      acc[3][0] += a3 * wv.x; acc[3][1] += a3 * wv.y; acc[3][2] += a3 * wv.z; acc[3][3] += a3 * wv.w;
    }
    __syncthreads();
  }
  float4 bv = make_float4(0.f, 0.f, 0.f, 0.f);
  if (finish) bv = *(const float4*)&bias[tx * 4];
#pragma unroll
  for (int i = 0; i < 4; ++i) {
    int row = rowBase + ty * 4 + i;
    if (row >= N) continue;
    float* cp = C + (size_t)row * 64 + tx * 4;
    float4 o = make_float4(acc[i][0], acc[i][1], acc[i][2], acc[i][3]);
    if (accum) {
      float4 p = *(const float4*)cp;
      o.x += p.x; o.y += p.y; o.z += p.z; o.w += p.w;
    }
    if (finish) {
      o.x = fmaxf(o.x + bv.x, 0.f);
      o.y = fmaxf(o.y + bv.y, 0.f);
      o.z = fmaxf(o.z + bv.z, 0.f);
      o.w = fmaxf(o.w + bv.w, 0.f);
    }
    *(float4*)cp = o;
  }
}

extern "C" void kernel_launch(void* const* d_in, const int* in_sizes, int n_in,
                              void* d_out, int out_size, void* d_ws, size_t ws_size,
                              hipStream_t stream) {
  const float* feat = (const float*)d_in[0];
  const float* ep   = (const float*)d_in[1];
  const int*   src  = (const int*)d_in[2];
  const int*   dst  = (const int*)d_in[3];
  const float* W1   = (const float*)d_in[4];
  const float* b1   = (const float*)d_in[5];
  const float* W2   = (const float*)d_in[6];
  const float* b2   = (const float*)d_in[7];
  const float* W3   = (const float*)d_in[8];
  const float* b3   = (const float*)d_in[9];
  float* out = (float*)d_out;
  const int N = in_sizes[0] / 128;
  const int E = in_sizes[1];
  const int nRows = 3 * N;
  const int nb = (nRows + 255) / 256;

  char* w = (char*)d_ws;
  size_t off = 0;
  QState* st = (QState*)(w + off);           off += WS_ALIGN(sizeof(QState));
  int* deg = (int*)(w + off);                off += WS_ALIGN((size_t)nRows * 4);
  const size_t zeroBytes = off;              // state + deg zeroed together
  int* rowPtr = (int*)(w + off);             off += WS_ALIGN((size_t)(nRows + 1) * 4);
  int* cursor = (int*)(w + off);             off += WS_ALIGN((size_t)nRows * 4);
  float* dinv = (float*)(w + off);           off += WS_ALIGN((size_t)nRows * 4);
  int* bsum = (int*)(w + off);               off += WS_ALIGN((size_t)nb * 4);
  unsigned char* cls = (unsigned char*)(w + off); off += WS_ALIGN((size_t)E);
  int* eSrc = (int*)(w + off);               off += WS_ALIGN((size_t)E * 4);
  float* h   = (float*)(w + off);            off += (size_t)N * 64 * 4;
  float* L1  = (float*)(w + off);            off += (size_t)N * 64 * 4;
  float* tmp = (float*)(w + off);            off += (size_t)N * 64 * 4;
  (void)ws_size; (void)n_in; (void)out_size;

  hipMemsetAsync(d_ws, 0, zeroBytes, stream);

  const int eb = (E + 255) / 256;
  qcount_kernel<<<eb, 256, 0, stream>>>(ep, st, E);
  qinit_kernel<<<1, 1, 0, stream>>>(st);
  for (int r = 0; r < 4; ++r) {
    qhist_kernel<<<512, 256, 0, stream>>>(ep, st, E, r);
    qupdate_kernel<<<1, 1, 0, stream>>>(st, r);
  }
  qvnext_kernel<<<eb, 256, 0, stream>>>(ep, st, E);
  qfinal_kernel<<<1, 1, 0, stream>>>(st);

  cls_deg_kernel<<<eb, 256, 0, stream>>>(ep, dst, cls, deg, st, N, E);
  scan1_kernel<<<nb, 256, 0, stream>>>(deg, bsum, nRows);
  scan2_kernel<<<1, 256, 0, stream>>>(bsum, nb);
  scan3_kernel<<<nb, 256, 0, stream>>>(deg, bsum, rowPtr, cursor, dinv, nRows);
  fill_kernel<<<eb, 256, 0, stream>>>(src, dst, cls, cursor, eSrc, N, E);

  const int gb = (N + 63) / 64;
  gemm64_kernel<128><<<gb, 256, 0, stream>>>(feat, W1, b1, tmp, N, 0, 1); // h1
  gemm64_kernel<64><<<gb, 256, 0, stream>>>(tmp, W2, b2, h, N, 0, 1);     // h

  // theta rows: pos=T[2], unk=T[1], neg=T[0]; combo = ch*h + c1*L1 + c2*L2
  const float chArr[3] = {0.f, 0.f, 3.f};
  const float c1Arr[3] = {0.f, 3.f, -3.f};
  const float c2Arr[3] = {0.75f, -1.5f, 0.75f};
  const int ggrid = (N + 15) / 16;
  for (int c = 0; c < 3; ++c) {
    const int* rp = rowPtr + (size_t)c * N;
    const float* dv = dinv + (size_t)c * N;
    gather_kernel<1><<<ggrid, 256, 0, stream>>>(h, nullptr, L1, rp, eSrc, dv,
                                                0.f, 0.f, 0.f, N);
    gather_kernel<2><<<ggrid, 256, 0, stream>>>(L1, h, tmp, rp, eSrc, dv,
                                                chArr[c], c1Arr[c], c2Arr[c], N);
    gemm64_kernel<64><<<gb, 256, 0, stream>>>(tmp, W3 + (size_t)c * 64 * 64, b3, out,
                                              N, c > 0 ? 1 : 0, c == 2 ? 1 : 0);
  }
}

// Round 3
// 1009.860 us; speedup vs baseline: 4.3798x; 1.8478x over previous
//
#include <hip/hip_runtime.h>
#include <cstdint>
#include <cstddef>

// ---------------------------------------------------------------------------
// GraphPartitionModule: quantile-masked 3-way edge partition -> per-class
// normalized-Laplacian powers (D=2) -> theta combination -> MLP head.
//
// R3: quantile phase rebuilt without contended atomics (qcount folded into
// round-0 radix histogram; qvnext uses register/wave-min reduction).
// Propagation fused: one 3N-row gather per step, combo written as [N,192],
// single K=192 output GEMM (ws_size-guarded fallback to R2 path).
// ---------------------------------------------------------------------------

#define WS_ALIGN(x) (((x) + 255) & ~(size_t)255)

struct QState {
  unsigned n_neg, n_pos;
  unsigned prefix_neg, prefix_pos;
  int rank_neg, rank_pos;
  float frac_neg, frac_pos;
  unsigned vnext_neg, vnext_pos;
  float thr_neg, thr_pos;
  int dup_neg, dup_pos;
  unsigned hist_neg[256];
  unsigned hist_pos[256];
};

// monotone float<->uint key mapping (ascending float == ascending key)
__device__ __forceinline__ unsigned f2key(float v) {
  unsigned u = __float_as_uint(v);
  return (u & 0x80000000u) ? ~u : (u | 0x80000000u);
}
__device__ __forceinline__ float key2f(unsigned k) {
  unsigned u = (k & 0x80000000u) ? (k ^ 0x80000000u) : ~k;
  return __uint_as_float(u);
}

__global__ __launch_bounds__(256) void qhist_kernel(const float* __restrict__ ep,
                                                    QState* st, int E, int round) {
  __shared__ unsigned hN[256], hP[256];
  hN[threadIdx.x] = 0u; hP[threadIdx.x] = 0u;
  __syncthreads();
  int shift = 24 - 8 * round;
  unsigned maskHi = 0u;
  if (round > 0) maskHi = 0xFFFFFFFFu << (shift + 8);
  unsigned pN = st->prefix_neg & maskHi;
  unsigned pP = st->prefix_pos & maskHi;
  int stride = gridDim.x * blockDim.x;
  for (int e = blockIdx.x * blockDim.x + threadIdx.x; e < E; e += stride) {
    float v = ep[e];
    unsigned key = f2key(v);
    if (v <= 0.f) {
      if ((key & maskHi) == pN) atomicAdd(&hN[(key >> shift) & 255], 1u);
    } else {
      if ((key & maskHi) == pP) atomicAdd(&hP[(key >> shift) & 255], 1u);
    }
  }
  __syncthreads();
  unsigned cN = hN[threadIdx.x], cP = hP[threadIdx.x];
  if (cN) atomicAdd(&st->hist_neg[threadIdx.x], cN);
  if (cP) atomicAdd(&st->hist_pos[threadIdx.x], cP);
}

// After round-0 hist: n_neg/n_pos = hist sums; compute ranks (f32 semantics
// matching jnp.nanquantile), do round-0 bucket select, re-zero hists.
__global__ __launch_bounds__(256) void qinit_kernel(QState* st) {
  __shared__ unsigned sN[256], sP[256], rN_[256], rP_[256];
  int t = threadIdx.x;
  unsigned hn = st->hist_neg[t], hp = st->hist_pos[t];
  sN[t] = hn; sP[t] = hp; rN_[t] = hn; rP_[t] = hp;
  __syncthreads();
  for (int off = 128; off > 0; off >>= 1) {
    if (t < off) { rN_[t] += rN_[t + off]; rP_[t] += rP_[t + off]; }
    __syncthreads();
  }
  if (t == 0) {
    unsigned nN = rN_[0], nP = rP_[0];
    st->n_neg = nN; st->n_pos = nP;
    float idxN = __fmul_rn(0.2f, (float)(nN - 1));
    float lowN = floorf(idxN);
    unsigned rn = (unsigned)(int)lowN;
    st->frac_neg = __fsub_rn(idxN, lowN);
    float idxP = __fmul_rn(0.8f, (float)(nP - 1));
    float lowP = floorf(idxP);
    unsigned rp = (unsigned)(int)lowP;
    st->frac_pos = __fsub_rn(idxP, lowP);
    st->vnext_neg = 0xFFFFFFFFu; st->vnext_pos = 0xFFFFFFFFu;
    {
      unsigned cum = 0, pref = 0;
      for (int b = 0; b < 256; ++b) {
        unsigned c = sN[b];
        if (rn < cum + c) { pref = ((unsigned)b) << 24; rn -= cum; break; }
        cum += c;
      }
      st->prefix_neg = pref; st->rank_neg = (int)rn;
    }
    {
      unsigned cum = 0, pref = 0;
      for (int b = 0; b < 256; ++b) {
        unsigned c = sP[b];
        if (rp < cum + c) { pref = ((unsigned)b) << 24; rp -= cum; break; }
        cum += c;
      }
      st->prefix_pos = pref; st->rank_pos = (int)rp;
    }
  }
  st->hist_neg[t] = 0u; st->hist_pos[t] = 0u;
}

__global__ void qupdate_kernel(QState* st, int round) {
  int shift = 24 - 8 * round;
  {
    unsigned cum = 0; unsigned r = (unsigned)st->rank_neg; unsigned pref = st->prefix_neg;
    for (int b = 0; b < 256; ++b) {
      unsigned c = st->hist_neg[b];
      if (r < cum + c) {
        pref |= ((unsigned)b) << shift; r -= cum;
        if (round == 3) st->dup_neg = (r + 1 < c) ? 1 : 0;
        break;
      }
      cum += c;
    }
    st->prefix_neg = pref; st->rank_neg = (int)r;
  }
  {
    unsigned cum = 0; unsigned r = (unsigned)st->rank_pos; unsigned pref = st->prefix_pos;
    for (int b = 0; b < 256; ++b) {
      unsigned c = st->hist_pos[b];
      if (r < cum + c) {
        pref |= ((unsigned)b) << shift; r -= cum;
        if (round == 3) st->dup_pos = (r + 1 < c) ? 1 : 0;
        break;
      }
      cum += c;
    }
    st->prefix_pos = pref; st->rank_pos = (int)r;
  }
  for (int i = 0; i < 256; ++i) { st->hist_neg[i] = 0u; st->hist_pos[i] = 0u; }
}

// min key strictly greater than the selected order statistic (register+wave min)
__global__ __launch_bounds__(256) void qvnext_kernel(const float* __restrict__ ep,
                                                     QState* st, int E) {
  unsigned pN = st->prefix_neg, pP = st->prefix_pos;
  unsigned mn = 0xFFFFFFFFu, mp = 0xFFFFFFFFu;
  int stride = gridDim.x * blockDim.x;
  for (int e = blockIdx.x * blockDim.x + threadIdx.x; e < E; e += stride) {
    float v = ep[e];
    unsigned key = f2key(v);
    if (v <= 0.f) { if (key > pN && key < mn) mn = key; }
    else          { if (key > pP && key < mp) mp = key; }
  }
#pragma unroll
  for (int off = 32; off > 0; off >>= 1) {
    unsigned a = (unsigned)__shfl_down((int)mn, off);
    unsigned b = (unsigned)__shfl_down((int)mp, off);
    mn = min(mn, a); mp = min(mp, b);
  }
  __shared__ unsigned wN[4], wP[4];
  int wid = threadIdx.x >> 6, lane = threadIdx.x & 63;
  if (lane == 0) { wN[wid] = mn; wP[wid] = mp; }
  __syncthreads();
  if (threadIdx.x == 0) {
    unsigned a = min(min(wN[0], wN[1]), min(wN[2], wN[3]));
    unsigned b = min(min(wP[0], wP[1]), min(wP[2], wP[3]));
    if (a != 0xFFFFFFFFu) atomicMin(&st->vnext_neg, a);
    if (b != 0xFFFFFFFFu) atomicMin(&st->vnext_pos, b);
  }
}

__global__ void qfinal_kernel(QState* st) {
  {
    float v0 = key2f(st->prefix_neg);
    float v1 = (st->dup_neg || st->vnext_neg == 0xFFFFFFFFu) ? v0 : key2f(st->vnext_neg);
    float f = st->frac_neg;
    st->thr_neg = (f > 0.f) ? __fadd_rn(v0, __fmul_rn(f, __fsub_rn(v1, v0))) : v0;
  }
  {
    float v0 = key2f(st->prefix_pos);
    float v1 = (st->dup_pos || st->vnext_pos == 0xFFFFFFFFu) ? v0 : key2f(st->vnext_pos);
    float f = st->frac_pos;
    st->thr_pos = (f > 0.f) ? __fadd_rn(v0, __fmul_rn(f, __fsub_rn(v1, v0))) : v0;
  }
}

// class per edge + per-(class,dst) in-degree histogram (int atomics)
__global__ void cls_deg_kernel(const float* __restrict__ ep, const int* __restrict__ dst,
                               unsigned char* __restrict__ cls, int* __restrict__ deg,
                               const QState* __restrict__ st, int N, int E) {
  int e = blockIdx.x * blockDim.x + threadIdx.x;
  if (e >= E) return;
  float thrN = st->thr_neg, thrP = st->thr_pos;
  float v = ep[e];
  int c = (v > thrP) ? 0 : ((v < thrN) ? 2 : 1);
  cls[e] = (unsigned char)c;
  atomicAdd(&deg[c * N + dst[e]], 1);
}

// ---- 3-kernel exclusive scan over deg[3N] -> rowPtr/cursor, fused dinv ----
__global__ __launch_bounds__(256) void scan1_kernel(const int* __restrict__ deg,
                                                    int* __restrict__ bsum, int nRows) {
  __shared__ int s[256];
  int i = blockIdx.x * 256 + threadIdx.x;
  s[threadIdx.x] = (i < nRows) ? deg[i] : 0;
  __syncthreads();
  for (int off = 128; off > 0; off >>= 1) {
    if (threadIdx.x < off) s[threadIdx.x] += s[threadIdx.x + off];
    __syncthreads();
  }
  if (threadIdx.x == 0) bsum[blockIdx.x] = s[0];
}

__global__ __launch_bounds__(256) void scan2_kernel(int* __restrict__ bsum, int nb) {
  __shared__ int s[256];
  __shared__ int carry;
  if (threadIdx.x == 0) carry = 0;
  __syncthreads();
  for (int base = 0; base < nb; base += 256) {
    int i = base + threadIdx.x;
    int v = (i < nb) ? bsum[i] : 0;
    s[threadIdx.x] = v;
    __syncthreads();
    for (int off = 1; off < 256; off <<= 1) {
      int x = (threadIdx.x >= off) ? s[threadIdx.x - off] : 0;
      __syncthreads();
      s[threadIdx.x] += x;
      __syncthreads();
    }
    int excl = s[threadIdx.x] - v;
    int c = carry;
    if (i < nb) bsum[i] = c + excl;
    int tot = s[255];
    __syncthreads();
    if (threadIdx.x == 0) carry = c + tot;
    __syncthreads();
  }
}

__global__ __launch_bounds__(256) void scan3_kernel(const int* __restrict__ deg,
    const int* __restrict__ bsum, int* __restrict__ rowPtr, int* __restrict__ cursor,
    float* __restrict__ dinv, int nRows) {
  __shared__ int s[256];
  int i = blockIdx.x * 256 + threadIdx.x;
  int v = (i < nRows) ? deg[i] : 0;
  s[threadIdx.x] = v;
  __syncthreads();
  for (int off = 1; off < 256; off <<= 1) {
    int x = (threadIdx.x >= off) ? s[threadIdx.x - off] : 0;
    __syncthreads();
    s[threadIdx.x] += x;
    __syncthreads();
  }
  if (i < nRows) {
    int excl = bsum[blockIdx.x] + s[threadIdx.x] - v;
    rowPtr[i] = excl;
    cursor[i] = excl;
    dinv[i] = 1.f / sqrtf(fmaxf((float)v, 1.f));
    if (i == nRows - 1) rowPtr[nRows] = excl + v;
  }
}

// bucket edges into CSR slots (order within a row is irrelevant: sums)
__global__ void fill_kernel(const int* __restrict__ src, const int* __restrict__ dst,
                            const unsigned char* __restrict__ cls, int* __restrict__ cursor,
                            int* __restrict__ eSrc, int N, int E) {
  int e = blockIdx.x * blockDim.x + threadIdx.x;
  if (e >= E) return;
  int row = (int)cls[e] * N + dst[e];
  int p = atomicAdd(&cursor[row], 1);
  eSrc[p] = src[e];
}

// Fused gather over all 3N (class,node) rows. 16 lanes per row, float4/lane.
// STEP 1: f = h [N,64] -> out L1all [3N,64]
// STEP 2: f = L1all [3N,64] -> out combo [N,192] column block c
template<int STEP>
__global__ __launch_bounds__(256) void gather3_kernel(const float* __restrict__ f,
    const float* __restrict__ h, float* __restrict__ outBuf,
    const int* __restrict__ rowPtr, const int* __restrict__ eSrc,
    const float* __restrict__ dinv, int N, int nRows) {
  int r = blockIdx.x * 16 + (threadIdx.x >> 4);
  if (r >= nRows) return;
  int l = threadIdx.x & 15;
  int c = r / N;
  int n = r - c * N;
  int beg = rowPtr[r], end = rowPtr[r + 1];
  int srcOfs = (STEP == 1) ? 0 : c * N;   // L1all rows are class-offset
  float4 acc = make_float4(0.f, 0.f, 0.f, 0.f);
  for (int e = beg; e < end; ++e) {
    int s = eSrc[e];
    float sc = dinv[c * N + s];
    float4 v = ((const float4*)f)[(size_t)(srcOfs + s) * 16 + l];
    acc.x += v.x * sc; acc.y += v.y * sc; acc.z += v.z * sc; acc.w += v.w * sc;
  }
  float di = dinv[r];
  if (STEP == 1) {
    float4 fv = ((const float4*)f)[(size_t)n * 16 + l];
    float4 o;
    o.x = fv.x - di * acc.x; o.y = fv.y - di * acc.y;
    o.z = fv.z - di * acc.z; o.w = fv.w - di * acc.w;
    ((float4*)outBuf)[(size_t)r * 16 + l] = o;
  } else {
    const float chA[3] = {0.f, 0.f, 3.f};
    const float c1A[3] = {0.f, 3.f, -3.f};
    const float c2A[3] = {0.75f, -1.5f, 0.75f};
    float ch = chA[c], c1 = c1A[c], c2 = c2A[c];
    float4 fv = ((const float4*)f)[(size_t)r * 16 + l];
    float4 hv = ((const float4*)h)[(size_t)n * 16 + l];
    float4 o;
    o.x = ch * hv.x + c1 * fv.x + c2 * (fv.x - di * acc.x);
    o.y = ch * hv.y + c1 * fv.y + c2 * (fv.y - di * acc.y);
    o.z = ch * hv.z + c1 * fv.z + c2 * (fv.z - di * acc.z);
    o.w = ch * hv.w + c1 * fv.w + c2 * (fv.w - di * acc.w);
    ((float4*)outBuf)[(size_t)n * 48 + c * 16 + l] = o;
  }
}

// Per-class gather (fallback path, R2-proven)
template<int STEP>
__global__ __launch_bounds__(256) void gather_kernel(const float* __restrict__ f,
    const float* __restrict__ h, float* __restrict__ outBuf,
    const int* __restrict__ rowPtr, const int* __restrict__ eSrc,
    const float* __restrict__ dinv, float ch, float c1, float c2, int N) {
  int n = blockIdx.x * 16 + (threadIdx.x >> 4);
  if (n >= N) return;
  int l = threadIdx.x & 15;
  int beg = rowPtr[n], end = rowPtr[n + 1];
  float4 acc = make_float4(0.f, 0.f, 0.f, 0.f);
  for (int e = beg; e < end; ++e) {
    int s = eSrc[e];
    float sc = dinv[s];
    float4 v = ((const float4*)f)[(size_t)s * 16 + l];
    acc.x += v.x * sc; acc.y += v.y * sc; acc.z += v.z * sc; acc.w += v.w * sc;
  }
  float di = dinv[n];
  size_t idx = (size_t)n * 16 + l;
  float4 fv = ((const float4*)f)[idx];
  float4 o;
  if (STEP == 1) {
    o.x = fv.x - di * acc.x; o.y = fv.y - di * acc.y;
    o.z = fv.z - di * acc.z; o.w = fv.w - di * acc.w;
  } else {
    float4 hv = ((const float4*)h)[idx];
    o.x = ch * hv.x + c1 * fv.x + c2 * (fv.x - di * acc.x);
    o.y = ch * hv.y + c1 * fv.y + c2 * (fv.y - di * acc.y);
    o.z = ch * hv.z + c1 * fv.z + c2 * (fv.z - di * acc.z);
    o.w = ch * hv.w + c1 * fv.w + c2 * (fv.w - di * acc.w);
  }
  ((float4*)outBuf)[idx] = o;
}

// C[N,64] = A[N,K] @ W[K,64] (+ C if accum) (+bias, relu if finish)
template<int K>
__global__ __launch_bounds__(256) void gemm64_kernel(const float* __restrict__ A,
    const float* __restrict__ W, const float* __restrict__ bias,
    float* C, int N, int accum, int finish) {
  __shared__ float As[64][65];
  __shared__ __align__(16) float Ws[64][64];
  const int tid = threadIdx.x;
  const int tx = tid & 15;
  const int ty = tid >> 4;
  const int rowBase = blockIdx.x * 64;
  float acc[4][4] = {};
  for (int kc = 0; kc < K; kc += 64) {
#pragma unroll
    for (int i = 0; i < 16; ++i) {
      int idx = tid + i * 256;
      int r = idx >> 6, c = idx & 63;
      int row = rowBase + r;
      float v = 0.f;
      if (row < N) v = A[(size_t)row * K + kc + c];
      As[c][r] = v;
    }
#pragma unroll
    for (int i = 0; i < 16; ++i) {
      int idx = tid + i * 256;
      int r = idx >> 6, c = idx & 63;
      Ws[r][c] = W[(size_t)(kc + r) * 64 + c];
    }
    __syncthreads();
#pragma unroll
    for (int k = 0; k < 64; ++k) {
      float a0 = As[k][ty * 4 + 0];
      float a1 = As[k][ty * 4 + 1];
      float a2 = As[k][ty * 4 + 2];
      float a3 = As[k][ty * 4 + 3];
      float4 wv = *(const float4*)&Ws[k][tx * 4];
      acc[0][0] += a0 * wv.x; acc[0][1] += a0 * wv.y; acc[0][2] += a0 * wv.z; acc[0][3] += a0 * wv.w;
      acc[1][0] += a1 * wv.x; acc[1][1] += a1 * wv.y; acc[1][2] += a1 * wv.z; acc[1][3] += a1 * wv.w;
      acc[2][0] += a2 * wv.x; acc[2][1] += a2 * wv.y; acc[2][2] += a2 * wv.z; acc[2][3] += a2 * wv.w;
      acc[3][0] += a3 * wv.x; acc[3][1] += a3 * wv.y; acc[3][2] += a3 * wv.z; acc[3][3] += a3 * wv.w;
    }
    __syncthreads();
  }
  float4 bv = make_float4(0.f, 0.f, 0.f, 0.f);
  if (finish) bv = *(const float4*)&bias[tx * 4];
#pragma unroll
  for (int i = 0; i < 4; ++i) {
    int row = rowBase + ty * 4 + i;
    if (row >= N) continue;
    float* cp = C + (size_t)row * 64 + tx * 4;
    float4 o = make_float4(acc[i][0], acc[i][1], acc[i][2], acc[i][3]);
    if (accum) {
      float4 p = *(const float4*)cp;
      o.x += p.x; o.y += p.y; o.z += p.z; o.w += p.w;
    }
    if (finish) {
      o.x = fmaxf(o.x + bv.x, 0.f);
      o.y = fmaxf(o.y + bv.y, 0.f);
      o.z = fmaxf(o.z + bv.z, 0.f);
      o.w = fmaxf(o.w + bv.w, 0.f);
    }
    *(float4*)cp = o;
  }
}

extern "C" void kernel_launch(void* const* d_in, const int* in_sizes, int n_in,
                              void* d_out, int out_size, void* d_ws, size_t ws_size,
                              hipStream_t stream) {
  const float* feat = (const float*)d_in[0];
  const float* ep   = (const float*)d_in[1];
  const int*   src  = (const int*)d_in[2];
  const int*   dst  = (const int*)d_in[3];
  const float* W1   = (const float*)d_in[4];
  const float* b1   = (const float*)d_in[5];
  const float* W2   = (const float*)d_in[6];
  const float* b2   = (const float*)d_in[7];
  const float* W3   = (const float*)d_in[8];
  const float* b3   = (const float*)d_in[9];
  float* out = (float*)d_out;
  const int N = in_sizes[0] / 128;
  const int E = in_sizes[1];
  const int nRows = 3 * N;
  const int nb = (nRows + 255) / 256;

  char* w = (char*)d_ws;
  size_t off = 0;
  QState* st = (QState*)(w + off);           off += WS_ALIGN(sizeof(QState));
  int* deg = (int*)(w + off);                off += WS_ALIGN((size_t)nRows * 4);
  const size_t zeroBytes = off;              // state + deg zeroed together
  int* rowPtr = (int*)(w + off);             off += WS_ALIGN((size_t)(nRows + 1) * 4);
  int* cursor = (int*)(w + off);             off += WS_ALIGN((size_t)nRows * 4);
  float* dinv = (float*)(w + off);           off += WS_ALIGN((size_t)nRows * 4);
  int* bsum = (int*)(w + off);               off += WS_ALIGN((size_t)nb * 4);
  unsigned char* cls = (unsigned char*)(w + off); off += WS_ALIGN((size_t)E);
  int* eSrc = (int*)(w + off);               off += WS_ALIGN((size_t)E * 4);
  float* h   = (float*)(w + off);            off += (size_t)N * 64 * 4;
  // fused: L1all [3N,64] + combo [N,192]; fallback: L1 [N,64] + tmp [N,64]
  const size_t fusedNeed = off + (size_t)nRows * 64 * 4 + (size_t)N * 192 * 4;
  const bool fused = (ws_size >= fusedNeed);
  float* L1all = (float*)(w + off);          // also temp for h1 (used pre-gather)
  float* combo = fused ? (float*)(w + off + (size_t)nRows * 64 * 4)
                       : (float*)(w + off + (size_t)N * 64 * 4);
  (void)n_in; (void)out_size;

  hipMemsetAsync(d_ws, 0, zeroBytes, stream);

  const int eb = (E + 255) / 256;
  qhist_kernel<<<512, 256, 0, stream>>>(ep, st, E, 0);
  qinit_kernel<<<1, 256, 0, stream>>>(st);
  for (int r = 1; r < 4; ++r) {
    qhist_kernel<<<512, 256, 0, stream>>>(ep, st, E, r);
    qupdate_kernel<<<1, 1, 0, stream>>>(st, r);
  }
  qvnext_kernel<<<512, 256, 0, stream>>>(ep, st, E);
  qfinal_kernel<<<1, 1, 0, stream>>>(st);

  cls_deg_kernel<<<eb, 256, 0, stream>>>(ep, dst, cls, deg, st, N, E);
  scan1_kernel<<<nb, 256, 0, stream>>>(deg, bsum, nRows);
  scan2_kernel<<<1, 256, 0, stream>>>(bsum, nb);
  scan3_kernel<<<nb, 256, 0, stream>>>(deg, bsum, rowPtr, cursor, dinv, nRows);
  fill_kernel<<<eb, 256, 0, stream>>>(src, dst, cls, cursor, eSrc, N, E);

  const int gb = (N + 63) / 64;
  gemm64_kernel<128><<<gb, 256, 0, stream>>>(feat, W1, b1, L1all, N, 0, 1); // h1 (temp)
  gemm64_kernel<64><<<gb, 256, 0, stream>>>(L1all, W2, b2, h, N, 0, 1);     // h

  if (fused) {
    const int g3 = (nRows + 15) / 16;
    gather3_kernel<1><<<g3, 256, 0, stream>>>(h, h, L1all, rowPtr, eSrc, dinv, N, nRows);
    gather3_kernel<2><<<g3, 256, 0, stream>>>(L1all, h, combo, rowPtr, eSrc, dinv, N, nRows);
    gemm64_kernel<192><<<gb, 256, 0, stream>>>(combo, W3, b3, out, N, 0, 1);
  } else {
    const float chArr[3] = {0.f, 0.f, 3.f};
    const float c1Arr[3] = {0.f, 3.f, -3.f};
    const float c2Arr[3] = {0.75f, -1.5f, 0.75f};
    const int ggrid = (N + 15) / 16;
    float* L1 = L1all;
    for (int c = 0; c < 3; ++c) {
      const int* rp = rowPtr + (size_t)c * N;
      const float* dv = dinv + (size_t)c * N;
      gather_kernel<1><<<ggrid, 256, 0, stream>>>(h, nullptr, L1, rp, eSrc, dv,
                                                  0.f, 0.f, 0.f, N);
      gather_kernel<2><<<ggrid, 256, 0, stream>>>(L1, h, combo, rp, eSrc, dv,
                                                  chArr[c], c1Arr[c], c2Arr[c], N);
      gemm64_kernel<64><<<gb, 256, 0, stream>>>(combo, W3 + (size_t)c * 64 * 64, b3, out,
                                                N, c > 0 ? 1 : 0, c == 2 ? 1 : 0);
    }
  }
}

// Round 4
// 685.182 us; speedup vs baseline: 6.4552x; 1.4739x over previous
//
#include <hip/hip_runtime.h>
#include <cstdint>
#include <cstddef>

// ---------------------------------------------------------------------------
// GraphPartitionModule: quantile-masked 3-way edge partition -> per-class
// normalized-Laplacian powers (D=2) -> theta combination -> MLP head.
//
// R4: all GEMMs moved to bf16 MFMA (16x16x32), fp32 accumulate.
//  - A tiles staged fp32->bf16 in LDS (row stride 40 shorts: 16B-aligned,
//    <=2-way bank aliasing which is free on gfx950).
//  - W pre-transposed to bf16 Wt[col][k] once per call (tiny, L1-resident),
//    B-fragments are single 16B coalesced global loads.
//  - bias+relu+accum fused in epilogue (C/D map: col=lane&15, row=quad*4+reg).
// Quantile radix-select + CSR gather machinery unchanged from R3.
// ---------------------------------------------------------------------------

#define WS_ALIGN(x) (((x) + 255) & ~(size_t)255)

typedef __attribute__((ext_vector_type(8))) short short8;
typedef __attribute__((ext_vector_type(4))) float floatx4;

struct QState {
  unsigned n_neg, n_pos;
  unsigned prefix_neg, prefix_pos;
  int rank_neg, rank_pos;
  float frac_neg, frac_pos;
  unsigned vnext_neg, vnext_pos;
  float thr_neg, thr_pos;
  int dup_neg, dup_pos;
  unsigned hist_neg[256];
  unsigned hist_pos[256];
};

// monotone float<->uint key mapping (ascending float == ascending key)
__device__ __forceinline__ unsigned f2key(float v) {
  unsigned u = __float_as_uint(v);
  return (u & 0x80000000u) ? ~u : (u | 0x80000000u);
}
__device__ __forceinline__ float key2f(unsigned k) {
  unsigned u = (k & 0x80000000u) ? (k ^ 0x80000000u) : ~k;
  return __uint_as_float(u);
}

__device__ __forceinline__ short bf16rn(float x) {   // fp32 -> bf16 RNE
  unsigned u = __float_as_uint(x);
  u = (u + 0x7FFFu + ((u >> 16) & 1u)) >> 16;
  return (short)u;
}

__global__ __launch_bounds__(256) void qhist_kernel(const float* __restrict__ ep,
                                                    QState* st, int E, int round) {
  __shared__ unsigned hN[256], hP[256];
  hN[threadIdx.x] = 0u; hP[threadIdx.x] = 0u;
  __syncthreads();
  int shift = 24 - 8 * round;
  unsigned maskHi = 0u;
  if (round > 0) maskHi = 0xFFFFFFFFu << (shift + 8);
  unsigned pN = st->prefix_neg & maskHi;
  unsigned pP = st->prefix_pos & maskHi;
  int stride = gridDim.x * blockDim.x;
  for (int e = blockIdx.x * blockDim.x + threadIdx.x; e < E; e += stride) {
    float v = ep[e];
    unsigned key = f2key(v);
    if (v <= 0.f) {
      if ((key & maskHi) == pN) atomicAdd(&hN[(key >> shift) & 255], 1u);
    } else {
      if ((key & maskHi) == pP) atomicAdd(&hP[(key >> shift) & 255], 1u);
    }
  }
  __syncthreads();
  unsigned cN = hN[threadIdx.x], cP = hP[threadIdx.x];
  if (cN) atomicAdd(&st->hist_neg[threadIdx.x], cN);
  if (cP) atomicAdd(&st->hist_pos[threadIdx.x], cP);
}

// After round-0 hist: n_neg/n_pos = hist sums; compute ranks (f32 semantics
// matching jnp.nanquantile), do round-0 bucket select, re-zero hists.
__global__ __launch_bounds__(256) void qinit_kernel(QState* st) {
  __shared__ unsigned sN[256], sP[256], rN_[256], rP_[256];
  int t = threadIdx.x;
  unsigned hn = st->hist_neg[t], hp = st->hist_pos[t];
  sN[t] = hn; sP[t] = hp; rN_[t] = hn; rP_[t] = hp;
  __syncthreads();
  for (int off = 128; off > 0; off >>= 1) {
    if (t < off) { rN_[t] += rN_[t + off]; rP_[t] += rP_[t + off]; }
    __syncthreads();
  }
  if (t == 0) {
    unsigned nN = rN_[0], nP = rP_[0];
    st->n_neg = nN; st->n_pos = nP;
    float idxN = __fmul_rn(0.2f, (float)(nN - 1));
    float lowN = floorf(idxN);
    unsigned rn = (unsigned)(int)lowN;
    st->frac_neg = __fsub_rn(idxN, lowN);
    float idxP = __fmul_rn(0.8f, (float)(nP - 1));
    float lowP = floorf(idxP);
    unsigned rp = (unsigned)(int)lowP;
    st->frac_pos = __fsub_rn(idxP, lowP);
    st->vnext_neg = 0xFFFFFFFFu; st->vnext_pos = 0xFFFFFFFFu;
    {
      unsigned cum = 0, pref = 0;
      for (int b = 0; b < 256; ++b) {
        unsigned c = sN[b];
        if (rn < cum + c) { pref = ((unsigned)b) << 24; rn -= cum; break; }
        cum += c;
      }
      st->prefix_neg = pref; st->rank_neg = (int)rn;
    }
    {
      unsigned cum = 0, pref = 0;
      for (int b = 0; b < 256; ++b) {
        unsigned c = sP[b];
        if (rp < cum + c) { pref = ((unsigned)b) << 24; rp -= cum; break; }
        cum += c;
      }
      st->prefix_pos = pref; st->rank_pos = (int)rp;
    }
  }
  st->hist_neg[t] = 0u; st->hist_pos[t] = 0u;
}

__global__ void qupdate_kernel(QState* st, int round) {
  int shift = 24 - 8 * round;
  {
    unsigned cum = 0; unsigned r = (unsigned)st->rank_neg; unsigned pref = st->prefix_neg;
    for (int b = 0; b < 256; ++b) {
      unsigned c = st->hist_neg[b];
      if (r < cum + c) {
        pref |= ((unsigned)b) << shift; r -= cum;
        if (round == 3) st->dup_neg = (r + 1 < c) ? 1 : 0;
        break;
      }
      cum += c;
    }
    st->prefix_neg = pref; st->rank_neg = (int)r;
  }
  {
    unsigned cum = 0; unsigned r = (unsigned)st->rank_pos; unsigned pref = st->prefix_pos;
    for (int b = 0; b < 256; ++b) {
      unsigned c = st->hist_pos[b];
      if (r < cum + c) {
        pref |= ((unsigned)b) << shift; r -= cum;
        if (round == 3) st->dup_pos = (r + 1 < c) ? 1 : 0;
        break;
      }
      cum += c;
    }
    st->prefix_pos = pref; st->rank_pos = (int)r;
  }
  for (int i = 0; i < 256; ++i) { st->hist_neg[i] = 0u; st->hist_pos[i] = 0u; }
}

// min key strictly greater than the selected order statistic (register+wave min)
__global__ __launch_bounds__(256) void qvnext_kernel(const float* __restrict__ ep,
                                                     QState* st, int E) {
  unsigned pN = st->prefix_neg, pP = st->prefix_pos;
  unsigned mn = 0xFFFFFFFFu, mp = 0xFFFFFFFFu;
  int stride = gridDim.x * blockDim.x;
  for (int e = blockIdx.x * blockDim.x + threadIdx.x; e < E; e += stride) {
    float v = ep[e];
    unsigned key = f2key(v);
    if (v <= 0.f) { if (key > pN && key < mn) mn = key; }
    else          { if (key > pP && key < mp) mp = key; }
  }
#pragma unroll
  for (int off = 32; off > 0; off >>= 1) {
    unsigned a = (unsigned)__shfl_down((int)mn, off);
    unsigned b = (unsigned)__shfl_down((int)mp, off);
    mn = min(mn, a); mp = min(mp, b);
  }
  __shared__ unsigned wN[4], wP[4];
  int wid = threadIdx.x >> 6, lane = threadIdx.x & 63;
  if (lane == 0) { wN[wid] = mn; wP[wid] = mp; }
  __syncthreads();
  if (threadIdx.x == 0) {
    unsigned a = min(min(wN[0], wN[1]), min(wN[2], wN[3]));
    unsigned b = min(min(wP[0], wP[1]), min(wP[2], wP[3]));
    if (a != 0xFFFFFFFFu) atomicMin(&st->vnext_neg, a);
    if (b != 0xFFFFFFFFu) atomicMin(&st->vnext_pos, b);
  }
}

__global__ void qfinal_kernel(QState* st) {
  {
    float v0 = key2f(st->prefix_neg);
    float v1 = (st->dup_neg || st->vnext_neg == 0xFFFFFFFFu) ? v0 : key2f(st->vnext_neg);
    float f = st->frac_neg;
    st->thr_neg = (f > 0.f) ? __fadd_rn(v0, __fmul_rn(f, __fsub_rn(v1, v0))) : v0;
  }
  {
    float v0 = key2f(st->prefix_pos);
    float v1 = (st->dup_pos || st->vnext_pos == 0xFFFFFFFFu) ? v0 : key2f(st->vnext_pos);
    float f = st->frac_pos;
    st->thr_pos = (f > 0.f) ? __fadd_rn(v0, __fmul_rn(f, __fsub_rn(v1, v0))) : v0;
  }
}

// class per edge + per-(class,dst) in-degree histogram (int atomics)
__global__ void cls_deg_kernel(const float* __restrict__ ep, const int* __restrict__ dst,
                               unsigned char* __restrict__ cls, int* __restrict__ deg,
                               const QState* __restrict__ st, int N, int E) {
  int e = blockIdx.x * blockDim.x + threadIdx.x;
  if (e >= E) return;
  float thrN = st->thr_neg, thrP = st->thr_pos;
  float v = ep[e];
  int c = (v > thrP) ? 0 : ((v < thrN) ? 2 : 1);
  cls[e] = (unsigned char)c;
  atomicAdd(&deg[c * N + dst[e]], 1);
}

// ---- 3-kernel exclusive scan over deg[3N] -> rowPtr/cursor, fused dinv ----
__global__ __launch_bounds__(256) void scan1_kernel(const int* __restrict__ deg,
                                                    int* __restrict__ bsum, int nRows) {
  __shared__ int s[256];
  int i = blockIdx.x * 256 + threadIdx.x;
  s[threadIdx.x] = (i < nRows) ? deg[i] : 0;
  __syncthreads();
  for (int off = 128; off > 0; off >>= 1) {
    if (threadIdx.x < off) s[threadIdx.x] += s[threadIdx.x + off];
    __syncthreads();
  }
  if (threadIdx.x == 0) bsum[blockIdx.x] = s[0];
}

__global__ __launch_bounds__(256) void scan2_kernel(int* __restrict__ bsum, int nb) {
  __shared__ int s[256];
  __shared__ int carry;
  if (threadIdx.x == 0) carry = 0;
  __syncthreads();
  for (int base = 0; base < nb; base += 256) {
    int i = base + threadIdx.x;
    int v = (i < nb) ? bsum[i] : 0;
    s[threadIdx.x] = v;
    __syncthreads();
    for (int off = 1; off < 256; off <<= 1) {
      int x = (threadIdx.x >= off) ? s[threadIdx.x - off] : 0;
      __syncthreads();
      s[threadIdx.x] += x;
      __syncthreads();
    }
    int excl = s[threadIdx.x] - v;
    int c = carry;
    if (i < nb) bsum[i] = c + excl;
    int tot = s[255];
    __syncthreads();
    if (threadIdx.x == 0) carry = c + tot;
    __syncthreads();
  }
}

__global__ __launch_bounds__(256) void scan3_kernel(const int* __restrict__ deg,
    const int* __restrict__ bsum, int* __restrict__ rowPtr, int* __restrict__ cursor,
    float* __restrict__ dinv, int nRows) {
  __shared__ int s[256];
  int i = blockIdx.x * 256 + threadIdx.x;
  int v = (i < nRows) ? deg[i] : 0;
  s[threadIdx.x] = v;
  __syncthreads();
  for (int off = 1; off < 256; off <<= 1) {
    int x = (threadIdx.x >= off) ? s[threadIdx.x - off] : 0;
    __syncthreads();
    s[threadIdx.x] += x;
    __syncthreads();
  }
  if (i < nRows) {
    int excl = bsum[blockIdx.x] + s[threadIdx.x] - v;
    rowPtr[i] = excl;
    cursor[i] = excl;
    dinv[i] = 1.f / sqrtf(fmaxf((float)v, 1.f));
    if (i == nRows - 1) rowPtr[nRows] = excl + v;
  }
}

// bucket edges into CSR slots (order within a row is irrelevant: sums)
__global__ void fill_kernel(const int* __restrict__ src, const int* __restrict__ dst,
                            const unsigned char* __restrict__ cls, int* __restrict__ cursor,
                            int* __restrict__ eSrc, int N, int E) {
  int e = blockIdx.x * blockDim.x + threadIdx.x;
  if (e >= E) return;
  int row = (int)cls[e] * N + dst[e];
  int p = atomicAdd(&cursor[row], 1);
  eSrc[p] = src[e];
}

// Fused gather over all 3N (class,node) rows. 16 lanes per row, float4/lane.
// STEP 1: f = h [N,64] -> out L1all [3N,64]
// STEP 2: f = L1all [3N,64] -> out combo [N,192] column block c
template<int STEP>
__global__ __launch_bounds__(256) void gather3_kernel(const float* __restrict__ f,
    const float* __restrict__ h, float* __restrict__ outBuf,
    const int* __restrict__ rowPtr, const int* __restrict__ eSrc,
    const float* __restrict__ dinv, int N, int nRows) {
  int r = blockIdx.x * 16 + (threadIdx.x >> 4);
  if (r >= nRows) return;
  int l = threadIdx.x & 15;
  int c = r / N;
  int n = r - c * N;
  int beg = rowPtr[r], end = rowPtr[r + 1];
  int srcOfs = (STEP == 1) ? 0 : c * N;   // L1all rows are class-offset
  float4 acc = make_float4(0.f, 0.f, 0.f, 0.f);
  for (int e = beg; e < end; ++e) {
    int s = eSrc[e];
    float sc = dinv[c * N + s];
    float4 v = ((const float4*)f)[(size_t)(srcOfs + s) * 16 + l];
    acc.x += v.x * sc; acc.y += v.y * sc; acc.z += v.z * sc; acc.w += v.w * sc;
  }
  float di = dinv[r];
  if (STEP == 1) {
    float4 fv = ((const float4*)f)[(size_t)n * 16 + l];
    float4 o;
    o.x = fv.x - di * acc.x; o.y = fv.y - di * acc.y;
    o.z = fv.z - di * acc.z; o.w = fv.w - di * acc.w;
    ((float4*)outBuf)[(size_t)r * 16 + l] = o;
  } else {
    const float chA[3] = {0.f, 0.f, 3.f};
    const float c1A[3] = {0.f, 3.f, -3.f};
    const float c2A[3] = {0.75f, -1.5f, 0.75f};
    float ch = chA[c], c1 = c1A[c], c2 = c2A[c];
    float4 fv = ((const float4*)f)[(size_t)r * 16 + l];
    float4 hv = ((const float4*)h)[(size_t)n * 16 + l];
    float4 o;
    o.x = ch * hv.x + c1 * fv.x + c2 * (fv.x - di * acc.x);
    o.y = ch * hv.y + c1 * fv.y + c2 * (fv.y - di * acc.y);
    o.z = ch * hv.z + c1 * fv.z + c2 * (fv.z - di * acc.z);
    o.w = ch * hv.w + c1 * fv.w + c2 * (fv.w - di * acc.w);
    ((float4*)outBuf)[(size_t)n * 48 + c * 16 + l] = o;
  }
}

// Per-class gather (fallback path)
template<int STEP>
__global__ __launch_bounds__(256) void gather_kernel(const float* __restrict__ f,
    const float* __restrict__ h, float* __restrict__ outBuf,
    const int* __restrict__ rowPtr, const int* __restrict__ eSrc,
    const float* __restrict__ dinv, float ch, float c1, float c2, int N) {
  int n = blockIdx.x * 16 + (threadIdx.x >> 4);
  if (n >= N) return;
  int l = threadIdx.x & 15;
  int beg = rowPtr[n], end = rowPtr[n + 1];
  float4 acc = make_float4(0.f, 0.f, 0.f, 0.f);
  for (int e = beg; e < end; ++e) {
    int s = eSrc[e];
    float sc = dinv[s];
    float4 v = ((const float4*)f)[(size_t)s * 16 + l];
    acc.x += v.x * sc; acc.y += v.y * sc; acc.z += v.z * sc; acc.w += v.w * sc;
  }
  float di = dinv[n];
  size_t idx = (size_t)n * 16 + l;
  float4 fv = ((const float4*)f)[idx];
  float4 o;
  if (STEP == 1) {
    o.x = fv.x - di * acc.x; o.y = fv.y - di * acc.y;
    o.z = fv.z - di * acc.z; o.w = fv.w - di * acc.w;
  } else {
    float4 hv = ((const float4*)h)[idx];
    o.x = ch * hv.x + c1 * fv.x + c2 * (fv.x - di * acc.x);
    o.y = ch * hv.y + c1 * fv.y + c2 * (fv.y - di * acc.y);
    o.z = ch * hv.z + c1 * fv.z + c2 * (fv.z - di * acc.z);
    o.w = ch * hv.w + c1 * fv.w + c2 * (fv.w - di * acc.w);
  }
  ((float4*)outBuf)[idx] = o;
}

// Wt[col*K + k] (bf16) = W[k*64 + col] (fp32) — weight transpose+cast, tiny.
__global__ void wconv_kernel(const float* __restrict__ W, short* __restrict__ Wt, int K) {
  int i = blockIdx.x * 256 + threadIdx.x;
  if (i >= K * 64) return;
  int col = i / K, k = i - col * K;
  Wt[i] = bf16rn(W[(size_t)k * 64 + col]);
}

// C[N,64] = A[N,K](fp32->bf16) @ Wt^T (bf16), fp32 accum via MFMA 16x16x32.
// Block: 64 rows x 64 cols, 4 waves; wave w computes rows [w*16, w*16+16).
// A staged in LDS bf16, row stride 40 shorts (16B-aligned, 2-way bank alias).
// B-fragments: 16B coalesced global loads from Wt[col][k] (L1/L2-resident).
template<int K>
__global__ __launch_bounds__(256) void gemm_mfma_kernel(const float* __restrict__ A,
    const short* __restrict__ Wt, const float* __restrict__ bias,
    float* __restrict__ C, int N, int accum, int finish) {
  __shared__ short As[64 * 40];
  const int tid = threadIdx.x;
  const int wave = tid >> 6, lane = tid & 63;
  const int m = lane & 15, quad = lane >> 4;
  const int rowBase = blockIdx.x * 64;
  floatx4 acc[4] = {{0.f,0.f,0.f,0.f},{0.f,0.f,0.f,0.f},{0.f,0.f,0.f,0.f},{0.f,0.f,0.f,0.f}};
  const int rs = tid >> 2;          // staging row 0..63
  const int cs = (tid & 3) * 8;     // staging col base 0/8/16/24
  const int rowS = rowBase + rs;
  const int aRow = (wave * 16 + m) * 40 + quad * 8;   // A-frag LDS offset
  for (int kc = 0; kc < K; kc += 32) {
    float4 v0 = make_float4(0.f, 0.f, 0.f, 0.f), v1 = v0;
    if (rowS < N) {
      const float* p = A + (size_t)rowS * K + kc + cs;
      v0 = *(const float4*)p;
      v1 = *(const float4*)(p + 4);
    }
    short8 s;
    s[0] = bf16rn(v0.x); s[1] = bf16rn(v0.y); s[2] = bf16rn(v0.z); s[3] = bf16rn(v0.w);
    s[4] = bf16rn(v1.x); s[5] = bf16rn(v1.y); s[6] = bf16rn(v1.z); s[7] = bf16rn(v1.w);
    *(short8*)&As[rs * 40 + cs] = s;
    __syncthreads();
    short8 af = *(const short8*)&As[aRow];
    const short* wp = Wt + (size_t)m * K + kc + quad * 8;
#pragma unroll
    for (int ct = 0; ct < 4; ++ct) {
      short8 bf = *(const short8*)(wp + (size_t)ct * 16 * K);
      acc[ct] = __builtin_amdgcn_mfma_f32_16x16x32_bf16(af, bf, acc[ct], 0, 0, 0);
    }
    __syncthreads();
  }
  const int r0 = rowBase + wave * 16 + quad * 4;
#pragma unroll
  for (int ct = 0; ct < 4; ++ct) {
    float b = finish ? bias[ct * 16 + m] : 0.f;
#pragma unroll
    for (int reg = 0; reg < 4; ++reg) {
      int row = r0 + reg;
      if (row < N) {
        float* cp = C + (size_t)row * 64 + ct * 16 + m;
        float o = acc[ct][reg];
        if (accum) o += *cp;
        if (finish) o = fmaxf(o + b, 0.f);
        *cp = o;
      }
    }
  }
}

extern "C" void kernel_launch(void* const* d_in, const int* in_sizes, int n_in,
                              void* d_out, int out_size, void* d_ws, size_t ws_size,
                              hipStream_t stream) {
  const float* feat = (const float*)d_in[0];
  const float* ep   = (const float*)d_in[1];
  const int*   src  = (const int*)d_in[2];
  const int*   dst  = (const int*)d_in[3];
  const float* W1   = (const float*)d_in[4];
  const float* b1   = (const float*)d_in[5];
  const float* W2   = (const float*)d_in[6];
  const float* b2   = (const float*)d_in[7];
  const float* W3   = (const float*)d_in[8];
  const float* b3   = (const float*)d_in[9];
  float* out = (float*)d_out;
  const int N = in_sizes[0] / 128;
  const int E = in_sizes[1];
  const int nRows = 3 * N;
  const int nb = (nRows + 255) / 256;

  char* w = (char*)d_ws;
  size_t off = 0;
  QState* st = (QState*)(w + off);           off += WS_ALIGN(sizeof(QState));
  int* deg = (int*)(w + off);                off += WS_ALIGN((size_t)nRows * 4);
  const size_t zeroBytes = off;              // state + deg zeroed together
  int* rowPtr = (int*)(w + off);             off += WS_ALIGN((size_t)(nRows + 1) * 4);
  int* cursor = (int*)(w + off);             off += WS_ALIGN((size_t)nRows * 4);
  float* dinv = (float*)(w + off);           off += WS_ALIGN((size_t)nRows * 4);
  int* bsum = (int*)(w + off);               off += WS_ALIGN((size_t)nb * 4);
  unsigned char* cls = (unsigned char*)(w + off); off += WS_ALIGN((size_t)E);
  int* eSrc = (int*)(w + off);               off += WS_ALIGN((size_t)E * 4);
  short* Wt1 = (short*)(w + off);            off += WS_ALIGN((size_t)64 * 128 * 2);
  short* Wt2 = (short*)(w + off);            off += WS_ALIGN((size_t)64 * 64 * 2);
  short* Wt3 = (short*)(w + off);            off += WS_ALIGN((size_t)64 * 192 * 2);
  float* h   = (float*)(w + off);            off += (size_t)N * 64 * 4;
  // fused: L1all [3N,64] + combo [N,192]; fallback: L1 [N,64] + tmp [N,64]
  const size_t fusedNeed = off + (size_t)nRows * 64 * 4 + (size_t)N * 192 * 4;
  const bool fused = (ws_size >= fusedNeed);
  float* L1all = (float*)(w + off);          // also temp for h1 (used pre-gather)
  float* combo = fused ? (float*)(w + off + (size_t)nRows * 64 * 4)
                       : (float*)(w + off + (size_t)N * 64 * 4);
  (void)n_in; (void)out_size;

  hipMemsetAsync(d_ws, 0, zeroBytes, stream);

  const int eb = (E + 255) / 256;
  qhist_kernel<<<512, 256, 0, stream>>>(ep, st, E, 0);
  qinit_kernel<<<1, 256, 0, stream>>>(st);
  for (int r = 1; r < 4; ++r) {
    qhist_kernel<<<512, 256, 0, stream>>>(ep, st, E, r);
    qupdate_kernel<<<1, 1, 0, stream>>>(st, r);
  }
  qvnext_kernel<<<512, 256, 0, stream>>>(ep, st, E);
  qfinal_kernel<<<1, 1, 0, stream>>>(st);

  cls_deg_kernel<<<eb, 256, 0, stream>>>(ep, dst, cls, deg, st, N, E);
  scan1_kernel<<<nb, 256, 0, stream>>>(deg, bsum, nRows);
  scan2_kernel<<<1, 256, 0, stream>>>(bsum, nb);
  scan3_kernel<<<nb, 256, 0, stream>>>(deg, bsum, rowPtr, cursor, dinv, nRows);
  fill_kernel<<<eb, 256, 0, stream>>>(src, dst, cls, cursor, eSrc, N, E);

  // weight transpose+cast (tiny; overlaps edge kernels in-order on stream)
  wconv_kernel<<<(128 * 64 + 255) / 256, 256, 0, stream>>>(W1, Wt1, 128);
  wconv_kernel<<<(64 * 64 + 255) / 256, 256, 0, stream>>>(W2, Wt2, 64);
  wconv_kernel<<<(192 * 64 + 255) / 256, 256, 0, stream>>>(W3, Wt3, 192);

  const int gb = (N + 63) / 64;
  gemm_mfma_kernel<128><<<gb, 256, 0, stream>>>(feat, Wt1, b1, L1all, N, 0, 1); // h1
  gemm_mfma_kernel<64><<<gb, 256, 0, stream>>>(L1all, Wt2, b2, h, N, 0, 1);     // h

  if (fused) {
    const int g3 = (nRows + 15) / 16;
    gather3_kernel<1><<<g3, 256, 0, stream>>>(h, h, L1all, rowPtr, eSrc, dinv, N, nRows);
    gather3_kernel<2><<<g3, 256, 0, stream>>>(L1all, h, combo, rowPtr, eSrc, dinv, N, nRows);
    gemm_mfma_kernel<192><<<gb, 256, 0, stream>>>(combo, Wt3, b3, out, N, 0, 1);
  } else {
    const float chArr[3] = {0.f, 0.f, 3.f};
    const float c1Arr[3] = {0.f, 3.f, -3.f};
    const float c2Arr[3] = {0.75f, -1.5f, 0.75f};
    const int ggrid = (N + 15) / 16;
    float* L1 = L1all;
    for (int c = 0; c < 3; ++c) {
      const int* rp = rowPtr + (size_t)c * N;
      const float* dv = dinv + (size_t)c * N;
      gather_kernel<1><<<ggrid, 256, 0, stream>>>(h, nullptr, L1, rp, eSrc, dv,
                                                  0.f, 0.f, 0.f, N);
      gather_kernel<2><<<ggrid, 256, 0, stream>>>(L1, h, combo, rp, eSrc, dv,
                                                  chArr[c], c1Arr[c], c2Arr[c], N);
      // reuse Wt2 buffer for per-class W3 chunk transpose
      wconv_kernel<<<(64 * 64 + 255) / 256, 256, 0, stream>>>(W3 + (size_t)c * 64 * 64, Wt2, 64);
      gemm_mfma_kernel<64><<<gb, 256, 0, stream>>>(combo, Wt2, b3, out,
                                                   N, c > 0 ? 1 : 0, c == 2 ? 1 : 0);
    }
  }
}

// Round 5
// 577.809 us; speedup vs baseline: 7.6548x; 1.1858x over previous
//
#include <hip/hip_runtime.h>
#include <cstdint>
#include <cstddef>

// ---------------------------------------------------------------------------
// GraphPartitionModule: quantile-masked 3-way edge partition -> per-class
// normalized-Laplacian powers (D=2) -> theta combination -> MLP head.
//
// R5:
//  - fill de-atomicized: cls_deg records each edge's within-row slot
//    (atomicAdd return) into myOff; fill is a pure scatter.
//  - propagation in bf16: h / L1all / combo stored bf16 (halves the random
//    gather row reads, 128B/row); fp32 accumulate everywhere.
//  - gemm_mfma<K,ABF,OBF>: bf16 or fp32 A-input / C-output variants.
// Quantile radix-select machinery unchanged (R3-proven).
// ---------------------------------------------------------------------------

#define WS_ALIGN(x) (((x) + 255) & ~(size_t)255)

typedef __attribute__((ext_vector_type(8))) short short8;
typedef __attribute__((ext_vector_type(4))) float floatx4;

struct QState {
  unsigned n_neg, n_pos;
  unsigned prefix_neg, prefix_pos;
  int rank_neg, rank_pos;
  float frac_neg, frac_pos;
  unsigned vnext_neg, vnext_pos;
  float thr_neg, thr_pos;
  int dup_neg, dup_pos;
  unsigned hist_neg[256];
  unsigned hist_pos[256];
};

// monotone float<->uint key mapping (ascending float == ascending key)
__device__ __forceinline__ unsigned f2key(float v) {
  unsigned u = __float_as_uint(v);
  return (u & 0x80000000u) ? ~u : (u | 0x80000000u);
}
__device__ __forceinline__ float key2f(unsigned k) {
  unsigned u = (k & 0x80000000u) ? (k ^ 0x80000000u) : ~k;
  return __uint_as_float(u);
}

__device__ __forceinline__ unsigned short bf16rn(float x) {   // fp32 -> bf16 RNE
  unsigned u = __float_as_uint(x);
  u = (u + 0x7FFFu + ((u >> 16) & 1u)) >> 16;
  return (unsigned short)u;
}
__device__ __forceinline__ float bf2f(unsigned short v) {
  return __uint_as_float(((unsigned)v) << 16);
}

__global__ __launch_bounds__(256) void qhist_kernel(const float* __restrict__ ep,
                                                    QState* st, int E, int round) {
  __shared__ unsigned hN[256], hP[256];
  hN[threadIdx.x] = 0u; hP[threadIdx.x] = 0u;
  __syncthreads();
  int shift = 24 - 8 * round;
  unsigned maskHi = 0u;
  if (round > 0) maskHi = 0xFFFFFFFFu << (shift + 8);
  unsigned pN = st->prefix_neg & maskHi;
  unsigned pP = st->prefix_pos & maskHi;
  int stride = gridDim.x * blockDim.x;
  for (int e = blockIdx.x * blockDim.x + threadIdx.x; e < E; e += stride) {
    float v = ep[e];
    unsigned key = f2key(v);
    if (v <= 0.f) {
      if ((key & maskHi) == pN) atomicAdd(&hN[(key >> shift) & 255], 1u);
    } else {
      if ((key & maskHi) == pP) atomicAdd(&hP[(key >> shift) & 255], 1u);
    }
  }
  __syncthreads();
  unsigned cN = hN[threadIdx.x], cP = hP[threadIdx.x];
  if (cN) atomicAdd(&st->hist_neg[threadIdx.x], cN);
  if (cP) atomicAdd(&st->hist_pos[threadIdx.x], cP);
}

// After round-0 hist: n_neg/n_pos = hist sums; compute ranks (f32 semantics
// matching jnp.nanquantile), do round-0 bucket select, re-zero hists.
__global__ __launch_bounds__(256) void qinit_kernel(QState* st) {
  __shared__ unsigned sN[256], sP[256], rN_[256], rP_[256];
  int t = threadIdx.x;
  unsigned hn = st->hist_neg[t], hp = st->hist_pos[t];
  sN[t] = hn; sP[t] = hp; rN_[t] = hn; rP_[t] = hp;
  __syncthreads();
  for (int off = 128; off > 0; off >>= 1) {
    if (t < off) { rN_[t] += rN_[t + off]; rP_[t] += rP_[t + off]; }
    __syncthreads();
  }
  if (t == 0) {
    unsigned nN = rN_[0], nP = rP_[0];
    st->n_neg = nN; st->n_pos = nP;
    float idxN = __fmul_rn(0.2f, (float)(nN - 1));
    float lowN = floorf(idxN);
    unsigned rn = (unsigned)(int)lowN;
    st->frac_neg = __fsub_rn(idxN, lowN);
    float idxP = __fmul_rn(0.8f, (float)(nP - 1));
    float lowP = floorf(idxP);
    unsigned rp = (unsigned)(int)lowP;
    st->frac_pos = __fsub_rn(idxP, lowP);
    st->vnext_neg = 0xFFFFFFFFu; st->vnext_pos = 0xFFFFFFFFu;
    {
      unsigned cum = 0, pref = 0;
      for (int b = 0; b < 256; ++b) {
        unsigned c = sN[b];
        if (rn < cum + c) { pref = ((unsigned)b) << 24; rn -= cum; break; }
        cum += c;
      }
      st->prefix_neg = pref; st->rank_neg = (int)rn;
    }
    {
      unsigned cum = 0, pref = 0;
      for (int b = 0; b < 256; ++b) {
        unsigned c = sP[b];
        if (rp < cum + c) { pref = ((unsigned)b) << 24; rp -= cum; break; }
        cum += c;
      }
      st->prefix_pos = pref; st->rank_pos = (int)rp;
    }
  }
  st->hist_neg[t] = 0u; st->hist_pos[t] = 0u;
}

__global__ void qupdate_kernel(QState* st, int round) {
  int shift = 24 - 8 * round;
  {
    unsigned cum = 0; unsigned r = (unsigned)st->rank_neg; unsigned pref = st->prefix_neg;
    for (int b = 0; b < 256; ++b) {
      unsigned c = st->hist_neg[b];
      if (r < cum + c) {
        pref |= ((unsigned)b) << shift; r -= cum;
        if (round == 3) st->dup_neg = (r + 1 < c) ? 1 : 0;
        break;
      }
      cum += c;
    }
    st->prefix_neg = pref; st->rank_neg = (int)r;
  }
  {
    unsigned cum = 0; unsigned r = (unsigned)st->rank_pos; unsigned pref = st->prefix_pos;
    for (int b = 0; b < 256; ++b) {
      unsigned c = st->hist_pos[b];
      if (r < cum + c) {
        pref |= ((unsigned)b) << shift; r -= cum;
        if (round == 3) st->dup_pos = (r + 1 < c) ? 1 : 0;
        break;
      }
      cum += c;
    }
    st->prefix_pos = pref; st->rank_pos = (int)r;
  }
  for (int i = 0; i < 256; ++i) { st->hist_neg[i] = 0u; st->hist_pos[i] = 0u; }
}

// min key strictly greater than the selected order statistic (register+wave min)
__global__ __launch_bounds__(256) void qvnext_kernel(const float* __restrict__ ep,
                                                     QState* st, int E) {
  unsigned pN = st->prefix_neg, pP = st->prefix_pos;
  unsigned mn = 0xFFFFFFFFu, mp = 0xFFFFFFFFu;
  int stride = gridDim.x * blockDim.x;
  for (int e = blockIdx.x * blockDim.x + threadIdx.x; e < E; e += stride) {
    float v = ep[e];
    unsigned key = f2key(v);
    if (v <= 0.f) { if (key > pN && key < mn) mn = key; }
    else          { if (key > pP && key < mp) mp = key; }
  }
#pragma unroll
  for (int off = 32; off > 0; off >>= 1) {
    unsigned a = (unsigned)__shfl_down((int)mn, off);
    unsigned b = (unsigned)__shfl_down((int)mp, off);
    mn = min(mn, a); mp = min(mp, b);
  }
  __shared__ unsigned wN[4], wP[4];
  int wid = threadIdx.x >> 6, lane = threadIdx.x & 63;
  if (lane == 0) { wN[wid] = mn; wP[wid] = mp; }
  __syncthreads();
  if (threadIdx.x == 0) {
    unsigned a = min(min(wN[0], wN[1]), min(wN[2], wN[3]));
    unsigned b = min(min(wP[0], wP[1]), min(wP[2], wP[3]));
    if (a != 0xFFFFFFFFu) atomicMin(&st->vnext_neg, a);
    if (b != 0xFFFFFFFFu) atomicMin(&st->vnext_pos, b);
  }
}

__global__ void qfinal_kernel(QState* st) {
  {
    float v0 = key2f(st->prefix_neg);
    float v1 = (st->dup_neg || st->vnext_neg == 0xFFFFFFFFu) ? v0 : key2f(st->vnext_neg);
    float f = st->frac_neg;
    st->thr_neg = (f > 0.f) ? __fadd_rn(v0, __fmul_rn(f, __fsub_rn(v1, v0))) : v0;
  }
  {
    float v0 = key2f(st->prefix_pos);
    float v1 = (st->dup_pos || st->vnext_pos == 0xFFFFFFFFu) ? v0 : key2f(st->vnext_pos);
    float f = st->frac_pos;
    st->thr_pos = (f > 0.f) ? __fadd_rn(v0, __fmul_rn(f, __fsub_rn(v1, v0))) : v0;
  }
}

// class per edge + per-(class,dst) in-degree histogram; record within-row slot
__global__ void cls_deg_kernel(const float* __restrict__ ep, const int* __restrict__ dst,
                               unsigned char* __restrict__ cls, int* __restrict__ deg,
                               int* __restrict__ myOff,
                               const QState* __restrict__ st, int N, int E) {
  int e = blockIdx.x * blockDim.x + threadIdx.x;
  if (e >= E) return;
  float thrN = st->thr_neg, thrP = st->thr_pos;
  float v = ep[e];
  int c = (v > thrP) ? 0 : ((v < thrN) ? 2 : 1);
  cls[e] = (unsigned char)c;
  myOff[e] = atomicAdd(&deg[c * N + dst[e]], 1);
}

// ---- 3-kernel exclusive scan over deg[3N] -> rowPtr, fused dinv ----
__global__ __launch_bounds__(256) void scan1_kernel(const int* __restrict__ deg,
                                                    int* __restrict__ bsum, int nRows) {
  __shared__ int s[256];
  int i = blockIdx.x * 256 + threadIdx.x;
  s[threadIdx.x] = (i < nRows) ? deg[i] : 0;
  __syncthreads();
  for (int off = 128; off > 0; off >>= 1) {
    if (threadIdx.x < off) s[threadIdx.x] += s[threadIdx.x + off];
    __syncthreads();
  }
  if (threadIdx.x == 0) bsum[blockIdx.x] = s[0];
}

__global__ __launch_bounds__(256) void scan2_kernel(int* __restrict__ bsum, int nb) {
  __shared__ int s[256];
  __shared__ int carry;
  if (threadIdx.x == 0) carry = 0;
  __syncthreads();
  for (int base = 0; base < nb; base += 256) {
    int i = base + threadIdx.x;
    int v = (i < nb) ? bsum[i] : 0;
    s[threadIdx.x] = v;
    __syncthreads();
    for (int off = 1; off < 256; off <<= 1) {
      int x = (threadIdx.x >= off) ? s[threadIdx.x - off] : 0;
      __syncthreads();
      s[threadIdx.x] += x;
      __syncthreads();
    }
    int excl = s[threadIdx.x] - v;
    int c = carry;
    if (i < nb) bsum[i] = c + excl;
    int tot = s[255];
    __syncthreads();
    if (threadIdx.x == 0) carry = c + tot;
    __syncthreads();
  }
}

__global__ __launch_bounds__(256) void scan3_kernel(const int* __restrict__ deg,
    const int* __restrict__ bsum, int* __restrict__ rowPtr,
    float* __restrict__ dinv, int nRows) {
  __shared__ int s[256];
  int i = blockIdx.x * 256 + threadIdx.x;
  int v = (i < nRows) ? deg[i] : 0;
  s[threadIdx.x] = v;
  __syncthreads();
  for (int off = 1; off < 256; off <<= 1) {
    int x = (threadIdx.x >= off) ? s[threadIdx.x - off] : 0;
    __syncthreads();
    s[threadIdx.x] += x;
    __syncthreads();
  }
  if (i < nRows) {
    int excl = bsum[blockIdx.x] + s[threadIdx.x] - v;
    rowPtr[i] = excl;
    dinv[i] = 1.f / sqrtf(fmaxf((float)v, 1.f));
    if (i == nRows - 1) rowPtr[nRows] = excl + v;
  }
}

// pure scatter: slot precomputed in cls_deg (no atomics)
__global__ void fill_kernel(const int* __restrict__ src, const int* __restrict__ dst,
                            const unsigned char* __restrict__ cls,
                            const int* __restrict__ rowPtr, const int* __restrict__ myOff,
                            int* __restrict__ eSrc, int N, int E) {
  int e = blockIdx.x * blockDim.x + threadIdx.x;
  if (e >= E) return;
  int row = (int)cls[e] * N + dst[e];
  eSrc[rowPtr[row] + myOff[e]] = src[e];
}

// Fused gather over all 3N (class,node) rows, bf16 data, fp32 accumulate.
// 16 lanes per row, ushort4 (4 bf16) per lane.
// STEP 1: f = h_bf [N,64] -> out L1_bf [3N,64]
// STEP 2: f = L1_bf [3N,64] -> out combo_bf [N,192] column block c
template<int STEP>
__global__ __launch_bounds__(256) void gather3_kernel(const unsigned short* __restrict__ f,
    const unsigned short* __restrict__ hb, unsigned short* __restrict__ outBuf,
    const int* __restrict__ rowPtr, const int* __restrict__ eSrc,
    const float* __restrict__ dinv, int N, int nRows) {
  int r = blockIdx.x * 16 + (threadIdx.x >> 4);
  if (r >= nRows) return;
  int l = threadIdx.x & 15;
  int c = r / N;
  int n = r - c * N;
  int beg = rowPtr[r], end = rowPtr[r + 1];
  int srcOfs = (STEP == 1) ? 0 : c * N;   // L1_bf rows are class-offset
  float ax = 0.f, ay = 0.f, az = 0.f, aw = 0.f;
  for (int e = beg; e < end; ++e) {
    int s = eSrc[e];
    float sc = dinv[c * N + s];
    ushort4 v = *(const ushort4*)&f[(size_t)(srcOfs + s) * 64 + l * 4];
    ax += bf2f(v.x) * sc; ay += bf2f(v.y) * sc;
    az += bf2f(v.z) * sc; aw += bf2f(v.w) * sc;
  }
  float di = dinv[r];
  if (STEP == 1) {
    ushort4 fv = *(const ushort4*)&f[(size_t)n * 64 + l * 4];
    ushort4 o;
    o.x = bf16rn(bf2f(fv.x) - di * ax);
    o.y = bf16rn(bf2f(fv.y) - di * ay);
    o.z = bf16rn(bf2f(fv.z) - di * az);
    o.w = bf16rn(bf2f(fv.w) - di * aw);
    *(ushort4*)&outBuf[(size_t)r * 64 + l * 4] = o;
  } else {
    const float chA[3] = {0.f, 0.f, 3.f};
    const float c1A[3] = {0.f, 3.f, -3.f};
    const float c2A[3] = {0.75f, -1.5f, 0.75f};
    float ch = chA[c], c1 = c1A[c], c2 = c2A[c];
    ushort4 fv = *(const ushort4*)&f[(size_t)r * 64 + l * 4];
    ushort4 hv = *(const ushort4*)&hb[(size_t)n * 64 + l * 4];
    float fx = bf2f(fv.x), fy = bf2f(fv.y), fz = bf2f(fv.z), fw = bf2f(fv.w);
    ushort4 o;
    o.x = bf16rn(ch * bf2f(hv.x) + c1 * fx + c2 * (fx - di * ax));
    o.y = bf16rn(ch * bf2f(hv.y) + c1 * fy + c2 * (fy - di * ay));
    o.z = bf16rn(ch * bf2f(hv.z) + c1 * fz + c2 * (fz - di * az));
    o.w = bf16rn(ch * bf2f(hv.w) + c1 * fw + c2 * (fw - di * aw));
    *(ushort4*)&outBuf[(size_t)n * 192 + c * 64 + l * 4] = o;
  }
}

// Per-class gather (fallback path), bf16 data
template<int STEP>
__global__ __launch_bounds__(256) void gatherF_kernel(const unsigned short* __restrict__ f,
    const unsigned short* __restrict__ hb, unsigned short* __restrict__ outBuf,
    const int* __restrict__ rowPtr, const int* __restrict__ eSrc,
    const float* __restrict__ dinv, float ch, float c1, float c2, int N) {
  int n = blockIdx.x * 16 + (threadIdx.x >> 4);
  if (n >= N) return;
  int l = threadIdx.x & 15;
  int beg = rowPtr[n], end = rowPtr[n + 1];
  float ax = 0.f, ay = 0.f, az = 0.f, aw = 0.f;
  for (int e = beg; e < end; ++e) {
    int s = eSrc[e];
    float sc = dinv[s];
    ushort4 v = *(const ushort4*)&f[(size_t)s * 64 + l * 4];
    ax += bf2f(v.x) * sc; ay += bf2f(v.y) * sc;
    az += bf2f(v.z) * sc; aw += bf2f(v.w) * sc;
  }
  float di = dinv[n];
  size_t idx = (size_t)n * 64 + l * 4;
  ushort4 fv = *(const ushort4*)&f[idx];
  float fx = bf2f(fv.x), fy = bf2f(fv.y), fz = bf2f(fv.z), fw = bf2f(fv.w);
  ushort4 o;
  if (STEP == 1) {
    o.x = bf16rn(fx - di * ax); o.y = bf16rn(fy - di * ay);
    o.z = bf16rn(fz - di * az); o.w = bf16rn(fw - di * aw);
  } else {
    ushort4 hv = *(const ushort4*)&hb[idx];
    o.x = bf16rn(ch * bf2f(hv.x) + c1 * fx + c2 * (fx - di * ax));
    o.y = bf16rn(ch * bf2f(hv.y) + c1 * fy + c2 * (fy - di * ay));
    o.z = bf16rn(ch * bf2f(hv.z) + c1 * fz + c2 * (fz - di * az));
    o.w = bf16rn(ch * bf2f(hv.w) + c1 * fw + c2 * (fw - di * aw));
  }
  *(ushort4*)&outBuf[idx] = o;
}

// Wt[col*K + k] (bf16) = W[k*64 + col] (fp32) — weight transpose+cast, tiny.
__global__ void wconv_kernel(const float* __restrict__ W, unsigned short* __restrict__ Wt,
                             int K) {
  int i = blockIdx.x * 256 + threadIdx.x;
  if (i >= K * 64) return;
  int col = i / K, k = i - col * K;
  Wt[i] = bf16rn(W[(size_t)k * 64 + col]);
}

// C[N,64] = A[N,K] @ Wt^T (bf16), fp32 accum via MFMA 16x16x32.
// ABF: A is bf16 (else fp32, converted during staging). OBF: C is bf16.
// Block: 64 rows x 64 cols, 4 waves; wave w computes rows [w*16, w*16+16).
// A staged in LDS bf16, row stride 40 shorts (16B-aligned, 2-way bank alias).
template<int K, int ABF, int OBF>
__global__ __launch_bounds__(256) void gemm_mfma_kernel(const void* __restrict__ Ain,
    const unsigned short* __restrict__ Wt, const float* __restrict__ bias,
    void* __restrict__ Cout, int N, int accum, int finish) {
  __shared__ short As[64 * 40];
  const int tid = threadIdx.x;
  const int wave = tid >> 6, lane = tid & 63;
  const int m = lane & 15, quad = lane >> 4;
  const int rowBase = blockIdx.x * 64;
  floatx4 acc[4] = {{0.f,0.f,0.f,0.f},{0.f,0.f,0.f,0.f},{0.f,0.f,0.f,0.f},{0.f,0.f,0.f,0.f}};
  const int rs = tid >> 2;          // staging row 0..63
  const int cs = (tid & 3) * 8;     // staging col base 0/8/16/24
  const int rowS = rowBase + rs;
  const int aRow = (wave * 16 + m) * 40 + quad * 8;   // A-frag LDS offset
  for (int kc = 0; kc < K; kc += 32) {
    short8 s = {0,0,0,0,0,0,0,0};
    if (rowS < N) {
      if (ABF) {
        s = *(const short8*)((const unsigned short*)Ain + (size_t)rowS * K + kc + cs);
      } else {
        const float* p = (const float*)Ain + (size_t)rowS * K + kc + cs;
        float4 v0 = *(const float4*)p;
        float4 v1 = *(const float4*)(p + 4);
        s[0] = bf16rn(v0.x); s[1] = bf16rn(v0.y); s[2] = bf16rn(v0.z); s[3] = bf16rn(v0.w);
        s[4] = bf16rn(v1.x); s[5] = bf16rn(v1.y); s[6] = bf16rn(v1.z); s[7] = bf16rn(v1.w);
      }
    }
    *(short8*)&As[rs * 40 + cs] = s;
    __syncthreads();
    short8 af = *(const short8*)&As[aRow];
    const unsigned short* wp = Wt + (size_t)m * K + kc + quad * 8;
#pragma unroll
    for (int ct = 0; ct < 4; ++ct) {
      short8 bf = *(const short8*)(wp + (size_t)ct * 16 * K);
      acc[ct] = __builtin_amdgcn_mfma_f32_16x16x32_bf16(af, bf, acc[ct], 0, 0, 0);
    }
    __syncthreads();
  }
  const int r0 = rowBase + wave * 16 + quad * 4;
#pragma unroll
  for (int ct = 0; ct < 4; ++ct) {
    float b = finish ? bias[ct * 16 + m] : 0.f;
#pragma unroll
    for (int reg = 0; reg < 4; ++reg) {
      int row = r0 + reg;
      if (row < N) {
        float o = acc[ct][reg];
        if (OBF) {
          if (finish) o = fmaxf(o + b, 0.f);
          ((unsigned short*)Cout)[(size_t)row * 64 + ct * 16 + m] = bf16rn(o);
        } else {
          float* cp = (float*)Cout + (size_t)row * 64 + ct * 16 + m;
          if (accum) o += *cp;
          if (finish) o = fmaxf(o + b, 0.f);
          *cp = o;
        }
      }
    }
  }
}

extern "C" void kernel_launch(void* const* d_in, const int* in_sizes, int n_in,
                              void* d_out, int out_size, void* d_ws, size_t ws_size,
                              hipStream_t stream) {
  const float* feat = (const float*)d_in[0];
  const float* ep   = (const float*)d_in[1];
  const int*   src  = (const int*)d_in[2];
  const int*   dst  = (const int*)d_in[3];
  const float* W1   = (const float*)d_in[4];
  const float* b1   = (const float*)d_in[5];
  const float* W2   = (const float*)d_in[6];
  const float* b2   = (const float*)d_in[7];
  const float* W3   = (const float*)d_in[8];
  const float* b3   = (const float*)d_in[9];
  float* out = (float*)d_out;
  const int N = in_sizes[0] / 128;
  const int E = in_sizes[1];
  const int nRows = 3 * N;
  const int nb = (nRows + 255) / 256;

  char* w = (char*)d_ws;
  size_t off = 0;
  QState* st = (QState*)(w + off);           off += WS_ALIGN(sizeof(QState));
  int* deg = (int*)(w + off);                off += WS_ALIGN((size_t)nRows * 4);
  const size_t zeroBytes = off;              // state + deg zeroed together
  int* rowPtr = (int*)(w + off);             off += WS_ALIGN((size_t)(nRows + 1) * 4);
  float* dinv = (float*)(w + off);           off += WS_ALIGN((size_t)nRows * 4);
  int* bsum = (int*)(w + off);               off += WS_ALIGN((size_t)nb * 4);
  unsigned char* cls = (unsigned char*)(w + off); off += WS_ALIGN((size_t)E);
  int* myOff = (int*)(w + off);              off += WS_ALIGN((size_t)E * 4);
  int* eSrc = (int*)(w + off);               off += WS_ALIGN((size_t)E * 4);
  unsigned short* Wt1 = (unsigned short*)(w + off); off += WS_ALIGN((size_t)64 * 128 * 2);
  unsigned short* Wt2 = (unsigned short*)(w + off); off += WS_ALIGN((size_t)64 * 64 * 2);
  unsigned short* Wt3 = (unsigned short*)(w + off); off += WS_ALIGN((size_t)64 * 192 * 2);
  unsigned short* h_bf = (unsigned short*)(w + off); off += WS_ALIGN((size_t)N * 64 * 2);
  // fused: L1_bf [3N,64] + combo_bf [N,192]; fallback: L1 [N,64] + combo [N,64]
  const size_t fusedNeed = off + (size_t)nRows * 64 * 2 + (size_t)N * 192 * 2;
  const bool fused = (ws_size >= fusedNeed);
  unsigned short* L1_bf = (unsigned short*)(w + off);   // also temp for h1
  unsigned short* combo_bf = fused
      ? (unsigned short*)(w + off + WS_ALIGN((size_t)nRows * 64 * 2))
      : (unsigned short*)(w + off + WS_ALIGN((size_t)N * 64 * 2));
  (void)n_in; (void)out_size;

  hipMemsetAsync(d_ws, 0, zeroBytes, stream);

  const int eb = (E + 255) / 256;
  qhist_kernel<<<512, 256, 0, stream>>>(ep, st, E, 0);
  qinit_kernel<<<1, 256, 0, stream>>>(st);
  for (int r = 1; r < 4; ++r) {
    qhist_kernel<<<512, 256, 0, stream>>>(ep, st, E, r);
    qupdate_kernel<<<1, 1, 0, stream>>>(st, r);
  }
  qvnext_kernel<<<512, 256, 0, stream>>>(ep, st, E);
  qfinal_kernel<<<1, 1, 0, stream>>>(st);

  cls_deg_kernel<<<eb, 256, 0, stream>>>(ep, dst, cls, deg, myOff, st, N, E);
  scan1_kernel<<<nb, 256, 0, stream>>>(deg, bsum, nRows);
  scan2_kernel<<<1, 256, 0, stream>>>(bsum, nb);
  scan3_kernel<<<nb, 256, 0, stream>>>(deg, bsum, rowPtr, dinv, nRows);
  fill_kernel<<<eb, 256, 0, stream>>>(src, dst, cls, rowPtr, myOff, eSrc, N, E);

  // weight transpose+cast (tiny)
  wconv_kernel<<<(128 * 64 + 255) / 256, 256, 0, stream>>>(W1, Wt1, 128);
  wconv_kernel<<<(64 * 64 + 255) / 256, 256, 0, stream>>>(W2, Wt2, 64);
  wconv_kernel<<<(192 * 64 + 255) / 256, 256, 0, stream>>>(W3, Wt3, 192);

  const int gb = (N + 63) / 64;
  // h1 (bf16, temp in L1_bf) -> h (bf16)
  gemm_mfma_kernel<128, 0, 1><<<gb, 256, 0, stream>>>(feat, Wt1, b1, L1_bf, N, 0, 1);
  gemm_mfma_kernel<64, 1, 1><<<gb, 256, 0, stream>>>(L1_bf, Wt2, b2, h_bf, N, 0, 1);

  if (fused) {
    const int g3 = (nRows + 15) / 16;
    gather3_kernel<1><<<g3, 256, 0, stream>>>(h_bf, h_bf, L1_bf, rowPtr, eSrc, dinv, N, nRows);
    gather3_kernel<2><<<g3, 256, 0, stream>>>(L1_bf, h_bf, combo_bf, rowPtr, eSrc, dinv, N, nRows);
    gemm_mfma_kernel<192, 1, 0><<<gb, 256, 0, stream>>>(combo_bf, Wt3, b3, out, N, 0, 1);
  } else {
    const float chArr[3] = {0.f, 0.f, 3.f};
    const float c1Arr[3] = {0.f, 3.f, -3.f};
    const float c2Arr[3] = {0.75f, -1.5f, 0.75f};
    const int ggrid = (N + 15) / 16;
    for (int c = 0; c < 3; ++c) {
      const int* rp = rowPtr + (size_t)c * N;
      const float* dv = dinv + (size_t)c * N;
      gatherF_kernel<1><<<ggrid, 256, 0, stream>>>(h_bf, nullptr, L1_bf, rp, eSrc, dv,
                                                   0.f, 0.f, 0.f, N);
      gatherF_kernel<2><<<ggrid, 256, 0, stream>>>(L1_bf, h_bf, combo_bf, rp, eSrc, dv,
                                                   chArr[c], c1Arr[c], c2Arr[c], N);
      wconv_kernel<<<(64 * 64 + 255) / 256, 256, 0, stream>>>(W3 + (size_t)c * 64 * 64, Wt2, 64);
      gemm_mfma_kernel<64, 1, 0><<<gb, 256, 0, stream>>>(combo_bf, Wt2, b3, out,
                                                         N, c > 0 ? 1 : 0, c == 2 ? 1 : 0);
    }
  }
}

// Round 6
// 539.007 us; speedup vs baseline: 8.2058x; 1.0720x over previous
//
#include <hip/hip_runtime.h>
#include <cstdint>
#include <cstddef>

// ---------------------------------------------------------------------------
// GraphPartitionModule: quantile-masked 3-way edge partition -> per-class
// normalized-Laplacian powers (D=2) -> theta combination -> MLP head.
//
// R6: gather edge-loops unrolled 4x with two independent accumulator sets
// (memory-level parallelism: 4 row loads in flight per 16-lane group; the
// R5 serial chain left the gathers latency-bound at 30% HBM / 32% VALU).
// Everything else unchanged from R5.
// ---------------------------------------------------------------------------

#define WS_ALIGN(x) (((x) + 255) & ~(size_t)255)

typedef __attribute__((ext_vector_type(8))) short short8;
typedef __attribute__((ext_vector_type(4))) float floatx4;

struct QState {
  unsigned n_neg, n_pos;
  unsigned prefix_neg, prefix_pos;
  int rank_neg, rank_pos;
  float frac_neg, frac_pos;
  unsigned vnext_neg, vnext_pos;
  float thr_neg, thr_pos;
  int dup_neg, dup_pos;
  unsigned hist_neg[256];
  unsigned hist_pos[256];
};

// monotone float<->uint key mapping (ascending float == ascending key)
__device__ __forceinline__ unsigned f2key(float v) {
  unsigned u = __float_as_uint(v);
  return (u & 0x80000000u) ? ~u : (u | 0x80000000u);
}
__device__ __forceinline__ float key2f(unsigned k) {
  unsigned u = (k & 0x80000000u) ? (k ^ 0x80000000u) : ~k;
  return __uint_as_float(u);
}

__device__ __forceinline__ unsigned short bf16rn(float x) {   // fp32 -> bf16 RNE
  unsigned u = __float_as_uint(x);
  u = (u + 0x7FFFu + ((u >> 16) & 1u)) >> 16;
  return (unsigned short)u;
}
__device__ __forceinline__ float bf2f(unsigned short v) {
  return __uint_as_float(((unsigned)v) << 16);
}

__global__ __launch_bounds__(256) void qhist_kernel(const float* __restrict__ ep,
                                                    QState* st, int E, int round) {
  __shared__ unsigned hN[256], hP[256];
  hN[threadIdx.x] = 0u; hP[threadIdx.x] = 0u;
  __syncthreads();
  int shift = 24 - 8 * round;
  unsigned maskHi = 0u;
  if (round > 0) maskHi = 0xFFFFFFFFu << (shift + 8);
  unsigned pN = st->prefix_neg & maskHi;
  unsigned pP = st->prefix_pos & maskHi;
  int stride = gridDim.x * blockDim.x;
  for (int e = blockIdx.x * blockDim.x + threadIdx.x; e < E; e += stride) {
    float v = ep[e];
    unsigned key = f2key(v);
    if (v <= 0.f) {
      if ((key & maskHi) == pN) atomicAdd(&hN[(key >> shift) & 255], 1u);
    } else {
      if ((key & maskHi) == pP) atomicAdd(&hP[(key >> shift) & 255], 1u);
    }
  }
  __syncthreads();
  unsigned cN = hN[threadIdx.x], cP = hP[threadIdx.x];
  if (cN) atomicAdd(&st->hist_neg[threadIdx.x], cN);
  if (cP) atomicAdd(&st->hist_pos[threadIdx.x], cP);
}

// After round-0 hist: n_neg/n_pos = hist sums; compute ranks (f32 semantics
// matching jnp.nanquantile), do round-0 bucket select, re-zero hists.
__global__ __launch_bounds__(256) void qinit_kernel(QState* st) {
  __shared__ unsigned sN[256], sP[256], rN_[256], rP_[256];
  int t = threadIdx.x;
  unsigned hn = st->hist_neg[t], hp = st->hist_pos[t];
  sN[t] = hn; sP[t] = hp; rN_[t] = hn; rP_[t] = hp;
  __syncthreads();
  for (int off = 128; off > 0; off >>= 1) {
    if (t < off) { rN_[t] += rN_[t + off]; rP_[t] += rP_[t + off]; }
    __syncthreads();
  }
  if (t == 0) {
    unsigned nN = rN_[0], nP = rP_[0];
    st->n_neg = nN; st->n_pos = nP;
    float idxN = __fmul_rn(0.2f, (float)(nN - 1));
    float lowN = floorf(idxN);
    unsigned rn = (unsigned)(int)lowN;
    st->frac_neg = __fsub_rn(idxN, lowN);
    float idxP = __fmul_rn(0.8f, (float)(nP - 1));
    float lowP = floorf(idxP);
    unsigned rp = (unsigned)(int)lowP;
    st->frac_pos = __fsub_rn(idxP, lowP);
    st->vnext_neg = 0xFFFFFFFFu; st->vnext_pos = 0xFFFFFFFFu;
    {
      unsigned cum = 0, pref = 0;
      for (int b = 0; b < 256; ++b) {
        unsigned c = sN[b];
        if (rn < cum + c) { pref = ((unsigned)b) << 24; rn -= cum; break; }
        cum += c;
      }
      st->prefix_neg = pref; st->rank_neg = (int)rn;
    }
    {
      unsigned cum = 0, pref = 0;
      for (int b = 0; b < 256; ++b) {
        unsigned c = sP[b];
        if (rp < cum + c) { pref = ((unsigned)b) << 24; rp -= cum; break; }
        cum += c;
      }
      st->prefix_pos = pref; st->rank_pos = (int)rp;
    }
  }
  st->hist_neg[t] = 0u; st->hist_pos[t] = 0u;
}

__global__ void qupdate_kernel(QState* st, int round) {
  int shift = 24 - 8 * round;
  {
    unsigned cum = 0; unsigned r = (unsigned)st->rank_neg; unsigned pref = st->prefix_neg;
    for (int b = 0; b < 256; ++b) {
      unsigned c = st->hist_neg[b];
      if (r < cum + c) {
        pref |= ((unsigned)b) << shift; r -= cum;
        if (round == 3) st->dup_neg = (r + 1 < c) ? 1 : 0;
        break;
      }
      cum += c;
    }
    st->prefix_neg = pref; st->rank_neg = (int)r;
  }
  {
    unsigned cum = 0; unsigned r = (unsigned)st->rank_pos; unsigned pref = st->prefix_pos;
    for (int b = 0; b < 256; ++b) {
      unsigned c = st->hist_pos[b];
      if (r < cum + c) {
        pref |= ((unsigned)b) << shift; r -= cum;
        if (round == 3) st->dup_pos = (r + 1 < c) ? 1 : 0;
        break;
      }
      cum += c;
    }
    st->prefix_pos = pref; st->rank_pos = (int)r;
  }
  for (int i = 0; i < 256; ++i) { st->hist_neg[i] = 0u; st->hist_pos[i] = 0u; }
}

// min key strictly greater than the selected order statistic (register+wave min)
__global__ __launch_bounds__(256) void qvnext_kernel(const float* __restrict__ ep,
                                                     QState* st, int E) {
  unsigned pN = st->prefix_neg, pP = st->prefix_pos;
  unsigned mn = 0xFFFFFFFFu, mp = 0xFFFFFFFFu;
  int stride = gridDim.x * blockDim.x;
  for (int e = blockIdx.x * blockDim.x + threadIdx.x; e < E; e += stride) {
    float v = ep[e];
    unsigned key = f2key(v);
    if (v <= 0.f) { if (key > pN && key < mn) mn = key; }
    else          { if (key > pP && key < mp) mp = key; }
  }
#pragma unroll
  for (int off = 32; off > 0; off >>= 1) {
    unsigned a = (unsigned)__shfl_down((int)mn, off);
    unsigned b = (unsigned)__shfl_down((int)mp, off);
    mn = min(mn, a); mp = min(mp, b);
  }
  __shared__ unsigned wN[4], wP[4];
  int wid = threadIdx.x >> 6, lane = threadIdx.x & 63;
  if (lane == 0) { wN[wid] = mn; wP[wid] = mp; }
  __syncthreads();
  if (threadIdx.x == 0) {
    unsigned a = min(min(wN[0], wN[1]), min(wN[2], wN[3]));
    unsigned b = min(min(wP[0], wP[1]), min(wP[2], wP[3]));
    if (a != 0xFFFFFFFFu) atomicMin(&st->vnext_neg, a);
    if (b != 0xFFFFFFFFu) atomicMin(&st->vnext_pos, b);
  }
}

__global__ void qfinal_kernel(QState* st) {
  {
    float v0 = key2f(st->prefix_neg);
    float v1 = (st->dup_neg || st->vnext_neg == 0xFFFFFFFFu) ? v0 : key2f(st->vnext_neg);
    float f = st->frac_neg;
    st->thr_neg = (f > 0.f) ? __fadd_rn(v0, __fmul_rn(f, __fsub_rn(v1, v0))) : v0;
  }
  {
    float v0 = key2f(st->prefix_pos);
    float v1 = (st->dup_pos || st->vnext_pos == 0xFFFFFFFFu) ? v0 : key2f(st->vnext_pos);
    float f = st->frac_pos;
    st->thr_pos = (f > 0.f) ? __fadd_rn(v0, __fmul_rn(f, __fsub_rn(v1, v0))) : v0;
  }
}

// class per edge + per-(class,dst) in-degree histogram; record within-row slot
__global__ void cls_deg_kernel(const float* __restrict__ ep, const int* __restrict__ dst,
                               unsigned char* __restrict__ cls, int* __restrict__ deg,
                               int* __restrict__ myOff,
                               const QState* __restrict__ st, int N, int E) {
  int e = blockIdx.x * blockDim.x + threadIdx.x;
  if (e >= E) return;
  float thrN = st->thr_neg, thrP = st->thr_pos;
  float v = ep[e];
  int c = (v > thrP) ? 0 : ((v < thrN) ? 2 : 1);
  cls[e] = (unsigned char)c;
  myOff[e] = atomicAdd(&deg[c * N + dst[e]], 1);
}

// ---- 3-kernel exclusive scan over deg[3N] -> rowPtr, fused dinv ----
__global__ __launch_bounds__(256) void scan1_kernel(const int* __restrict__ deg,
                                                    int* __restrict__ bsum, int nRows) {
  __shared__ int s[256];
  int i = blockIdx.x * 256 + threadIdx.x;
  s[threadIdx.x] = (i < nRows) ? deg[i] : 0;
  __syncthreads();
  for (int off = 128; off > 0; off >>= 1) {
    if (threadIdx.x < off) s[threadIdx.x] += s[threadIdx.x + off];
    __syncthreads();
  }
  if (threadIdx.x == 0) bsum[blockIdx.x] = s[0];
}

__global__ __launch_bounds__(256) void scan2_kernel(int* __restrict__ bsum, int nb) {
  __shared__ int s[256];
  __shared__ int carry;
  if (threadIdx.x == 0) carry = 0;
  __syncthreads();
  for (int base = 0; base < nb; base += 256) {
    int i = base + threadIdx.x;
    int v = (i < nb) ? bsum[i] : 0;
    s[threadIdx.x] = v;
    __syncthreads();
    for (int off = 1; off < 256; off <<= 1) {
      int x = (threadIdx.x >= off) ? s[threadIdx.x - off] : 0;
      __syncthreads();
      s[threadIdx.x] += x;
      __syncthreads();
    }
    int excl = s[threadIdx.x] - v;
    int c = carry;
    if (i < nb) bsum[i] = c + excl;
    int tot = s[255];
    __syncthreads();
    if (threadIdx.x == 0) carry = c + tot;
    __syncthreads();
  }
}

__global__ __launch_bounds__(256) void scan3_kernel(const int* __restrict__ deg,
    const int* __restrict__ bsum, int* __restrict__ rowPtr,
    float* __restrict__ dinv, int nRows) {
  __shared__ int s[256];
  int i = blockIdx.x * 256 + threadIdx.x;
  int v = (i < nRows) ? deg[i] : 0;
  s[threadIdx.x] = v;
  __syncthreads();
  for (int off = 1; off < 256; off <<= 1) {
    int x = (threadIdx.x >= off) ? s[threadIdx.x - off] : 0;
    __syncthreads();
    s[threadIdx.x] += x;
    __syncthreads();
  }
  if (i < nRows) {
    int excl = bsum[blockIdx.x] + s[threadIdx.x] - v;
    rowPtr[i] = excl;
    dinv[i] = 1.f / sqrtf(fmaxf((float)v, 1.f));
    if (i == nRows - 1) rowPtr[nRows] = excl + v;
  }
}

// pure scatter: slot precomputed in cls_deg (no atomics)
__global__ void fill_kernel(const int* __restrict__ src, const int* __restrict__ dst,
                            const unsigned char* __restrict__ cls,
                            const int* __restrict__ rowPtr, const int* __restrict__ myOff,
                            int* __restrict__ eSrc, int N, int E) {
  int e = blockIdx.x * blockDim.x + threadIdx.x;
  if (e >= E) return;
  int row = (int)cls[e] * N + dst[e];
  eSrc[rowPtr[row] + myOff[e]] = src[e];
}

// Fused gather over all 3N (class,node) rows, bf16 data, fp32 accumulate.
// 16 lanes per row, ushort4 (4 bf16) per lane. Edge loop unrolled 4x with
// two accumulator sets: 4 row loads in flight per group (R6 MLP fix).
// STEP 1: f = h_bf [N,64] -> out L1_bf [3N,64]
// STEP 2: f = L1_bf [3N,64] -> out combo_bf [N,192] column block c
template<int STEP>
__global__ __launch_bounds__(256) void gather3_kernel(const unsigned short* __restrict__ f,
    const unsigned short* __restrict__ hb, unsigned short* __restrict__ outBuf,
    const int* __restrict__ rowPtr, const int* __restrict__ eSrc,
    const float* __restrict__ dinv, int N, int nRows) {
  int r = blockIdx.x * 16 + (threadIdx.x >> 4);
  if (r >= nRows) return;
  int l = threadIdx.x & 15;
  int c = r / N;
  int n = r - c * N;
  int beg = rowPtr[r], end = rowPtr[r + 1];
  const int cb = c * N;
  const int srcOfs = (STEP == 1) ? 0 : cb;   // L1_bf rows are class-offset
  float ax = 0.f, ay = 0.f, az = 0.f, aw = 0.f;
  float bx = 0.f, by = 0.f, bz = 0.f, bw = 0.f;
  int e = beg;
  for (; e + 4 <= end; e += 4) {
    int s0 = eSrc[e],     s1 = eSrc[e + 1];
    int s2 = eSrc[e + 2], s3 = eSrc[e + 3];
    float c0 = dinv[cb + s0], c1 = dinv[cb + s1];
    float c2 = dinv[cb + s2], c3 = dinv[cb + s3];
    ushort4 v0 = *(const ushort4*)&f[(size_t)(srcOfs + s0) * 64 + l * 4];
    ushort4 v1 = *(const ushort4*)&f[(size_t)(srcOfs + s1) * 64 + l * 4];
    ushort4 v2 = *(const ushort4*)&f[(size_t)(srcOfs + s2) * 64 + l * 4];
    ushort4 v3 = *(const ushort4*)&f[(size_t)(srcOfs + s3) * 64 + l * 4];
    ax += bf2f(v0.x) * c0; ay += bf2f(v0.y) * c0; az += bf2f(v0.z) * c0; aw += bf2f(v0.w) * c0;
    bx += bf2f(v1.x) * c1; by += bf2f(v1.y) * c1; bz += bf2f(v1.z) * c1; bw += bf2f(v1.w) * c1;
    ax += bf2f(v2.x) * c2; ay += bf2f(v2.y) * c2; az += bf2f(v2.z) * c2; aw += bf2f(v2.w) * c2;
    bx += bf2f(v3.x) * c3; by += bf2f(v3.y) * c3; bz += bf2f(v3.z) * c3; bw += bf2f(v3.w) * c3;
  }
  for (; e < end; ++e) {
    int s = eSrc[e];
    float sc = dinv[cb + s];
    ushort4 v = *(const ushort4*)&f[(size_t)(srcOfs + s) * 64 + l * 4];
    ax += bf2f(v.x) * sc; ay += bf2f(v.y) * sc;
    az += bf2f(v.z) * sc; aw += bf2f(v.w) * sc;
  }
  ax += bx; ay += by; az += bz; aw += bw;
  float di = dinv[r];
  if (STEP == 1) {
    ushort4 fv = *(const ushort4*)&f[(size_t)n * 64 + l * 4];
    ushort4 o;
    o.x = bf16rn(bf2f(fv.x) - di * ax);
    o.y = bf16rn(bf2f(fv.y) - di * ay);
    o.z = bf16rn(bf2f(fv.z) - di * az);
    o.w = bf16rn(bf2f(fv.w) - di * aw);
    *(ushort4*)&outBuf[(size_t)r * 64 + l * 4] = o;
  } else {
    const float chA[3] = {0.f, 0.f, 3.f};
    const float c1A[3] = {0.f, 3.f, -3.f};
    const float c2A[3] = {0.75f, -1.5f, 0.75f};
    float ch = chA[c], c1 = c1A[c], c2 = c2A[c];
    ushort4 fv = *(const ushort4*)&f[(size_t)r * 64 + l * 4];
    ushort4 hv = *(const ushort4*)&hb[(size_t)n * 64 + l * 4];
    float fx = bf2f(fv.x), fy = bf2f(fv.y), fz = bf2f(fv.z), fw = bf2f(fv.w);
    ushort4 o;
    o.x = bf16rn(ch * bf2f(hv.x) + c1 * fx + c2 * (fx - di * ax));
    o.y = bf16rn(ch * bf2f(hv.y) + c1 * fy + c2 * (fy - di * ay));
    o.z = bf16rn(ch * bf2f(hv.z) + c1 * fz + c2 * (fz - di * az));
    o.w = bf16rn(ch * bf2f(hv.w) + c1 * fw + c2 * (fw - di * aw));
    *(ushort4*)&outBuf[(size_t)n * 192 + c * 64 + l * 4] = o;
  }
}

// Per-class gather (fallback path), bf16 data, same 4x unroll
template<int STEP>
__global__ __launch_bounds__(256) void gatherF_kernel(const unsigned short* __restrict__ f,
    const unsigned short* __restrict__ hb, unsigned short* __restrict__ outBuf,
    const int* __restrict__ rowPtr, const int* __restrict__ eSrc,
    const float* __restrict__ dinv, float ch, float c1, float c2, int N) {
  int n = blockIdx.x * 16 + (threadIdx.x >> 4);
  if (n >= N) return;
  int l = threadIdx.x & 15;
  int beg = rowPtr[n], end = rowPtr[n + 1];
  float ax = 0.f, ay = 0.f, az = 0.f, aw = 0.f;
  float bx = 0.f, by = 0.f, bz = 0.f, bw = 0.f;
  int e = beg;
  for (; e + 4 <= end; e += 4) {
    int s0 = eSrc[e], s1 = eSrc[e + 1], s2 = eSrc[e + 2], s3 = eSrc[e + 3];
    float c0 = dinv[s0], c1_ = dinv[s1], c2_ = dinv[s2], c3 = dinv[s3];
    ushort4 v0 = *(const ushort4*)&f[(size_t)s0 * 64 + l * 4];
    ushort4 v1 = *(const ushort4*)&f[(size_t)s1 * 64 + l * 4];
    ushort4 v2 = *(const ushort4*)&f[(size_t)s2 * 64 + l * 4];
    ushort4 v3 = *(const ushort4*)&f[(size_t)s3 * 64 + l * 4];
    ax += bf2f(v0.x) * c0; ay += bf2f(v0.y) * c0; az += bf2f(v0.z) * c0; aw += bf2f(v0.w) * c0;
    bx += bf2f(v1.x) * c1_; by += bf2f(v1.y) * c1_; bz += bf2f(v1.z) * c1_; bw += bf2f(v1.w) * c1_;
    ax += bf2f(v2.x) * c2_; ay += bf2f(v2.y) * c2_; az += bf2f(v2.z) * c2_; aw += bf2f(v2.w) * c2_;
    bx += bf2f(v3.x) * c3; by += bf2f(v3.y) * c3; bz += bf2f(v3.z) * c3; bw += bf2f(v3.w) * c3;
  }
  for (; e < end; ++e) {
    int s = eSrc[e];
    float sc = dinv[s];
    ushort4 v = *(const ushort4*)&f[(size_t)s * 64 + l * 4];
    ax += bf2f(v.x) * sc; ay += bf2f(v.y) * sc;
    az += bf2f(v.z) * sc; aw += bf2f(v.w) * sc;
  }
  ax += bx; ay += by; az += bz; aw += bw;
  float di = dinv[n];
  size_t idx = (size_t)n * 64 + l * 4;
  ushort4 fv = *(const ushort4*)&f[idx];
  float fx = bf2f(fv.x), fy = bf2f(fv.y), fz = bf2f(fv.z), fw = bf2f(fv.w);
  ushort4 o;
  if (STEP == 1) {
    o.x = bf16rn(fx - di * ax); o.y = bf16rn(fy - di * ay);
    o.z = bf16rn(fz - di * az); o.w = bf16rn(fw - di * aw);
  } else {
    ushort4 hv = *(const ushort4*)&hb[idx];
    o.x = bf16rn(ch * bf2f(hv.x) + c1 * fx + c2 * (fx - di * ax));
    o.y = bf16rn(ch * bf2f(hv.y) + c1 * fy + c2 * (fy - di * ay));
    o.z = bf16rn(ch * bf2f(hv.z) + c1 * fz + c2 * (fz - di * az));
    o.w = bf16rn(ch * bf2f(hv.w) + c1 * fw + c2 * (fw - di * aw));
  }
  *(ushort4*)&outBuf[idx] = o;
}

// Wt[col*K + k] (bf16) = W[k*64 + col] (fp32) — weight transpose+cast, tiny.
__global__ void wconv_kernel(const float* __restrict__ W, unsigned short* __restrict__ Wt,
                             int K) {
  int i = blockIdx.x * 256 + threadIdx.x;
  if (i >= K * 64) return;
  int col = i / K, k = i - col * K;
  Wt[i] = bf16rn(W[(size_t)k * 64 + col]);
}

// C[N,64] = A[N,K] @ Wt^T (bf16), fp32 accum via MFMA 16x16x32.
// ABF: A is bf16 (else fp32, converted during staging). OBF: C is bf16.
template<int K, int ABF, int OBF>
__global__ __launch_bounds__(256) void gemm_mfma_kernel(const void* __restrict__ Ain,
    const unsigned short* __restrict__ Wt, const float* __restrict__ bias,
    void* __restrict__ Cout, int N, int accum, int finish) {
  __shared__ short As[64 * 40];
  const int tid = threadIdx.x;
  const int wave = tid >> 6, lane = tid & 63;
  const int m = lane & 15, quad = lane >> 4;
  const int rowBase = blockIdx.x * 64;
  floatx4 acc[4] = {{0.f,0.f,0.f,0.f},{0.f,0.f,0.f,0.f},{0.f,0.f,0.f,0.f},{0.f,0.f,0.f,0.f}};
  const int rs = tid >> 2;          // staging row 0..63
  const int cs = (tid & 3) * 8;     // staging col base 0/8/16/24
  const int rowS = rowBase + rs;
  const int aRow = (wave * 16 + m) * 40 + quad * 8;   // A-frag LDS offset
  for (int kc = 0; kc < K; kc += 32) {
    short8 s = {0,0,0,0,0,0,0,0};
    if (rowS < N) {
      if (ABF) {
        s = *(const short8*)((const unsigned short*)Ain + (size_t)rowS * K + kc + cs);
      } else {
        const float* p = (const float*)Ain + (size_t)rowS * K + kc + cs;
        float4 v0 = *(const float4*)p;
        float4 v1 = *(const float4*)(p + 4);
        s[0] = bf16rn(v0.x); s[1] = bf16rn(v0.y); s[2] = bf16rn(v0.z); s[3] = bf16rn(v0.w);
        s[4] = bf16rn(v1.x); s[5] = bf16rn(v1.y); s[6] = bf16rn(v1.z); s[7] = bf16rn(v1.w);
      }
    }
    *(short8*)&As[rs * 40 + cs] = s;
    __syncthreads();
    short8 af = *(const short8*)&As[aRow];
    const unsigned short* wp = Wt + (size_t)m * K + kc + quad * 8;
#pragma unroll
    for (int ct = 0; ct < 4; ++ct) {
      short8 bf = *(const short8*)(wp + (size_t)ct * 16 * K);
      acc[ct] = __builtin_amdgcn_mfma_f32_16x16x32_bf16(af, bf, acc[ct], 0, 0, 0);
    }
    __syncthreads();
  }
  const int r0 = rowBase + wave * 16 + quad * 4;
#pragma unroll
  for (int ct = 0; ct < 4; ++ct) {
    float b = finish ? bias[ct * 16 + m] : 0.f;
#pragma unroll
    for (int reg = 0; reg < 4; ++reg) {
      int row = r0 + reg;
      if (row < N) {
        float o = acc[ct][reg];
        if (OBF) {
          if (finish) o = fmaxf(o + b, 0.f);
          ((unsigned short*)Cout)[(size_t)row * 64 + ct * 16 + m] = bf16rn(o);
        } else {
          float* cp = (float*)Cout + (size_t)row * 64 + ct * 16 + m;
          if (accum) o += *cp;
          if (finish) o = fmaxf(o + b, 0.f);
          *cp = o;
        }
      }
    }
  }
}

extern "C" void kernel_launch(void* const* d_in, const int* in_sizes, int n_in,
                              void* d_out, int out_size, void* d_ws, size_t ws_size,
                              hipStream_t stream) {
  const float* feat = (const float*)d_in[0];
  const float* ep   = (const float*)d_in[1];
  const int*   src  = (const int*)d_in[2];
  const int*   dst  = (const int*)d_in[3];
  const float* W1   = (const float*)d_in[4];
  const float* b1   = (const float*)d_in[5];
  const float* W2   = (const float*)d_in[6];
  const float* b2   = (const float*)d_in[7];
  const float* W3   = (const float*)d_in[8];
  const float* b3   = (const float*)d_in[9];
  float* out = (float*)d_out;
  const int N = in_sizes[0] / 128;
  const int E = in_sizes[1];
  const int nRows = 3 * N;
  const int nb = (nRows + 255) / 256;

  char* w = (char*)d_ws;
  size_t off = 0;
  QState* st = (QState*)(w + off);           off += WS_ALIGN(sizeof(QState));
  int* deg = (int*)(w + off);                off += WS_ALIGN((size_t)nRows * 4);
  const size_t zeroBytes = off;              // state + deg zeroed together
  int* rowPtr = (int*)(w + off);             off += WS_ALIGN((size_t)(nRows + 1) * 4);
  float* dinv = (float*)(w + off);           off += WS_ALIGN((size_t)nRows * 4);
  int* bsum = (int*)(w + off);               off += WS_ALIGN((size_t)nb * 4);
  unsigned char* cls = (unsigned char*)(w + off); off += WS_ALIGN((size_t)E);
  int* myOff = (int*)(w + off);              off += WS_ALIGN((size_t)E * 4);
  int* eSrc = (int*)(w + off);               off += WS_ALIGN((size_t)E * 4);
  unsigned short* Wt1 = (unsigned short*)(w + off); off += WS_ALIGN((size_t)64 * 128 * 2);
  unsigned short* Wt2 = (unsigned short*)(w + off); off += WS_ALIGN((size_t)64 * 64 * 2);
  unsigned short* Wt3 = (unsigned short*)(w + off); off += WS_ALIGN((size_t)64 * 192 * 2);
  unsigned short* h_bf = (unsigned short*)(w + off); off += WS_ALIGN((size_t)N * 64 * 2);
  // fused: L1_bf [3N,64] + combo_bf [N,192]; fallback: L1 [N,64] + combo [N,64]
  const size_t fusedNeed = off + (size_t)nRows * 64 * 2 + (size_t)N * 192 * 2;
  const bool fused = (ws_size >= fusedNeed);
  unsigned short* L1_bf = (unsigned short*)(w + off);   // also temp for h1
  unsigned short* combo_bf = fused
      ? (unsigned short*)(w + off + WS_ALIGN((size_t)nRows * 64 * 2))
      : (unsigned short*)(w + off + WS_ALIGN((size_t)N * 64 * 2));
  (void)n_in; (void)out_size;

  hipMemsetAsync(d_ws, 0, zeroBytes, stream);

  const int eb = (E + 255) / 256;
  qhist_kernel<<<512, 256, 0, stream>>>(ep, st, E, 0);
  qinit_kernel<<<1, 256, 0, stream>>>(st);
  for (int r = 1; r < 4; ++r) {
    qhist_kernel<<<512, 256, 0, stream>>>(ep, st, E, r);
    qupdate_kernel<<<1, 1, 0, stream>>>(st, r);
  }
  qvnext_kernel<<<512, 256, 0, stream>>>(ep, st, E);
  qfinal_kernel<<<1, 1, 0, stream>>>(st);

  cls_deg_kernel<<<eb, 256, 0, stream>>>(ep, dst, cls, deg, myOff, st, N, E);
  scan1_kernel<<<nb, 256, 0, stream>>>(deg, bsum, nRows);
  scan2_kernel<<<1, 256, 0, stream>>>(bsum, nb);
  scan3_kernel<<<nb, 256, 0, stream>>>(deg, bsum, rowPtr, dinv, nRows);
  fill_kernel<<<eb, 256, 0, stream>>>(src, dst, cls, rowPtr, myOff, eSrc, N, E);

  // weight transpose+cast (tiny)
  wconv_kernel<<<(128 * 64 + 255) / 256, 256, 0, stream>>>(W1, Wt1, 128);
  wconv_kernel<<<(64 * 64 + 255) / 256, 256, 0, stream>>>(W2, Wt2, 64);
  wconv_kernel<<<(192 * 64 + 255) / 256, 256, 0, stream>>>(W3, Wt3, 192);

  const int gb = (N + 63) / 64;
  // h1 (bf16, temp in L1_bf) -> h (bf16)
  gemm_mfma_kernel<128, 0, 1><<<gb, 256, 0, stream>>>(feat, Wt1, b1, L1_bf, N, 0, 1);
  gemm_mfma_kernel<64, 1, 1><<<gb, 256, 0, stream>>>(L1_bf, Wt2, b2, h_bf, N, 0, 1);

  if (fused) {
    const int g3 = (nRows + 15) / 16;
    gather3_kernel<1><<<g3, 256, 0, stream>>>(h_bf, h_bf, L1_bf, rowPtr, eSrc, dinv, N, nRows);
    gather3_kernel<2><<<g3, 256, 0, stream>>>(L1_bf, h_bf, combo_bf, rowPtr, eSrc, dinv, N, nRows);
    gemm_mfma_kernel<192, 1, 0><<<gb, 256, 0, stream>>>(combo_bf, Wt3, b3, out, N, 0, 1);
  } else {
    const float chArr[3] = {0.f, 0.f, 3.f};
    const float c1Arr[3] = {0.f, 3.f, -3.f};
    const float c2Arr[3] = {0.75f, -1.5f, 0.75f};
    const int ggrid = (N + 15) / 16;
    for (int c = 0; c < 3; ++c) {
      const int* rp = rowPtr + (size_t)c * N;
      const float* dv = dinv + (size_t)c * N;
      gatherF_kernel<1><<<ggrid, 256, 0, stream>>>(h_bf, nullptr, L1_bf, rp, eSrc, dv,
                                                   0.f, 0.f, 0.f, N);
      gatherF_kernel<2><<<ggrid, 256, 0, stream>>>(L1_bf, h_bf, combo_bf, rp, eSrc, dv,
                                                   chArr[c], c1Arr[c], c2Arr[c], N);
      wconv_kernel<<<(64 * 64 + 255) / 256, 256, 0, stream>>>(W3 + (size_t)c * 64 * 64, Wt2, 64);
      gemm_mfma_kernel<64, 1, 0><<<gb, 256, 0, stream>>>(combo_bf, Wt2, b3, out,
                                                         N, c > 0 ? 1 : 0, c == 2 ? 1 : 0);
    }
  }
}

// Round 7
// 510.970 us; speedup vs baseline: 8.6561x; 1.0549x over previous
//
#include <hip/hip_runtime.h>
#include <cstdint>
#include <cstddef>

// ---------------------------------------------------------------------------
// GraphPartitionModule: quantile-masked 3-way edge partition -> per-class
// normalized-Laplacian powers (D=2) -> theta combination -> MLP head.
//
// R7: CSR build rebuilt as a bucket-staged multisplit (zero per-edge global
// atomics, no partial-line scatter):
//   count (LDS hist, per-block partials) -> scanA/scanB (bucket bases) ->
//   scatter (LDS cursors, L2-resident per-block regions) ->
//   build (per-bucket LDS counting sort -> coalesced deg/dinv/rowPtr/eSrc).
// Buckets = 512 consecutive rows, so bucket payloads are contiguous CSR
// segments. Replaces cls_deg (71us, 22.5G atomic/s fabric wall) + scans +
// fill (~51MB partial-line writes).
// Quantile radix-select, bf16 gathers (4x unrolled), MFMA GEMMs unchanged.
// ---------------------------------------------------------------------------

#define WS_ALIGN(x) (((x) + 255) & ~(size_t)255)
#define NBLK 256          // edge-streaming blocks for count/scatter (must match)
#define MAXNB 1024        // LDS cap: supports nRows <= 512*1024

typedef __attribute__((ext_vector_type(8))) short short8;
typedef __attribute__((ext_vector_type(4))) float floatx4;

struct QState {
  unsigned n_neg, n_pos;
  unsigned prefix_neg, prefix_pos;
  int rank_neg, rank_pos;
  float frac_neg, frac_pos;
  unsigned vnext_neg, vnext_pos;
  float thr_neg, thr_pos;
  int dup_neg, dup_pos;
  unsigned hist_neg[256];
  unsigned hist_pos[256];
};

// monotone float<->uint key mapping (ascending float == ascending key)
__device__ __forceinline__ unsigned f2key(float v) {
  unsigned u = __float_as_uint(v);
  return (u & 0x80000000u) ? ~u : (u | 0x80000000u);
}
__device__ __forceinline__ float key2f(unsigned k) {
  unsigned u = (k & 0x80000000u) ? (k ^ 0x80000000u) : ~k;
  return __uint_as_float(u);
}

__device__ __forceinline__ unsigned short bf16rn(float x) {   // fp32 -> bf16 RNE
  unsigned u = __float_as_uint(x);
  u = (u + 0x7FFFu + ((u >> 16) & 1u)) >> 16;
  return (unsigned short)u;
}
__device__ __forceinline__ float bf2f(unsigned short v) {
  return __uint_as_float(((unsigned)v) << 16);
}

// ======================= quantile radix-select (R3-proven) ==================
__global__ __launch_bounds__(256) void qhist_kernel(const float* __restrict__ ep,
                                                    QState* st, int E, int round) {
  __shared__ unsigned hN[256], hP[256];
  hN[threadIdx.x] = 0u; hP[threadIdx.x] = 0u;
  __syncthreads();
  int shift = 24 - 8 * round;
  unsigned maskHi = 0u;
  if (round > 0) maskHi = 0xFFFFFFFFu << (shift + 8);
  unsigned pN = st->prefix_neg & maskHi;
  unsigned pP = st->prefix_pos & maskHi;
  int stride = gridDim.x * blockDim.x;
  for (int e = blockIdx.x * blockDim.x + threadIdx.x; e < E; e += stride) {
    float v = ep[e];
    unsigned key = f2key(v);
    if (v <= 0.f) {
      if ((key & maskHi) == pN) atomicAdd(&hN[(key >> shift) & 255], 1u);
    } else {
      if ((key & maskHi) == pP) atomicAdd(&hP[(key >> shift) & 255], 1u);
    }
  }
  __syncthreads();
  unsigned cN = hN[threadIdx.x], cP = hP[threadIdx.x];
  if (cN) atomicAdd(&st->hist_neg[threadIdx.x], cN);
  if (cP) atomicAdd(&st->hist_pos[threadIdx.x], cP);
}

__global__ __launch_bounds__(256) void qinit_kernel(QState* st) {
  __shared__ unsigned sN[256], sP[256], rN_[256], rP_[256];
  int t = threadIdx.x;
  unsigned hn = st->hist_neg[t], hp = st->hist_pos[t];
  sN[t] = hn; sP[t] = hp; rN_[t] = hn; rP_[t] = hp;
  __syncthreads();
  for (int off = 128; off > 0; off >>= 1) {
    if (t < off) { rN_[t] += rN_[t + off]; rP_[t] += rP_[t + off]; }
    __syncthreads();
  }
  if (t == 0) {
    unsigned nN = rN_[0], nP = rP_[0];
    st->n_neg = nN; st->n_pos = nP;
    float idxN = __fmul_rn(0.2f, (float)(nN - 1));
    float lowN = floorf(idxN);
    unsigned rn = (unsigned)(int)lowN;
    st->frac_neg = __fsub_rn(idxN, lowN);
    float idxP = __fmul_rn(0.8f, (float)(nP - 1));
    float lowP = floorf(idxP);
    unsigned rp = (unsigned)(int)lowP;
    st->frac_pos = __fsub_rn(idxP, lowP);
    st->vnext_neg = 0xFFFFFFFFu; st->vnext_pos = 0xFFFFFFFFu;
    {
      unsigned cum = 0, pref = 0;
      for (int b = 0; b < 256; ++b) {
        unsigned c = sN[b];
        if (rn < cum + c) { pref = ((unsigned)b) << 24; rn -= cum; break; }
        cum += c;
      }
      st->prefix_neg = pref; st->rank_neg = (int)rn;
    }
    {
      unsigned cum = 0, pref = 0;
      for (int b = 0; b < 256; ++b) {
        unsigned c = sP[b];
        if (rp < cum + c) { pref = ((unsigned)b) << 24; rp -= cum; break; }
        cum += c;
      }
      st->prefix_pos = pref; st->rank_pos = (int)rp;
    }
  }
  st->hist_neg[t] = 0u; st->hist_pos[t] = 0u;
}

__global__ void qupdate_kernel(QState* st, int round) {
  int shift = 24 - 8 * round;
  {
    unsigned cum = 0; unsigned r = (unsigned)st->rank_neg; unsigned pref = st->prefix_neg;
    for (int b = 0; b < 256; ++b) {
      unsigned c = st->hist_neg[b];
      if (r < cum + c) {
        pref |= ((unsigned)b) << shift; r -= cum;
        if (round == 3) st->dup_neg = (r + 1 < c) ? 1 : 0;
        break;
      }
      cum += c;
    }
    st->prefix_neg = pref; st->rank_neg = (int)r;
  }
  {
    unsigned cum = 0; unsigned r = (unsigned)st->rank_pos; unsigned pref = st->prefix_pos;
    for (int b = 0; b < 256; ++b) {
      unsigned c = st->hist_pos[b];
      if (r < cum + c) {
        pref |= ((unsigned)b) << shift; r -= cum;
        if (round == 3) st->dup_pos = (r + 1 < c) ? 1 : 0;
        break;
      }
      cum += c;
    }
    st->prefix_pos = pref; st->rank_pos = (int)r;
  }
  for (int i = 0; i < 256; ++i) { st->hist_neg[i] = 0u; st->hist_pos[i] = 0u; }
}

__global__ __launch_bounds__(256) void qvnext_kernel(const float* __restrict__ ep,
                                                     QState* st, int E) {
  unsigned pN = st->prefix_neg, pP = st->prefix_pos;
  unsigned mn = 0xFFFFFFFFu, mp = 0xFFFFFFFFu;
  int stride = gridDim.x * blockDim.x;
  for (int e = blockIdx.x * blockDim.x + threadIdx.x; e < E; e += stride) {
    float v = ep[e];
    unsigned key = f2key(v);
    if (v <= 0.f) { if (key > pN && key < mn) mn = key; }
    else          { if (key > pP && key < mp) mp = key; }
  }
#pragma unroll
  for (int off = 32; off > 0; off >>= 1) {
    unsigned a = (unsigned)__shfl_down((int)mn, off);
    unsigned b = (unsigned)__shfl_down((int)mp, off);
    mn = min(mn, a); mp = min(mp, b);
  }
  __shared__ unsigned wN[4], wP[4];
  int wid = threadIdx.x >> 6, lane = threadIdx.x & 63;
  if (lane == 0) { wN[wid] = mn; wP[wid] = mp; }
  __syncthreads();
  if (threadIdx.x == 0) {
    unsigned a = min(min(wN[0], wN[1]), min(wN[2], wN[3]));
    unsigned b = min(min(wP[0], wP[1]), min(wP[2], wP[3]));
    if (a != 0xFFFFFFFFu) atomicMin(&st->vnext_neg, a);
    if (b != 0xFFFFFFFFu) atomicMin(&st->vnext_pos, b);
  }
}

__global__ void qfinal_kernel(QState* st) {
  {
    float v0 = key2f(st->prefix_neg);
    float v1 = (st->dup_neg || st->vnext_neg == 0xFFFFFFFFu) ? v0 : key2f(st->vnext_neg);
    float f = st->frac_neg;
    st->thr_neg = (f > 0.f) ? __fadd_rn(v0, __fmul_rn(f, __fsub_rn(v1, v0))) : v0;
  }
  {
    float v0 = key2f(st->prefix_pos);
    float v1 = (st->dup_pos || st->vnext_pos == 0xFFFFFFFFu) ? v0 : key2f(st->vnext_pos);
    float f = st->frac_pos;
    st->thr_pos = (f > 0.f) ? __fadd_rn(v0, __fmul_rn(f, __fsub_rn(v1, v0))) : v0;
  }
}

// ======================= bucket-staged CSR build (R7) =======================
// Buckets = 512 consecutive rows of the (class,dst) row space [0, 3N).

// K1: per-edge rowKey + per-block LDS bucket histograms -> global partials.
__global__ __launch_bounds__(256) void bucket_count(const float* __restrict__ ep,
    const int* __restrict__ dst, const QState* __restrict__ st,
    int* __restrict__ rowKey, int* __restrict__ part, int N, int E, int NB) {
  __shared__ unsigned hist[MAXNB];
  for (int i = threadIdx.x; i < NB; i += 256) hist[i] = 0u;
  __syncthreads();
  float thrN = st->thr_neg, thrP = st->thr_pos;
  const int stride = NBLK * 256;
  for (int e = blockIdx.x * 256 + threadIdx.x; e < E; e += stride) {
    float v = ep[e];
    int c = (v > thrP) ? 0 : ((v < thrN) ? 2 : 1);
    int row = c * N + dst[e];
    rowKey[e] = row;
    atomicAdd(&hist[row >> 9], 1u);
  }
  __syncthreads();
  for (int i = threadIdx.x; i < NB; i += 256)
    part[blockIdx.x * NB + i] = (int)hist[i];
}

// K2a: bucket totals + exclusive scan -> bucketPtr[0..NB].
__global__ __launch_bounds__(1024) void bucket_scanA(const int* __restrict__ part,
    int* __restrict__ bucketPtr, int NB) {
  __shared__ int s[1024];
  int t = threadIdx.x;
  int tot = 0;
  if (t < NB) {
#pragma unroll 4
    for (int blk = 0; blk < NBLK; ++blk) tot += part[blk * NB + t];
  }
  s[t] = tot;
  __syncthreads();
  for (int off = 1; off < 1024; off <<= 1) {
    int x = (t >= off) ? s[t - off] : 0;
    __syncthreads();
    s[t] += x;
    __syncthreads();
  }
  int excl = s[t] - tot;
  if (t < NB) bucketPtr[t] = excl;
  if (t == NB - 1) bucketPtr[NB] = excl + tot;
}

// K2b: per-(block,bucket) base via wave scan over the 256 block partials.
__global__ __launch_bounds__(64) void bucket_scanB(const int* __restrict__ part,
    const int* __restrict__ bucketPtr, int* __restrict__ baseArr, int NB) {
  int b = blockIdx.x;
  if (b >= NB) return;
  int l = threadIdx.x;                       // 0..63, 4 blocks each
  int p0 = part[(4 * l + 0) * NB + b];
  int p1 = part[(4 * l + 1) * NB + b];
  int p2 = part[(4 * l + 2) * NB + b];
  int p3 = part[(4 * l + 3) * NB + b];
  int mySum = p0 + p1 + p2 + p3;
  int v = mySum;
#pragma unroll
  for (int off = 1; off < 64; off <<= 1) {
    int x = __shfl_up(v, off);
    if (l >= off) v += x;
  }
  int base = bucketPtr[b] + (v - mySum);     // exclusive over blocks
  baseArr[(4 * l + 0) * NB + b] = base;
  baseArr[(4 * l + 1) * NB + b] = base + p0;
  baseArr[(4 * l + 2) * NB + b] = base + p0 + p1;
  baseArr[(4 * l + 3) * NB + b] = base + p0 + p1 + p2;
}

// K3: scatter (row,src) pairs into bucket-grouped staging. LDS cursors only;
// each block's write regions are contiguous per bucket and L2-resident.
__global__ __launch_bounds__(256) void bucket_scatter(const int* __restrict__ rowKey,
    const int* __restrict__ src, const int* __restrict__ baseArr,
    int2* __restrict__ staged, int E, int NB) {
  __shared__ int cur[MAXNB];
  for (int i = threadIdx.x; i < NB; i += 256)
    cur[i] = baseArr[blockIdx.x * NB + i];
  __syncthreads();
  const int stride = NBLK * 256;
  for (int e = blockIdx.x * 256 + threadIdx.x; e < E; e += stride) {
    int row = rowKey[e];
    int pos = atomicAdd(&cur[row >> 9], 1);
    staged[pos] = make_int2(row, src[e]);
  }
}

// K4: per-bucket counting sort -> deg/dinv/rowPtr coalesced, eSrc into the
// bucket's contiguous CSR segment. Reads staged twice (unbounded-safe).
__global__ __launch_bounds__(256) void bucket_build(const int2* __restrict__ staged,
    const int* __restrict__ bucketPtr, int* __restrict__ rowPtrG,
    float* __restrict__ dinv, int* __restrict__ eSrc, int nRows, int NB) {
  __shared__ int degL[512], excl2[512], cur[512], sb[256];
  int b = blockIdx.x;
  int lo = bucketPtr[b], hi = bucketPtr[b + 1];
  int rowBase = b << 9;
  int t = threadIdx.x;
  degL[t] = 0; degL[t + 256] = 0;
  __syncthreads();
  for (int e = lo + t; e < hi; e += 256)
    atomicAdd(&degL[staged[e].x - rowBase], 1);
  __syncthreads();
  int a0 = degL[2 * t], a1 = degL[2 * t + 1];
  sb[t] = a0 + a1;
  __syncthreads();
  for (int off = 1; off < 256; off <<= 1) {
    int x = (t >= off) ? sb[t - off] : 0;
    __syncthreads();
    sb[t] += x;
    __syncthreads();
  }
  int pairExcl = sb[t] - (a0 + a1);
  excl2[2 * t] = pairExcl;
  excl2[2 * t + 1] = pairExcl + a0;
  __syncthreads();
  for (int i = t; i < 512; i += 256) {
    int row = rowBase + i;
    if (row < nRows) {
      int base = lo + excl2[i];
      rowPtrG[row] = base;
      cur[i] = base;
      dinv[row] = 1.f / sqrtf(fmaxf((float)degL[i], 1.f));
    }
  }
  if (b == NB - 1 && t == 0) rowPtrG[nRows] = bucketPtr[NB];
  __syncthreads();
  for (int e = lo + t; e < hi; e += 256) {
    int2 p = staged[e];
    int pos = atomicAdd(&cur[p.x - rowBase], 1);
    eSrc[pos] = p.y;
  }
}

// ======================= propagation gathers (R6-proven) ====================
template<int STEP>
__global__ __launch_bounds__(256) void gather3_kernel(const unsigned short* __restrict__ f,
    const unsigned short* __restrict__ hb, unsigned short* __restrict__ outBuf,
    const int* __restrict__ rowPtr, const int* __restrict__ eSrc,
    const float* __restrict__ dinv, int N, int nRows) {
  int r = blockIdx.x * 16 + (threadIdx.x >> 4);
  if (r >= nRows) return;
  int l = threadIdx.x & 15;
  int c = r / N;
  int n = r - c * N;
  int beg = rowPtr[r], end = rowPtr[r + 1];
  const int cb = c * N;
  const int srcOfs = (STEP == 1) ? 0 : cb;   // L1_bf rows are class-offset
  float ax = 0.f, ay = 0.f, az = 0.f, aw = 0.f;
  float bx = 0.f, by = 0.f, bz = 0.f, bw = 0.f;
  int e = beg;
  for (; e + 4 <= end; e += 4) {
    int s0 = eSrc[e],     s1 = eSrc[e + 1];
    int s2 = eSrc[e + 2], s3 = eSrc[e + 3];
    float c0 = dinv[cb + s0], c1 = dinv[cb + s1];
    float c2 = dinv[cb + s2], c3 = dinv[cb + s3];
    ushort4 v0 = *(const ushort4*)&f[(size_t)(srcOfs + s0) * 64 + l * 4];
    ushort4 v1 = *(const ushort4*)&f[(size_t)(srcOfs + s1) * 64 + l * 4];
    ushort4 v2 = *(const ushort4*)&f[(size_t)(srcOfs + s2) * 64 + l * 4];
    ushort4 v3 = *(const ushort4*)&f[(size_t)(srcOfs + s3) * 64 + l * 4];
    ax += bf2f(v0.x) * c0; ay += bf2f(v0.y) * c0; az += bf2f(v0.z) * c0; aw += bf2f(v0.w) * c0;
    bx += bf2f(v1.x) * c1; by += bf2f(v1.y) * c1; bz += bf2f(v1.z) * c1; bw += bf2f(v1.w) * c1;
    ax += bf2f(v2.x) * c2; ay += bf2f(v2.y) * c2; az += bf2f(v2.z) * c2; aw += bf2f(v2.w) * c2;
    bx += bf2f(v3.x) * c3; by += bf2f(v3.y) * c3; bz += bf2f(v3.z) * c3; bw += bf2f(v3.w) * c3;
  }
  for (; e < end; ++e) {
    int s = eSrc[e];
    float sc = dinv[cb + s];
    ushort4 v = *(const ushort4*)&f[(size_t)(srcOfs + s) * 64 + l * 4];
    ax += bf2f(v.x) * sc; ay += bf2f(v.y) * sc;
    az += bf2f(v.z) * sc; aw += bf2f(v.w) * sc;
  }
  ax += bx; ay += by; az += bz; aw += bw;
  float di = dinv[r];
  if (STEP == 1) {
    ushort4 fv = *(const ushort4*)&f[(size_t)n * 64 + l * 4];
    ushort4 o;
    o.x = bf16rn(bf2f(fv.x) - di * ax);
    o.y = bf16rn(bf2f(fv.y) - di * ay);
    o.z = bf16rn(bf2f(fv.z) - di * az);
    o.w = bf16rn(bf2f(fv.w) - di * aw);
    *(ushort4*)&outBuf[(size_t)r * 64 + l * 4] = o;
  } else {
    const float chA[3] = {0.f, 0.f, 3.f};
    const float c1A[3] = {0.f, 3.f, -3.f};
    const float c2A[3] = {0.75f, -1.5f, 0.75f};
    float ch = chA[c], c1 = c1A[c], c2 = c2A[c];
    ushort4 fv = *(const ushort4*)&f[(size_t)r * 64 + l * 4];
    ushort4 hv = *(const ushort4*)&hb[(size_t)n * 64 + l * 4];
    float fx = bf2f(fv.x), fy = bf2f(fv.y), fz = bf2f(fv.z), fw = bf2f(fv.w);
    ushort4 o;
    o.x = bf16rn(ch * bf2f(hv.x) + c1 * fx + c2 * (fx - di * ax));
    o.y = bf16rn(ch * bf2f(hv.y) + c1 * fy + c2 * (fy - di * ay));
    o.z = bf16rn(ch * bf2f(hv.z) + c1 * fz + c2 * (fz - di * az));
    o.w = bf16rn(ch * bf2f(hv.w) + c1 * fw + c2 * (fw - di * aw));
    *(ushort4*)&outBuf[(size_t)n * 192 + c * 64 + l * 4] = o;
  }
}

// Per-class gather (fallback path), bf16 data, same 4x unroll
template<int STEP>
__global__ __launch_bounds__(256) void gatherF_kernel(const unsigned short* __restrict__ f,
    const unsigned short* __restrict__ hb, unsigned short* __restrict__ outBuf,
    const int* __restrict__ rowPtr, const int* __restrict__ eSrc,
    const float* __restrict__ dinv, float ch, float c1, float c2, int N) {
  int n = blockIdx.x * 16 + (threadIdx.x >> 4);
  if (n >= N) return;
  int l = threadIdx.x & 15;
  int beg = rowPtr[n], end = rowPtr[n + 1];
  float ax = 0.f, ay = 0.f, az = 0.f, aw = 0.f;
  float bx = 0.f, by = 0.f, bz = 0.f, bw = 0.f;
  int e = beg;
  for (; e + 4 <= end; e += 4) {
    int s0 = eSrc[e], s1 = eSrc[e + 1], s2 = eSrc[e + 2], s3 = eSrc[e + 3];
    float c0 = dinv[s0], c1_ = dinv[s1], c2_ = dinv[s2], c3 = dinv[s3];
    ushort4 v0 = *(const ushort4*)&f[(size_t)s0 * 64 + l * 4];
    ushort4 v1 = *(const ushort4*)&f[(size_t)s1 * 64 + l * 4];
    ushort4 v2 = *(const ushort4*)&f[(size_t)s2 * 64 + l * 4];
    ushort4 v3 = *(const ushort4*)&f[(size_t)s3 * 64 + l * 4];
    ax += bf2f(v0.x) * c0; ay += bf2f(v0.y) * c0; az += bf2f(v0.z) * c0; aw += bf2f(v0.w) * c0;
    bx += bf2f(v1.x) * c1_; by += bf2f(v1.y) * c1_; bz += bf2f(v1.z) * c1_; bw += bf2f(v1.w) * c1_;
    ax += bf2f(v2.x) * c2_; ay += bf2f(v2.y) * c2_; az += bf2f(v2.z) * c2_; aw += bf2f(v2.w) * c2_;
    bx += bf2f(v3.x) * c3; by += bf2f(v3.y) * c3; bz += bf2f(v3.z) * c3; bw += bf2f(v3.w) * c3;
  }
  for (; e < end; ++e) {
    int s = eSrc[e];
    float sc = dinv[s];
    ushort4 v = *(const ushort4*)&f[(size_t)s * 64 + l * 4];
    ax += bf2f(v.x) * sc; ay += bf2f(v.y) * sc;
    az += bf2f(v.z) * sc; aw += bf2f(v.w) * sc;
  }
  ax += bx; ay += by; az += bz; aw += bw;
  float di = dinv[n];
  size_t idx = (size_t)n * 64 + l * 4;
  ushort4 fv = *(const ushort4*)&f[idx];
  float fx = bf2f(fv.x), fy = bf2f(fv.y), fz = bf2f(fv.z), fw = bf2f(fv.w);
  ushort4 o;
  if (STEP == 1) {
    o.x = bf16rn(fx - di * ax); o.y = bf16rn(fy - di * ay);
    o.z = bf16rn(fz - di * az); o.w = bf16rn(fw - di * aw);
  } else {
    ushort4 hv = *(const ushort4*)&hb[idx];
    o.x = bf16rn(ch * bf2f(hv.x) + c1 * fx + c2 * (fx - di * ax));
    o.y = bf16rn(ch * bf2f(hv.y) + c1 * fy + c2 * (fy - di * ay));
    o.z = bf16rn(ch * bf2f(hv.z) + c1 * fz + c2 * (fz - di * az));
    o.w = bf16rn(ch * bf2f(hv.w) + c1 * fw + c2 * (fw - di * aw));
  }
  *(ushort4*)&outBuf[idx] = o;
}

// ======================= MFMA GEMMs (R5-proven) =============================
__global__ void wconv_kernel(const float* __restrict__ W, unsigned short* __restrict__ Wt,
                             int K) {
  int i = blockIdx.x * 256 + threadIdx.x;
  if (i >= K * 64) return;
  int col = i / K, k = i - col * K;
  Wt[i] = bf16rn(W[(size_t)k * 64 + col]);
}

template<int K, int ABF, int OBF>
__global__ __launch_bounds__(256) void gemm_mfma_kernel(const void* __restrict__ Ain,
    const unsigned short* __restrict__ Wt, const float* __restrict__ bias,
    void* __restrict__ Cout, int N, int accum, int finish) {
  __shared__ short As[64 * 40];
  const int tid = threadIdx.x;
  const int wave = tid >> 6, lane = tid & 63;
  const int m = lane & 15, quad = lane >> 4;
  const int rowBase = blockIdx.x * 64;
  floatx4 acc[4] = {{0.f,0.f,0.f,0.f},{0.f,0.f,0.f,0.f},{0.f,0.f,0.f,0.f},{0.f,0.f,0.f,0.f}};
  const int rs = tid >> 2;          // staging row 0..63
  const int cs = (tid & 3) * 8;     // staging col base 0/8/16/24
  const int rowS = rowBase + rs;
  const int aRow = (wave * 16 + m) * 40 + quad * 8;   // A-frag LDS offset
  for (int kc = 0; kc < K; kc += 32) {
    short8 s = {0,0,0,0,0,0,0,0};
    if (rowS < N) {
      if (ABF) {
        s = *(const short8*)((const unsigned short*)Ain + (size_t)rowS * K + kc + cs);
      } else {
        const float* p = (const float*)Ain + (size_t)rowS * K + kc + cs;
        float4 v0 = *(const float4*)p;
        float4 v1 = *(const float4*)(p + 4);
        s[0] = bf16rn(v0.x); s[1] = bf16rn(v0.y); s[2] = bf16rn(v0.z); s[3] = bf16rn(v0.w);
        s[4] = bf16rn(v1.x); s[5] = bf16rn(v1.y); s[6] = bf16rn(v1.z); s[7] = bf16rn(v1.w);
      }
    }
    *(short8*)&As[rs * 40 + cs] = s;
    __syncthreads();
    short8 af = *(const short8*)&As[aRow];
    const unsigned short* wp = Wt + (size_t)m * K + kc + quad * 8;
#pragma unroll
    for (int ct = 0; ct < 4; ++ct) {
      short8 bf = *(const short8*)(wp + (size_t)ct * 16 * K);
      acc[ct] = __builtin_amdgcn_mfma_f32_16x16x32_bf16(af, bf, acc[ct], 0, 0, 0);
    }
    __syncthreads();
  }
  const int r0 = rowBase + wave * 16 + quad * 4;
#pragma unroll
  for (int ct = 0; ct < 4; ++ct) {
    float b = finish ? bias[ct * 16 + m] : 0.f;
#pragma unroll
    for (int reg = 0; reg < 4; ++reg) {
      int row = r0 + reg;
      if (row < N) {
        float o = acc[ct][reg];
        if (OBF) {
          if (finish) o = fmaxf(o + b, 0.f);
          ((unsigned short*)Cout)[(size_t)row * 64 + ct * 16 + m] = bf16rn(o);
        } else {
          float* cp = (float*)Cout + (size_t)row * 64 + ct * 16 + m;
          if (accum) o += *cp;
          if (finish) o = fmaxf(o + b, 0.f);
          *cp = o;
        }
      }
    }
  }
}

extern "C" void kernel_launch(void* const* d_in, const int* in_sizes, int n_in,
                              void* d_out, int out_size, void* d_ws, size_t ws_size,
                              hipStream_t stream) {
  const float* feat = (const float*)d_in[0];
  const float* ep   = (const float*)d_in[1];
  const int*   src  = (const int*)d_in[2];
  const int*   dst  = (const int*)d_in[3];
  const float* W1   = (const float*)d_in[4];
  const float* b1   = (const float*)d_in[5];
  const float* W2   = (const float*)d_in[6];
  const float* b2   = (const float*)d_in[7];
  const float* W3   = (const float*)d_in[8];
  const float* b3   = (const float*)d_in[9];
  float* out = (float*)d_out;
  const int N = in_sizes[0] / 128;
  const int E = in_sizes[1];
  const int nRows = 3 * N;
  const int NB = (nRows + 511) >> 9;   // 512-row buckets; requires NB <= MAXNB

  char* w = (char*)d_ws;
  size_t off = 0;
  QState* st = (QState*)(w + off);           off += WS_ALIGN(sizeof(QState));
  const size_t zeroBytes = off;              // QState only
  int* rowPtr = (int*)(w + off);             off += WS_ALIGN((size_t)(nRows + 1) * 4);
  float* dinv = (float*)(w + off);           off += WS_ALIGN((size_t)nRows * 4);
  int* rowKey = (int*)(w + off);             off += WS_ALIGN((size_t)E * 4);
  int* partHist = (int*)(w + off);           off += WS_ALIGN((size_t)NBLK * NB * 4);
  int* baseArr = (int*)(w + off);            off += WS_ALIGN((size_t)NBLK * NB * 4);
  int* bucketPtr = (int*)(w + off);          off += WS_ALIGN((size_t)(NB + 1) * 4);
  int2* staged = (int2*)(w + off);           off += WS_ALIGN((size_t)E * 8);
  int* eSrc = (int*)(w + off);               off += WS_ALIGN((size_t)E * 4);
  unsigned short* Wt1 = (unsigned short*)(w + off); off += WS_ALIGN((size_t)64 * 128 * 2);
  unsigned short* Wt2 = (unsigned short*)(w + off); off += WS_ALIGN((size_t)64 * 64 * 2);
  unsigned short* Wt3 = (unsigned short*)(w + off); off += WS_ALIGN((size_t)64 * 192 * 2);
  unsigned short* h_bf = (unsigned short*)(w + off); off += WS_ALIGN((size_t)N * 64 * 2);
  // fused: L1_bf [3N,64] + combo_bf [N,192]; fallback: L1 [N,64] + combo [N,64]
  const size_t fusedNeed = off + (size_t)nRows * 64 * 2 + (size_t)N * 192 * 2;
  const bool fused = (ws_size >= fusedNeed);
  unsigned short* L1_bf = (unsigned short*)(w + off);   // also temp for h1
  unsigned short* combo_bf = fused
      ? (unsigned short*)(w + off + WS_ALIGN((size_t)nRows * 64 * 2))
      : (unsigned short*)(w + off + WS_ALIGN((size_t)N * 64 * 2));
  (void)n_in; (void)out_size;

  hipMemsetAsync(d_ws, 0, zeroBytes, stream);

  // ---- quantile thresholds (exact radix-select) ----
  qhist_kernel<<<512, 256, 0, stream>>>(ep, st, E, 0);
  qinit_kernel<<<1, 256, 0, stream>>>(st);
  for (int r = 1; r < 4; ++r) {
    qhist_kernel<<<512, 256, 0, stream>>>(ep, st, E, r);
    qupdate_kernel<<<1, 1, 0, stream>>>(st, r);
  }
  qvnext_kernel<<<512, 256, 0, stream>>>(ep, st, E);
  qfinal_kernel<<<1, 1, 0, stream>>>(st);

  // ---- weights + MLP (independent of edges) ----
  wconv_kernel<<<(128 * 64 + 255) / 256, 256, 0, stream>>>(W1, Wt1, 128);
  wconv_kernel<<<(64 * 64 + 255) / 256, 256, 0, stream>>>(W2, Wt2, 64);
  wconv_kernel<<<(192 * 64 + 255) / 256, 256, 0, stream>>>(W3, Wt3, 192);
  const int gb = (N + 63) / 64;
  gemm_mfma_kernel<128, 0, 1><<<gb, 256, 0, stream>>>(feat, Wt1, b1, L1_bf, N, 0, 1);
  gemm_mfma_kernel<64, 1, 1><<<gb, 256, 0, stream>>>(L1_bf, Wt2, b2, h_bf, N, 0, 1);

  // ---- bucket-staged CSR build ----
  bucket_count<<<NBLK, 256, 0, stream>>>(ep, dst, st, rowKey, partHist, N, E, NB);
  bucket_scanA<<<1, 1024, 0, stream>>>(partHist, bucketPtr, NB);
  bucket_scanB<<<NB, 64, 0, stream>>>(partHist, bucketPtr, baseArr, NB);
  bucket_scatter<<<NBLK, 256, 0, stream>>>(rowKey, src, baseArr, staged, E, NB);
  bucket_build<<<NB, 256, 0, stream>>>(staged, bucketPtr, rowPtr, dinv, eSrc, nRows, NB);

  // ---- propagation + head ----
  if (fused) {
    const int g3 = (nRows + 15) / 16;
    gather3_kernel<1><<<g3, 256, 0, stream>>>(h_bf, h_bf, L1_bf, rowPtr, eSrc, dinv, N, nRows);
    gather3_kernel<2><<<g3, 256, 0, stream>>>(L1_bf, h_bf, combo_bf, rowPtr, eSrc, dinv, N, nRows);
    gemm_mfma_kernel<192, 1, 0><<<gb, 256, 0, stream>>>(combo_bf, Wt3, b3, out, N, 0, 1);
  } else {
    const float chArr[3] = {0.f, 0.f, 3.f};
    const float c1Arr[3] = {0.f, 3.f, -3.f};
    const float c2Arr[3] = {0.75f, -1.5f, 0.75f};
    const int ggrid = (N + 15) / 16;
    for (int c = 0; c < 3; ++c) {
      const int* rp = rowPtr + (size_t)c * N;
      const float* dv = dinv + (size_t)c * N;
      gatherF_kernel<1><<<ggrid, 256, 0, stream>>>(h_bf, nullptr, L1_bf, rp, eSrc, dv,
                                                   0.f, 0.f, 0.f, N);
      gatherF_kernel<2><<<ggrid, 256, 0, stream>>>(L1_bf, h_bf, combo_bf, rp, eSrc, dv,
                                                   chArr[c], c1Arr[c], c2Arr[c], N);
      wconv_kernel<<<(64 * 64 + 255) / 256, 256, 0, stream>>>(W3 + (size_t)c * 64 * 64, Wt2, 64);
      gemm_mfma_kernel<64, 1, 0><<<gb, 256, 0, stream>>>(combo_bf, Wt2, b3, out,
                                                         N, c > 0 ? 1 : 0, c == 2 ? 1 : 0);
    }
  }
}

// Round 8
// 502.983 us; speedup vs baseline: 8.7935x; 1.0159x over previous
//
#include <hip/hip_runtime.h>
#include <cstdint>
#include <cstddef>

// ---------------------------------------------------------------------------
// GraphPartitionModule: quantile-masked 3-way edge partition -> per-class
// normalized-Laplacian powers (D=2) -> theta combination -> MLP head.
//
// R8:
//  - gather3: each 16-lane group processes TWO rows jointly (independent
//    accumulators; 2-4 loads in flight even for short rows; divergence
//    waste max-of-4 ~1.7x -> ~1.3x). Avg degree is only 5.3 so the R6
//    4x unroll rarely fired.
//  - gemm_mfma: 128-row tiles (2 A-frags/wave, 8 MFMA per barrier pair,
//    half the barriers per output element) - the three GEMMs were the
//    hidden ~150us in the R7 profile gap.
//  - wconv x3 merged into one launch.
// Quantile radix-select + bucket-staged CSR unchanged (R7-proven).
// ---------------------------------------------------------------------------

#define WS_ALIGN(x) (((x) + 255) & ~(size_t)255)
#define NBLK 256          // edge-streaming blocks for count/scatter (must match)
#define MAXNB 1024        // LDS cap: supports nRows <= 512*1024

typedef __attribute__((ext_vector_type(8))) short short8;
typedef __attribute__((ext_vector_type(4))) float floatx4;

struct QState {
  unsigned n_neg, n_pos;
  unsigned prefix_neg, prefix_pos;
  int rank_neg, rank_pos;
  float frac_neg, frac_pos;
  unsigned vnext_neg, vnext_pos;
  float thr_neg, thr_pos;
  int dup_neg, dup_pos;
  unsigned hist_neg[256];
  unsigned hist_pos[256];
};

// monotone float<->uint key mapping (ascending float == ascending key)
__device__ __forceinline__ unsigned f2key(float v) {
  unsigned u = __float_as_uint(v);
  return (u & 0x80000000u) ? ~u : (u | 0x80000000u);
}
__device__ __forceinline__ float key2f(unsigned k) {
  unsigned u = (k & 0x80000000u) ? (k ^ 0x80000000u) : ~k;
  return __uint_as_float(u);
}

__device__ __forceinline__ unsigned short bf16rn(float x) {   // fp32 -> bf16 RNE
  unsigned u = __float_as_uint(x);
  u = (u + 0x7FFFu + ((u >> 16) & 1u)) >> 16;
  return (unsigned short)u;
}
__device__ __forceinline__ float bf2f(unsigned short v) {
  return __uint_as_float(((unsigned)v) << 16);
}

// ======================= quantile radix-select (R3-proven) ==================
__global__ __launch_bounds__(256) void qhist_kernel(const float* __restrict__ ep,
                                                    QState* st, int E, int round) {
  __shared__ unsigned hN[256], hP[256];
  hN[threadIdx.x] = 0u; hP[threadIdx.x] = 0u;
  __syncthreads();
  int shift = 24 - 8 * round;
  unsigned maskHi = 0u;
  if (round > 0) maskHi = 0xFFFFFFFFu << (shift + 8);
  unsigned pN = st->prefix_neg & maskHi;
  unsigned pP = st->prefix_pos & maskHi;
  int stride = gridDim.x * blockDim.x;
  for (int e = blockIdx.x * blockDim.x + threadIdx.x; e < E; e += stride) {
    float v = ep[e];
    unsigned key = f2key(v);
    if (v <= 0.f) {
      if ((key & maskHi) == pN) atomicAdd(&hN[(key >> shift) & 255], 1u);
    } else {
      if ((key & maskHi) == pP) atomicAdd(&hP[(key >> shift) & 255], 1u);
    }
  }
  __syncthreads();
  unsigned cN = hN[threadIdx.x], cP = hP[threadIdx.x];
  if (cN) atomicAdd(&st->hist_neg[threadIdx.x], cN);
  if (cP) atomicAdd(&st->hist_pos[threadIdx.x], cP);
}

__global__ __launch_bounds__(256) void qinit_kernel(QState* st) {
  __shared__ unsigned sN[256], sP[256], rN_[256], rP_[256];
  int t = threadIdx.x;
  unsigned hn = st->hist_neg[t], hp = st->hist_pos[t];
  sN[t] = hn; sP[t] = hp; rN_[t] = hn; rP_[t] = hp;
  __syncthreads();
  for (int off = 128; off > 0; off >>= 1) {
    if (t < off) { rN_[t] += rN_[t + off]; rP_[t] += rP_[t + off]; }
    __syncthreads();
  }
  if (t == 0) {
    unsigned nN = rN_[0], nP = rP_[0];
    st->n_neg = nN; st->n_pos = nP;
    float idxN = __fmul_rn(0.2f, (float)(nN - 1));
    float lowN = floorf(idxN);
    unsigned rn = (unsigned)(int)lowN;
    st->frac_neg = __fsub_rn(idxN, lowN);
    float idxP = __fmul_rn(0.8f, (float)(nP - 1));
    float lowP = floorf(idxP);
    unsigned rp = (unsigned)(int)lowP;
    st->frac_pos = __fsub_rn(idxP, lowP);
    st->vnext_neg = 0xFFFFFFFFu; st->vnext_pos = 0xFFFFFFFFu;
    {
      unsigned cum = 0, pref = 0;
      for (int b = 0; b < 256; ++b) {
        unsigned c = sN[b];
        if (rn < cum + c) { pref = ((unsigned)b) << 24; rn -= cum; break; }
        cum += c;
      }
      st->prefix_neg = pref; st->rank_neg = (int)rn;
    }
    {
      unsigned cum = 0, pref = 0;
      for (int b = 0; b < 256; ++b) {
        unsigned c = sP[b];
        if (rp < cum + c) { pref = ((unsigned)b) << 24; rp -= cum; break; }
        cum += c;
      }
      st->prefix_pos = pref; st->rank_pos = (int)rp;
    }
  }
  st->hist_neg[t] = 0u; st->hist_pos[t] = 0u;
}

__global__ void qupdate_kernel(QState* st, int round) {
  int shift = 24 - 8 * round;
  {
    unsigned cum = 0; unsigned r = (unsigned)st->rank_neg; unsigned pref = st->prefix_neg;
    for (int b = 0; b < 256; ++b) {
      unsigned c = st->hist_neg[b];
      if (r < cum + c) {
        pref |= ((unsigned)b) << shift; r -= cum;
        if (round == 3) st->dup_neg = (r + 1 < c) ? 1 : 0;
        break;
      }
      cum += c;
    }
    st->prefix_neg = pref; st->rank_neg = (int)r;
  }
  {
    unsigned cum = 0; unsigned r = (unsigned)st->rank_pos; unsigned pref = st->prefix_pos;
    for (int b = 0; b < 256; ++b) {
      unsigned c = st->hist_pos[b];
      if (r < cum + c) {
        pref |= ((unsigned)b) << shift; r -= cum;
        if (round == 3) st->dup_pos = (r + 1 < c) ? 1 : 0;
        break;
      }
      cum += c;
    }
    st->prefix_pos = pref; st->rank_pos = (int)r;
  }
  for (int i = 0; i < 256; ++i) { st->hist_neg[i] = 0u; st->hist_pos[i] = 0u; }
}

__global__ __launch_bounds__(256) void qvnext_kernel(const float* __restrict__ ep,
                                                     QState* st, int E) {
  unsigned pN = st->prefix_neg, pP = st->prefix_pos;
  unsigned mn = 0xFFFFFFFFu, mp = 0xFFFFFFFFu;
  int stride = gridDim.x * blockDim.x;
  for (int e = blockIdx.x * blockDim.x + threadIdx.x; e < E; e += stride) {
    float v = ep[e];
    unsigned key = f2key(v);
    if (v <= 0.f) { if (key > pN && key < mn) mn = key; }
    else          { if (key > pP && key < mp) mp = key; }
  }
#pragma unroll
  for (int off = 32; off > 0; off >>= 1) {
    unsigned a = (unsigned)__shfl_down((int)mn, off);
    unsigned b = (unsigned)__shfl_down((int)mp, off);
    mn = min(mn, a); mp = min(mp, b);
  }
  __shared__ unsigned wN[4], wP[4];
  int wid = threadIdx.x >> 6, lane = threadIdx.x & 63;
  if (lane == 0) { wN[wid] = mn; wP[wid] = mp; }
  __syncthreads();
  if (threadIdx.x == 0) {
    unsigned a = min(min(wN[0], wN[1]), min(wN[2], wN[3]));
    unsigned b = min(min(wP[0], wP[1]), min(wP[2], wP[3]));
    if (a != 0xFFFFFFFFu) atomicMin(&st->vnext_neg, a);
    if (b != 0xFFFFFFFFu) atomicMin(&st->vnext_pos, b);
  }
}

__global__ void qfinal_kernel(QState* st) {
  {
    float v0 = key2f(st->prefix_neg);
    float v1 = (st->dup_neg || st->vnext_neg == 0xFFFFFFFFu) ? v0 : key2f(st->vnext_neg);
    float f = st->frac_neg;
    st->thr_neg = (f > 0.f) ? __fadd_rn(v0, __fmul_rn(f, __fsub_rn(v1, v0))) : v0;
  }
  {
    float v0 = key2f(st->prefix_pos);
    float v1 = (st->dup_pos || st->vnext_pos == 0xFFFFFFFFu) ? v0 : key2f(st->vnext_pos);
    float f = st->frac_pos;
    st->thr_pos = (f > 0.f) ? __fadd_rn(v0, __fmul_rn(f, __fsub_rn(v1, v0))) : v0;
  }
}

// ======================= bucket-staged CSR build (R7-proven) ================
__global__ __launch_bounds__(256) void bucket_count(const float* __restrict__ ep,
    const int* __restrict__ dst, const QState* __restrict__ st,
    int* __restrict__ rowKey, int* __restrict__ part, int N, int E, int NB) {
  __shared__ unsigned hist[MAXNB];
  for (int i = threadIdx.x; i < NB; i += 256) hist[i] = 0u;
  __syncthreads();
  float thrN = st->thr_neg, thrP = st->thr_pos;
  const int stride = NBLK * 256;
  for (int e = blockIdx.x * 256 + threadIdx.x; e < E; e += stride) {
    float v = ep[e];
    int c = (v > thrP) ? 0 : ((v < thrN) ? 2 : 1);
    int row = c * N + dst[e];
    rowKey[e] = row;
    atomicAdd(&hist[row >> 9], 1u);
  }
  __syncthreads();
  for (int i = threadIdx.x; i < NB; i += 256)
    part[blockIdx.x * NB + i] = (int)hist[i];
}

__global__ __launch_bounds__(1024) void bucket_scanA(const int* __restrict__ part,
    int* __restrict__ bucketPtr, int NB) {
  __shared__ int s[1024];
  int t = threadIdx.x;
  int tot = 0;
  if (t < NB) {
#pragma unroll 4
    for (int blk = 0; blk < NBLK; ++blk) tot += part[blk * NB + t];
  }
  s[t] = tot;
  __syncthreads();
  for (int off = 1; off < 1024; off <<= 1) {
    int x = (t >= off) ? s[t - off] : 0;
    __syncthreads();
    s[t] += x;
    __syncthreads();
  }
  int excl = s[t] - tot;
  if (t < NB) bucketPtr[t] = excl;
  if (t == NB - 1) bucketPtr[NB] = excl + tot;
}

__global__ __launch_bounds__(64) void bucket_scanB(const int* __restrict__ part,
    const int* __restrict__ bucketPtr, int* __restrict__ baseArr, int NB) {
  int b = blockIdx.x;
  if (b >= NB) return;
  int l = threadIdx.x;                       // 0..63, 4 blocks each
  int p0 = part[(4 * l + 0) * NB + b];
  int p1 = part[(4 * l + 1) * NB + b];
  int p2 = part[(4 * l + 2) * NB + b];
  int p3 = part[(4 * l + 3) * NB + b];
  int mySum = p0 + p1 + p2 + p3;
  int v = mySum;
#pragma unroll
  for (int off = 1; off < 64; off <<= 1) {
    int x = __shfl_up(v, off);
    if (l >= off) v += x;
  }
  int base = bucketPtr[b] + (v - mySum);     // exclusive over blocks
  baseArr[(4 * l + 0) * NB + b] = base;
  baseArr[(4 * l + 1) * NB + b] = base + p0;
  baseArr[(4 * l + 2) * NB + b] = base + p0 + p1;
  baseArr[(4 * l + 3) * NB + b] = base + p0 + p1 + p2;
}

__global__ __launch_bounds__(256) void bucket_scatter(const int* __restrict__ rowKey,
    const int* __restrict__ src, const int* __restrict__ baseArr,
    int2* __restrict__ staged, int E, int NB) {
  __shared__ int cur[MAXNB];
  for (int i = threadIdx.x; i < NB; i += 256)
    cur[i] = baseArr[blockIdx.x * NB + i];
  __syncthreads();
  const int stride = NBLK * 256;
  for (int e = blockIdx.x * 256 + threadIdx.x; e < E; e += stride) {
    int row = rowKey[e];
    int pos = atomicAdd(&cur[row >> 9], 1);
    staged[pos] = make_int2(row, src[e]);
  }
}

__global__ __launch_bounds__(256) void bucket_build(const int2* __restrict__ staged,
    const int* __restrict__ bucketPtr, int* __restrict__ rowPtrG,
    float* __restrict__ dinv, int* __restrict__ eSrc, int nRows, int NB) {
  __shared__ int degL[512], excl2[512], cur[512], sb[256];
  int b = blockIdx.x;
  int lo = bucketPtr[b], hi = bucketPtr[b + 1];
  int rowBase = b << 9;
  int t = threadIdx.x;
  degL[t] = 0; degL[t + 256] = 0;
  __syncthreads();
  for (int e = lo + t; e < hi; e += 256)
    atomicAdd(&degL[staged[e].x - rowBase], 1);
  __syncthreads();
  int a0 = degL[2 * t], a1 = degL[2 * t + 1];
  sb[t] = a0 + a1;
  __syncthreads();
  for (int off = 1; off < 256; off <<= 1) {
    int x = (t >= off) ? sb[t - off] : 0;
    __syncthreads();
    sb[t] += x;
    __syncthreads();
  }
  int pairExcl = sb[t] - (a0 + a1);
  excl2[2 * t] = pairExcl;
  excl2[2 * t + 1] = pairExcl + a0;
  __syncthreads();
  for (int i = t; i < 512; i += 256) {
    int row = rowBase + i;
    if (row < nRows) {
      int base = lo + excl2[i];
      rowPtrG[row] = base;
      cur[i] = base;
      dinv[row] = 1.f / sqrtf(fmaxf((float)degL[i], 1.f));
    }
  }
  if (b == NB - 1 && t == 0) rowPtrG[nRows] = bucketPtr[NB];
  __syncthreads();
  for (int e = lo + t; e < hi; e += 256) {
    int2 p = staged[e];
    int pos = atomicAdd(&cur[p.x - rowBase], 1);
    eSrc[pos] = p.y;
  }
}

// ======================= propagation gathers (R8: dual-row groups) ==========
// Each 16-lane group processes rows rA=2g, rB=2g+1 with independent fp32
// accumulators; joint loop keeps 2-4 row loads in flight even for short rows.
// STEP 1: f = h_bf [N,64] -> out L1_bf [3N,64]
// STEP 2: f = L1_bf [3N,64] -> out combo_bf [N,192] column block c
template<int STEP>
__global__ __launch_bounds__(256) void gather3_kernel(const unsigned short* __restrict__ f,
    const unsigned short* __restrict__ hb, unsigned short* __restrict__ outBuf,
    const int* __restrict__ rowPtr, const int* __restrict__ eSrc,
    const float* __restrict__ dinv, int N, int nRows) {
  const int g = blockIdx.x * 16 + (threadIdx.x >> 4);
  const int rA = 2 * g, rB = rA + 1;
  if (rA >= nRows) return;
  const bool hasB = (rB < nRows);
  const int l4 = (threadIdx.x & 15) * 4;
  const int cA = rA / N, nA = rA - cA * N, cbA = cA * N;
  const int cB = hasB ? rB / N : 0;
  const int nB = hasB ? rB - cB * N : 0, cbB = cB * N;
  const int soA = (STEP == 1) ? 0 : cbA;
  const int soB = (STEP == 1) ? 0 : cbB;
  int eA = rowPtr[rA], endA = rowPtr[rA + 1];
  int eB = hasB ? rowPtr[rB] : 0;
  int endB = hasB ? rowPtr[rB + 1] : 0;
  float aAx = 0.f, aAy = 0.f, aAz = 0.f, aAw = 0.f;
  float aBx = 0.f, aBy = 0.f, aBz = 0.f, aBw = 0.f;
  // joint 2A + 2B (4 loads in flight)
  while (eA + 2 <= endA && eB + 2 <= endB) {
    int s0 = eSrc[eA], s1 = eSrc[eA + 1];
    int s2 = eSrc[eB], s3 = eSrc[eB + 1];
    float d0 = dinv[cbA + s0], d1 = dinv[cbA + s1];
    float d2 = dinv[cbB + s2], d3 = dinv[cbB + s3];
    ushort4 v0 = *(const ushort4*)&f[(size_t)(soA + s0) * 64 + l4];
    ushort4 v1 = *(const ushort4*)&f[(size_t)(soA + s1) * 64 + l4];
    ushort4 v2 = *(const ushort4*)&f[(size_t)(soB + s2) * 64 + l4];
    ushort4 v3 = *(const ushort4*)&f[(size_t)(soB + s3) * 64 + l4];
    aAx += bf2f(v0.x) * d0; aAy += bf2f(v0.y) * d0; aAz += bf2f(v0.z) * d0; aAw += bf2f(v0.w) * d0;
    aAx += bf2f(v1.x) * d1; aAy += bf2f(v1.y) * d1; aAz += bf2f(v1.z) * d1; aAw += bf2f(v1.w) * d1;
    aBx += bf2f(v2.x) * d2; aBy += bf2f(v2.y) * d2; aBz += bf2f(v2.z) * d2; aBw += bf2f(v2.w) * d2;
    aBx += bf2f(v3.x) * d3; aBy += bf2f(v3.y) * d3; aBz += bf2f(v3.z) * d3; aBw += bf2f(v3.w) * d3;
    eA += 2; eB += 2;
  }
  // joint 1A + 1B
  while (eA < endA && eB < endB) {
    int s0 = eSrc[eA], s2 = eSrc[eB];
    float d0 = dinv[cbA + s0], d2 = dinv[cbB + s2];
    ushort4 v0 = *(const ushort4*)&f[(size_t)(soA + s0) * 64 + l4];
    ushort4 v2 = *(const ushort4*)&f[(size_t)(soB + s2) * 64 + l4];
    aAx += bf2f(v0.x) * d0; aAy += bf2f(v0.y) * d0; aAz += bf2f(v0.z) * d0; aAw += bf2f(v0.w) * d0;
    aBx += bf2f(v2.x) * d2; aBy += bf2f(v2.y) * d2; aBz += bf2f(v2.z) * d2; aBw += bf2f(v2.w) * d2;
    ++eA; ++eB;
  }
  // tail A (2x unrolled)
  for (; eA + 2 <= endA; eA += 2) {
    int s0 = eSrc[eA], s1 = eSrc[eA + 1];
    float d0 = dinv[cbA + s0], d1 = dinv[cbA + s1];
    ushort4 v0 = *(const ushort4*)&f[(size_t)(soA + s0) * 64 + l4];
    ushort4 v1 = *(const ushort4*)&f[(size_t)(soA + s1) * 64 + l4];
    aAx += bf2f(v0.x) * d0; aAy += bf2f(v0.y) * d0; aAz += bf2f(v0.z) * d0; aAw += bf2f(v0.w) * d0;
    aAx += bf2f(v1.x) * d1; aAy += bf2f(v1.y) * d1; aAz += bf2f(v1.z) * d1; aAw += bf2f(v1.w) * d1;
  }
  for (; eA < endA; ++eA) {
    int s0 = eSrc[eA];
    float d0 = dinv[cbA + s0];
    ushort4 v0 = *(const ushort4*)&f[(size_t)(soA + s0) * 64 + l4];
    aAx += bf2f(v0.x) * d0; aAy += bf2f(v0.y) * d0; aAz += bf2f(v0.z) * d0; aAw += bf2f(v0.w) * d0;
  }
  // tail B (2x unrolled)
  for (; eB + 2 <= endB; eB += 2) {
    int s2 = eSrc[eB], s3 = eSrc[eB + 1];
    float d2 = dinv[cbB + s2], d3 = dinv[cbB + s3];
    ushort4 v2 = *(const ushort4*)&f[(size_t)(soB + s2) * 64 + l4];
    ushort4 v3 = *(const ushort4*)&f[(size_t)(soB + s3) * 64 + l4];
    aBx += bf2f(v2.x) * d2; aBy += bf2f(v2.y) * d2; aBz += bf2f(v2.z) * d2; aBw += bf2f(v2.w) * d2;
    aBx += bf2f(v3.x) * d3; aBy += bf2f(v3.y) * d3; aBz += bf2f(v3.z) * d3; aBw += bf2f(v3.w) * d3;
  }
  for (; eB < endB; ++eB) {
    int s2 = eSrc[eB];
    float d2 = dinv[cbB + s2];
    ushort4 v2 = *(const ushort4*)&f[(size_t)(soB + s2) * 64 + l4];
    aBx += bf2f(v2.x) * d2; aBy += bf2f(v2.y) * d2; aBz += bf2f(v2.z) * d2; aBw += bf2f(v2.w) * d2;
  }
  const float chA_[3] = {0.f, 0.f, 3.f};
  const float c1A_[3] = {0.f, 3.f, -3.f};
  const float c2A_[3] = {0.75f, -1.5f, 0.75f};
  {
    float di = dinv[rA];
    if (STEP == 1) {
      ushort4 fv = *(const ushort4*)&f[(size_t)nA * 64 + l4];
      ushort4 o;
      o.x = bf16rn(bf2f(fv.x) - di * aAx);
      o.y = bf16rn(bf2f(fv.y) - di * aAy);
      o.z = bf16rn(bf2f(fv.z) - di * aAz);
      o.w = bf16rn(bf2f(fv.w) - di * aAw);
      *(ushort4*)&outBuf[(size_t)rA * 64 + l4] = o;
    } else {
      float ch = chA_[cA], c1 = c1A_[cA], c2 = c2A_[cA];
      ushort4 fv = *(const ushort4*)&f[(size_t)rA * 64 + l4];
      ushort4 hv = *(const ushort4*)&hb[(size_t)nA * 64 + l4];
      float fx = bf2f(fv.x), fy = bf2f(fv.y), fz = bf2f(fv.z), fw = bf2f(fv.w);
      ushort4 o;
      o.x = bf16rn(ch * bf2f(hv.x) + c1 * fx + c2 * (fx - di * aAx));
      o.y = bf16rn(ch * bf2f(hv.y) + c1 * fy + c2 * (fy - di * aAy));
      o.z = bf16rn(ch * bf2f(hv.z) + c1 * fz + c2 * (fz - di * aAz));
      o.w = bf16rn(ch * bf2f(hv.w) + c1 * fw + c2 * (fw - di * aAw));
      *(ushort4*)&outBuf[(size_t)nA * 192 + cA * 64 + l4] = o;
    }
  }
  if (hasB) {
    float di = dinv[rB];
    if (STEP == 1) {
      ushort4 fv = *(const ushort4*)&f[(size_t)nB * 64 + l4];
      ushort4 o;
      o.x = bf16rn(bf2f(fv.x) - di * aBx);
      o.y = bf16rn(bf2f(fv.y) - di * aBy);
      o.z = bf16rn(bf2f(fv.z) - di * aBz);
      o.w = bf16rn(bf2f(fv.w) - di * aBw);
      *(ushort4*)&outBuf[(size_t)rB * 64 + l4] = o;
    } else {
      float ch = chA_[cB], c1 = c1A_[cB], c2 = c2A_[cB];
      ushort4 fv = *(const ushort4*)&f[(size_t)rB * 64 + l4];
      ushort4 hv = *(const ushort4*)&hb[(size_t)nB * 64 + l4];
      float fx = bf2f(fv.x), fy = bf2f(fv.y), fz = bf2f(fv.z), fw = bf2f(fv.w);
      ushort4 o;
      o.x = bf16rn(ch * bf2f(hv.x) + c1 * fx + c2 * (fx - di * aBx));
      o.y = bf16rn(ch * bf2f(hv.y) + c1 * fy + c2 * (fy - di * aBy));
      o.z = bf16rn(ch * bf2f(hv.z) + c1 * fz + c2 * (fz - di * aBz));
      o.w = bf16rn(ch * bf2f(hv.w) + c1 * fw + c2 * (fw - di * aBw));
      *(ushort4*)&outBuf[(size_t)nB * 192 + cB * 64 + l4] = o;
    }
  }
}

// Per-class gather (fallback path), bf16 data, R6 4x unroll
template<int STEP>
__global__ __launch_bounds__(256) void gatherF_kernel(const unsigned short* __restrict__ f,
    const unsigned short* __restrict__ hb, unsigned short* __restrict__ outBuf,
    const int* __restrict__ rowPtr, const int* __restrict__ eSrc,
    const float* __restrict__ dinv, float ch, float c1, float c2, int N) {
  int n = blockIdx.x * 16 + (threadIdx.x >> 4);
  if (n >= N) return;
  int l = threadIdx.x & 15;
  int beg = rowPtr[n], end = rowPtr[n + 1];
  float ax = 0.f, ay = 0.f, az = 0.f, aw = 0.f;
  float bx = 0.f, by = 0.f, bz = 0.f, bw = 0.f;
  int e = beg;
  for (; e + 4 <= end; e += 4) {
    int s0 = eSrc[e], s1 = eSrc[e + 1], s2 = eSrc[e + 2], s3 = eSrc[e + 3];
    float c0 = dinv[s0], c1_ = dinv[s1], c2_ = dinv[s2], c3 = dinv[s3];
    ushort4 v0 = *(const ushort4*)&f[(size_t)s0 * 64 + l * 4];
    ushort4 v1 = *(const ushort4*)&f[(size_t)s1 * 64 + l * 4];
    ushort4 v2 = *(const ushort4*)&f[(size_t)s2 * 64 + l * 4];
    ushort4 v3 = *(const ushort4*)&f[(size_t)s3 * 64 + l * 4];
    ax += bf2f(v0.x) * c0; ay += bf2f(v0.y) * c0; az += bf2f(v0.z) * c0; aw += bf2f(v0.w) * c0;
    bx += bf2f(v1.x) * c1_; by += bf2f(v1.y) * c1_; bz += bf2f(v1.z) * c1_; bw += bf2f(v1.w) * c1_;
    ax += bf2f(v2.x) * c2_; ay += bf2f(v2.y) * c2_; az += bf2f(v2.z) * c2_; aw += bf2f(v2.w) * c2_;
    bx += bf2f(v3.x) * c3; by += bf2f(v3.y) * c3; bz += bf2f(v3.z) * c3; bw += bf2f(v3.w) * c3;
  }
  for (; e < end; ++e) {
    int s = eSrc[e];
    float sc = dinv[s];
    ushort4 v = *(const ushort4*)&f[(size_t)s * 64 + l * 4];
    ax += bf2f(v.x) * sc; ay += bf2f(v.y) * sc;
    az += bf2f(v.z) * sc; aw += bf2f(v.w) * sc;
  }
  ax += bx; ay += by; az += bz; aw += bw;
  float di = dinv[n];
  size_t idx = (size_t)n * 64 + l * 4;
  ushort4 fv = *(const ushort4*)&f[idx];
  float fx = bf2f(fv.x), fy = bf2f(fv.y), fz = bf2f(fv.z), fw = bf2f(fv.w);
  ushort4 o;
  if (STEP == 1) {
    o.x = bf16rn(fx - di * ax); o.y = bf16rn(fy - di * ay);
    o.z = bf16rn(fz - di * az); o.w = bf16rn(fw - di * aw);
  } else {
    ushort4 hv = *(const ushort4*)&hb[idx];
    o.x = bf16rn(ch * bf2f(hv.x) + c1 * fx + c2 * (fx - di * ax));
    o.y = bf16rn(ch * bf2f(hv.y) + c1 * fy + c2 * (fy - di * ay));
    o.z = bf16rn(ch * bf2f(hv.z) + c1 * fz + c2 * (fz - di * az));
    o.w = bf16rn(ch * bf2f(hv.w) + c1 * fw + c2 * (fw - di * aw));
  }
  *(ushort4*)&outBuf[idx] = o;
}

// ======================= MFMA GEMMs (R8: 128-row tiles) =====================
// Wt layouts: Wt1[col][k] K=128 at off 0; Wt2 K=64; Wt3 K=192 (separate bufs).
__global__ void wconvAll_kernel(const float* __restrict__ W1, const float* __restrict__ W2,
                                const float* __restrict__ W3,
                                unsigned short* __restrict__ Wt1,
                                unsigned short* __restrict__ Wt2,
                                unsigned short* __restrict__ Wt3) {
  int i = blockIdx.x * 256 + threadIdx.x;
  if (i < 8192) {                    // Wt1: 64 cols x K=128
    int col = i >> 7, k = i & 127;
    Wt1[i] = bf16rn(W1[(size_t)k * 64 + col]);
  } else if (i < 12288) {            // Wt2: 64 x 64
    int j = i - 8192;
    int col = j >> 6, k = j & 63;
    Wt2[j] = bf16rn(W2[(size_t)k * 64 + col]);
  } else if (i < 24576) {            // Wt3: 64 cols x K=192
    int j = i - 12288;
    int col = j / 192, k = j - col * 192;
    Wt3[j] = bf16rn(W3[(size_t)k * 64 + col]);
  }
}

// C[N,64] = A[N,K] @ Wt^T (bf16), fp32 accum via MFMA 16x16x32.
// 128-row x 64-col tile, 4 waves; wave w covers rows [w*32, w*32+32) via two
// A-fragments; 8 MFMAs between each barrier pair.
template<int K, int ABF, int OBF>
__global__ __launch_bounds__(256) void gemm_mfma_kernel(const void* __restrict__ Ain,
    const unsigned short* __restrict__ Wt, const float* __restrict__ bias,
    void* __restrict__ Cout, int N, int accum, int finish) {
  __shared__ short As[128 * 40];
  const int tid = threadIdx.x;
  const int wave = tid >> 6, lane = tid & 63;
  const int m = lane & 15, quad = lane >> 4;
  const int rowBase = blockIdx.x * 128;
  floatx4 acc[2][4] = {};
  const int rs = tid >> 1;          // staging row 0..127
  const int cs = (tid & 1) * 16;    // staging col base 0/16
  const int rowS = rowBase + rs;
  const int aRow0 = (wave * 32 + m) * 40 + quad * 8;
  const int aRow1 = aRow0 + 16 * 40;
  for (int kc = 0; kc < K; kc += 32) {
    short8 s0 = {0,0,0,0,0,0,0,0}, s1 = s0;
    if (rowS < N) {
      if (ABF) {
        const unsigned short* p = (const unsigned short*)Ain + (size_t)rowS * K + kc + cs;
        s0 = *(const short8*)p;
        s1 = *(const short8*)(p + 8);
      } else {
        const float* p = (const float*)Ain + (size_t)rowS * K + kc + cs;
        float4 v0 = *(const float4*)p;
        float4 v1 = *(const float4*)(p + 4);
        float4 v2 = *(const float4*)(p + 8);
        float4 v3 = *(const float4*)(p + 12);
        s0[0] = bf16rn(v0.x); s0[1] = bf16rn(v0.y); s0[2] = bf16rn(v0.z); s0[3] = bf16rn(v0.w);
        s0[4] = bf16rn(v1.x); s0[5] = bf16rn(v1.y); s0[6] = bf16rn(v1.z); s0[7] = bf16rn(v1.w);
        s1[0] = bf16rn(v2.x); s1[1] = bf16rn(v2.y); s1[2] = bf16rn(v2.z); s1[3] = bf16rn(v2.w);
        s1[4] = bf16rn(v3.x); s1[5] = bf16rn(v3.y); s1[6] = bf16rn(v3.z); s1[7] = bf16rn(v3.w);
      }
    }
    *(short8*)&As[rs * 40 + cs] = s0;
    *(short8*)&As[rs * 40 + cs + 8] = s1;
    __syncthreads();
    short8 af0 = *(const short8*)&As[aRow0];
    short8 af1 = *(const short8*)&As[aRow1];
    const unsigned short* wp = Wt + (size_t)m * K + kc + quad * 8;
#pragma unroll
    for (int ct = 0; ct < 4; ++ct) {
      short8 bf = *(const short8*)(wp + (size_t)ct * 16 * K);
      acc[0][ct] = __builtin_amdgcn_mfma_f32_16x16x32_bf16(af0, bf, acc[0][ct], 0, 0, 0);
      acc[1][ct] = __builtin_amdgcn_mfma_f32_16x16x32_bf16(af1, bf, acc[1][ct], 0, 0, 0);
    }
    __syncthreads();
  }
#pragma unroll
  for (int h = 0; h < 2; ++h) {
    const int r0 = rowBase + wave * 32 + h * 16 + quad * 4;
#pragma unroll
    for (int ct = 0; ct < 4; ++ct) {
      float b = finish ? bias[ct * 16 + m] : 0.f;
#pragma unroll
      for (int reg = 0; reg < 4; ++reg) {
        int row = r0 + reg;
        if (row < N) {
          float o = acc[h][ct][reg];
          if (OBF) {
            if (finish) o = fmaxf(o + b, 0.f);
            ((unsigned short*)Cout)[(size_t)row * 64 + ct * 16 + m] = bf16rn(o);
          } else {
            float* cp = (float*)Cout + (size_t)row * 64 + ct * 16 + m;
            if (accum) o += *cp;
            if (finish) o = fmaxf(o + b, 0.f);
            *cp = o;
          }
        }
      }
    }
  }
}

extern "C" void kernel_launch(void* const* d_in, const int* in_sizes, int n_in,
                              void* d_out, int out_size, void* d_ws, size_t ws_size,
                              hipStream_t stream) {
  const float* feat = (const float*)d_in[0];
  const float* ep   = (const float*)d_in[1];
  const int*   src  = (const int*)d_in[2];
  const int*   dst  = (const int*)d_in[3];
  const float* W1   = (const float*)d_in[4];
  const float* b1   = (const float*)d_in[5];
  const float* W2   = (const float*)d_in[6];
  const float* b2   = (const float*)d_in[7];
  const float* W3   = (const float*)d_in[8];
  const float* b3   = (const float*)d_in[9];
  float* out = (float*)d_out;
  const int N = in_sizes[0] / 128;
  const int E = in_sizes[1];
  const int nRows = 3 * N;
  const int NB = (nRows + 511) >> 9;   // 512-row buckets; requires NB <= MAXNB

  char* w = (char*)d_ws;
  size_t off = 0;
  QState* st = (QState*)(w + off);           off += WS_ALIGN(sizeof(QState));
  const size_t zeroBytes = off;              // QState only
  int* rowPtr = (int*)(w + off);             off += WS_ALIGN((size_t)(nRows + 1) * 4);
  float* dinv = (float*)(w + off);           off += WS_ALIGN((size_t)nRows * 4);
  int* rowKey = (int*)(w + off);             off += WS_ALIGN((size_t)E * 4);
  int* partHist = (int*)(w + off);           off += WS_ALIGN((size_t)NBLK * NB * 4);
  int* baseArr = (int*)(w + off);            off += WS_ALIGN((size_t)NBLK * NB * 4);
  int* bucketPtr = (int*)(w + off);          off += WS_ALIGN((size_t)(NB + 1) * 4);
  int2* staged = (int2*)(w + off);           off += WS_ALIGN((size_t)E * 8);
  int* eSrc = (int*)(w + off);               off += WS_ALIGN((size_t)E * 4);
  unsigned short* Wt1 = (unsigned short*)(w + off); off += WS_ALIGN((size_t)64 * 128 * 2);
  unsigned short* Wt2 = (unsigned short*)(w + off); off += WS_ALIGN((size_t)64 * 64 * 2);
  unsigned short* Wt3 = (unsigned short*)(w + off); off += WS_ALIGN((size_t)64 * 192 * 2);
  unsigned short* h_bf = (unsigned short*)(w + off); off += WS_ALIGN((size_t)N * 64 * 2);
  // fused: L1_bf [3N,64] + combo_bf [N,192]; fallback: L1 [N,64] + combo [N,64]
  const size_t fusedNeed = off + (size_t)nRows * 64 * 2 + (size_t)N * 192 * 2;
  const bool fused = (ws_size >= fusedNeed);
  unsigned short* L1_bf = (unsigned short*)(w + off);   // also temp for h1
  unsigned short* combo_bf = fused
      ? (unsigned short*)(w + off + WS_ALIGN((size_t)nRows * 64 * 2))
      : (unsigned short*)(w + off + WS_ALIGN((size_t)N * 64 * 2));
  (void)n_in; (void)out_size;

  hipMemsetAsync(d_ws, 0, zeroBytes, stream);

  // ---- quantile thresholds (exact radix-select) ----
  qhist_kernel<<<512, 256, 0, stream>>>(ep, st, E, 0);
  qinit_kernel<<<1, 256, 0, stream>>>(st);
  for (int r = 1; r < 4; ++r) {
    qhist_kernel<<<512, 256, 0, stream>>>(ep, st, E, r);
    qupdate_kernel<<<1, 1, 0, stream>>>(st, r);
  }
  qvnext_kernel<<<512, 256, 0, stream>>>(ep, st, E);
  qfinal_kernel<<<1, 1, 0, stream>>>(st);

  // ---- weights + MLP (independent of edges) ----
  wconvAll_kernel<<<(24576 + 255) / 256, 256, 0, stream>>>(W1, W2, W3, Wt1, Wt2, Wt3);
  const int gb = (N + 127) / 128;
  gemm_mfma_kernel<128, 0, 1><<<gb, 256, 0, stream>>>(feat, Wt1, b1, L1_bf, N, 0, 1);
  gemm_mfma_kernel<64, 1, 1><<<gb, 256, 0, stream>>>(L1_bf, Wt2, b2, h_bf, N, 0, 1);

  // ---- bucket-staged CSR build ----
  bucket_count<<<NBLK, 256, 0, stream>>>(ep, dst, st, rowKey, partHist, N, E, NB);
  bucket_scanA<<<1, 1024, 0, stream>>>(partHist, bucketPtr, NB);
  bucket_scanB<<<NB, 64, 0, stream>>>(partHist, bucketPtr, baseArr, NB);
  bucket_scatter<<<NBLK, 256, 0, stream>>>(rowKey, src, baseArr, staged, E, NB);
  bucket_build<<<NB, 256, 0, stream>>>(staged, bucketPtr, rowPtr, dinv, eSrc, nRows, NB);

  // ---- propagation + head ----
  if (fused) {
    const int g3 = (nRows + 31) / 32;
    gather3_kernel<1><<<g3, 256, 0, stream>>>(h_bf, h_bf, L1_bf, rowPtr, eSrc, dinv, N, nRows);
    gather3_kernel<2><<<g3, 256, 0, stream>>>(L1_bf, h_bf, combo_bf, rowPtr, eSrc, dinv, N, nRows);
    gemm_mfma_kernel<192, 1, 0><<<gb, 256, 0, stream>>>(combo_bf, Wt3, b3, out, N, 0, 1);
  } else {
    const float chArr[3] = {0.f, 0.f, 3.f};
    const float c1Arr[3] = {0.f, 3.f, -3.f};
    const float c2Arr[3] = {0.75f, -1.5f, 0.75f};
    const int ggrid = (N + 15) / 16;
    for (int c = 0; c < 3; ++c) {
      const int* rp = rowPtr + (size_t)c * N;
      const float* dv = dinv + (size_t)c * N;
      gatherF_kernel<1><<<ggrid, 256, 0, stream>>>(h_bf, nullptr, L1_bf, rp, eSrc, dv,
                                                   0.f, 0.f, 0.f, N);
      gatherF_kernel<2><<<ggrid, 256, 0, stream>>>(L1_bf, h_bf, combo_bf, rp, eSrc, dv,
                                                   chArr[c], c1Arr[c], c2Arr[c], N);
      gemm_mfma_kernel<64, 1, 0><<<gb, 256, 0, stream>>>(combo_bf, Wt2, b3, out,
                                                         N, c > 0 ? 1 : 0, c == 2 ? 1 : 0);
    }
  }
}